// Round 1
// baseline (1699.585 us; speedup 1.0000x reference)
//
#include <hip/hip_runtime.h>
#include <math.h>

// ---- problem constants ----
#define L0T 2048000   // 160*160*80
#define L1T 512000    // 80*80*80
#define L2T 128000    // 40*40*80
#define LTOT 2688000
#define NTOT 5600     // 2000+2000+1600
#define NW 88         // ceil(5600/64)
#define NBUCK 65536
#define CANDCAP 8192

// monotone order-preserving key for f32
__device__ __forceinline__ unsigned mkey(float f){
  unsigned u = __float_as_uint(f);
  return u ^ ((unsigned)(((int)u) >> 31) | 0x80000000u);
}

__global__ void hist_kernel(const float* __restrict__ c0, const float* __restrict__ c1,
                            const float* __restrict__ c2, unsigned* __restrict__ hist){
  int g = blockIdx.x * blockDim.x + threadIdx.x;
  int stride = gridDim.x * blockDim.x;
  const int Q = LTOT / 4;
  for (int q = g; q < Q; q += stride){
    int e = q * 4;
    int lvl, idx; const float* p;
    if (e < L0T){ lvl = 0; idx = e; p = c0; }
    else if (e < L0T + L1T){ lvl = 1; idx = e - L0T; p = c1; }
    else { lvl = 2; idx = e - (L0T + L1T); p = c2; }
    float4 v = *(const float4*)(p + idx);
    unsigned* h = hist + lvl * NBUCK;
    atomicAdd(&h[mkey(v.x) >> 16], 1u);
    atomicAdd(&h[mkey(v.y) >> 16], 1u);
    atomicAdd(&h[mkey(v.z) >> 16], 1u);
    atomicAdd(&h[mkey(v.w) >> 16], 1u);
  }
}

// one block per level: find b* = max bucket with count_ge(b*) >= K
__global__ __launch_bounds__(1024) void thresh_kernel(const unsigned* __restrict__ hist,
                                                      unsigned* __restrict__ bstar){
  int lvl = blockIdx.x;
  const unsigned* h = hist + lvl * NBUCK;
  unsigned K = (lvl == 2) ? 1600u : 2000u;
  __shared__ unsigned partial[1024];
  int t = threadIdx.x;
  unsigned s = 0;
  for (int b = t * 64; b < t * 64 + 64; ++b) s += h[b];
  partial[t] = s;
  __syncthreads();
  if (t == 0){
    unsigned acc = 0; int seg = 1023;
    while (seg >= 0 && acc + partial[seg] < K){ acc += partial[seg]; --seg; }
    unsigned bs = 0;
    if (seg >= 0){
      for (int b = seg * 64 + 63; b >= seg * 64; --b){
        acc += h[b];
        if (acc >= K){ bs = (unsigned)b; break; }
      }
    }
    bstar[lvl] = bs;
  }
}

__global__ void compact_kernel(const float* __restrict__ c0, const float* __restrict__ c1,
                               const float* __restrict__ c2, const unsigned* __restrict__ bstar,
                               unsigned* __restrict__ candCnt, unsigned long long* __restrict__ cand){
  unsigned b0 = bstar[0], b1 = bstar[1], b2 = bstar[2];
  int g = blockIdx.x * blockDim.x + threadIdx.x;
  int stride = gridDim.x * blockDim.x;
  for (int e = g; e < LTOT; e += stride){
    int lvl, idx; const float* p; unsigned bs;
    if (e < L0T){ lvl = 0; idx = e; p = c0; bs = b0; }
    else if (e < L0T + L1T){ lvl = 1; idx = e - L0T; p = c1; bs = b1; }
    else { lvl = 2; idx = e - (L0T + L1T); p = c2; bs = b2; }
    unsigned key = mkey(p[idx]);
    if ((key >> 16) >= bs){
      unsigned pos = atomicAdd(&candCnt[lvl], 1u);
      if (pos < CANDCAP)
        cand[lvl * CANDCAP + pos] = ((unsigned long long)key << 32) | (unsigned)(~(unsigned)idx);
    }
  }
}

// per level: bitonic-sort candidates (desc key, asc idx), emit top-K into concat arrays
__global__ __launch_bounds__(1024) void level_sort_kernel(
    const float* __restrict__ box0, const float* __restrict__ box1, const float* __restrict__ box2,
    const unsigned* __restrict__ candCnt, const unsigned long long* __restrict__ cand,
    unsigned* __restrict__ ckey, float* __restrict__ cscore, int* __restrict__ clabel,
    float* __restrict__ cbox, unsigned* __restrict__ cvalid){
  extern __shared__ unsigned long long lds[];
  int lvl = blockIdx.x;
  int K = (lvl == 2) ? 1600 : 2000;
  int base = lvl * 2000;
  const float* bx = (lvl == 0) ? box0 : ((lvl == 1) ? box1 : box2);
  unsigned cnt = candCnt[lvl]; if (cnt > CANDCAP) cnt = CANDCAP;
  for (int i = threadIdx.x; i < CANDCAP; i += blockDim.x)
    lds[i] = (i < (int)cnt) ? cand[lvl * CANDCAP + i] : 0ull;
  __syncthreads();
  for (int kk = 2; kk <= CANDCAP; kk <<= 1){
    for (int j = kk >> 1; j > 0; j >>= 1){
      for (int i = threadIdx.x; i < CANDCAP; i += blockDim.x){
        int l = i ^ j;
        if (l > i){
          unsigned long long a = lds[i], b = lds[l];
          bool up = ((i & kk) == 0);
          if ((a > b) == up){ lds[i] = b; lds[l] = a; }
        }
      }
      __syncthreads();
    }
  }
  for (int r = threadIdx.x; r < K; r += blockDim.x){
    unsigned long long e = lds[CANDCAP - 1 - r];     // descending rank r
    unsigned key = (unsigned)(e >> 32);
    unsigned idx = ~(unsigned)e;
    int anchor = (int)(idx / 80u);
    int lbl = (int)(idx % 80u);
    unsigned fb = (key & 0x80000000u) ? (key ^ 0x80000000u) : ~key;
    float logit = __uint_as_float(fb);
    float sc = 1.0f / (1.0f + expf(-logit));
    int pos = base + r;
    ckey[pos] = key;
    cscore[pos] = sc;
    clabel[pos] = lbl;
    cvalid[pos] = (sc > 0.05f) ? 1u : 0u;
    const float* bp = bx + (size_t)anchor * 4;
    cbox[pos * 4 + 0] = bp[0]; cbox[pos * 4 + 1] = bp[1];
    cbox[pos * 4 + 2] = bp[2]; cbox[pos * 4 + 3] = bp[3];
  }
}

// global stable sort by (valid?key:0 desc, concat-pos asc); emit sorted arrays + offset boxes
__global__ __launch_bounds__(1024) void global_sort_kernel(
    const unsigned* __restrict__ ckey, const float* __restrict__ cscore,
    const int* __restrict__ clabel, const float* __restrict__ cbox,
    const unsigned* __restrict__ cvalid,
    float* __restrict__ sscore, int* __restrict__ slabel, float* __restrict__ sbox,
    float* __restrict__ soff, unsigned* __restrict__ svalid){
  extern __shared__ unsigned long long lds[];
  const int NP = 8192;
  for (int i = threadIdx.x; i < NP; i += blockDim.x){
    unsigned long long e = 0ull;
    if (i < NTOT){
      unsigned eff = cvalid[i] ? ckey[i] : 0u;
      e = ((unsigned long long)eff << 32) | (unsigned)(~(unsigned)i);
    }
    lds[i] = e;
  }
  __syncthreads();
  for (int kk = 2; kk <= NP; kk <<= 1){
    for (int j = kk >> 1; j > 0; j >>= 1){
      for (int i = threadIdx.x; i < NP; i += blockDim.x){
        int l = i ^ j;
        if (l > i){
          unsigned long long a = lds[i], b = lds[l];
          bool up = ((i & kk) == 0);
          if ((a > b) == up){ lds[i] = b; lds[l] = a; }
        }
      }
      __syncthreads();
    }
  }
  for (int r = threadIdx.x; r < NTOT; r += blockDim.x){
    unsigned long long e = lds[NP - 1 - r];
    int o = (int)(~(unsigned)e);
    int lbl = clabel[o];
    float off = (float)lbl * 10000.0f;
    sscore[r] = cscore[o];
    slabel[r] = lbl;
    svalid[r] = cvalid[o];
    float b0 = cbox[o * 4 + 0], b1 = cbox[o * 4 + 1], b2 = cbox[o * 4 + 2], b3 = cbox[o * 4 + 3];
    sbox[r * 4 + 0] = b0; sbox[r * 4 + 1] = b1; sbox[r * 4 + 2] = b2; sbox[r * 4 + 3] = b3;
    soff[r * 4 + 0] = b0 + off; soff[r * 4 + 1] = b1 + off;
    soff[r * 4 + 2] = b2 + off; soff[r * 4 + 3] = b3 + off;
  }
}

// suppression bitmask: mask[i][wj] bit jj = (j>i && iou(i,j)>0.6) with offset boxes
__global__ void nms_mask_kernel(const float* __restrict__ soff, const int* __restrict__ slabel,
                                unsigned* __restrict__ rowAny, unsigned long long* __restrict__ mask){
  __shared__ float cb[64][4];
  __shared__ float ca[64];
  __shared__ int cl[64];
  int wi = blockIdx.x, wj = blockIdx.y;
  int t = threadIdx.x;
  int i = wi * 64 + t;
  if (wj < wi){                      // all j < i: word is zero, but must be initialized
    if (i < NTOT) mask[(size_t)i * NW + wj] = 0ull;
    return;
  }
  int j0 = wj * 64;
  int j = j0 + t;
  if (j < NTOT){
    float x1 = soff[j * 4 + 0], y1 = soff[j * 4 + 1];
    float x2 = soff[j * 4 + 2], y2 = soff[j * 4 + 3];
    cb[t][0] = x1; cb[t][1] = y1; cb[t][2] = x2; cb[t][3] = y2;
    {
#pragma clang fp contract(off)
      ca[t] = fmaxf(x2 - x1, 0.0f) * fmaxf(y2 - y1, 0.0f);
    }
    cl[t] = slabel[j];
  } else {
    cl[t] = -1;
  }
  __syncthreads();
  if (i >= NTOT) return;
  float ax1 = soff[i * 4 + 0], ay1 = soff[i * 4 + 1];
  float ax2 = soff[i * 4 + 2], ay2 = soff[i * 4 + 3];
  int li = slabel[i];
  float areaA;
  {
#pragma clang fp contract(off)
    areaA = fmaxf(ax2 - ax1, 0.0f) * fmaxf(ay2 - ay1, 0.0f);
  }
  unsigned long long w = 0ull;
  for (int jj = 0; jj < 64; ++jj){
    int jg = j0 + jj;
    if (jg >= NTOT) break;
    if (jg <= i) continue;
    if (cl[jj] != li) continue;
    {
#pragma clang fp contract(off)
      float ltx = fmaxf(ax1, cb[jj][0]);
      float lty = fmaxf(ay1, cb[jj][1]);
      float rbx = fminf(ax2, cb[jj][2]);
      float rby = fminf(ay2, cb[jj][3]);
      float ww = fmaxf(rbx - ltx, 0.0f);
      float hh = fmaxf(rby - lty, 0.0f);
      float inter = ww * hh;
      float uni = (areaA + ca[jj]) - inter;
      float iou = inter / fmaxf(uni, 1e-9f);
      if (iou > 0.6f) w |= (1ull << jj);
    }
  }
  mask[(size_t)i * NW + wj] = w;
  if (w) rowAny[i] = 1u;
}

// single-wave sequential greedy scan; removed bits live in registers (word w: lane w / lane w-64)
__global__ void nms_scan_kernel(const unsigned long long* __restrict__ mask,
                                const unsigned* __restrict__ rowAny,
                                const unsigned* __restrict__ svalid,
                                unsigned long long* __restrict__ keepW){
  int lane = threadIdx.x;  // 64 threads
  unsigned long long rem0 = 0ull, rem1 = 0ull;
  for (int w = 0; w < NW; ++w){
    int e = w * 64 + lane;
    unsigned v = (e < NTOT) ? svalid[e] : 0u;
    unsigned long long bal = __ballot(v == 0u);   // invalid/out-of-range = pre-suppressed
    if (w == lane) rem0 = bal;
    if (w == 64 + lane) rem1 = bal;
  }
  for (int c = 0; c < NW; ++c){
    int row = c * 64 + lane;
    unsigned long long D = 0ull;
    unsigned any = 0u;
    if (row < NTOT){
      D = mask[(size_t)row * NW + c];   // diagonal word (intra-chunk bits, all > own pos)
      any = rowAny[row];
    }
    unsigned long long a0 = __shfl(rem0, c & 63);
    unsigned long long a1 = __shfl(rem1, c & 63);
    unsigned long long rem = (c < 64) ? a0 : a1;
    // serial resolve only over rows with intra-chunk suppression bits (usually none)
    unsigned long long nz = __ballot(D != 0ull);
    while (nz){
      int b = __builtin_ctzll(nz);
      nz &= nz - 1;
      unsigned long long Db = __shfl(D, b);       // uniform path: all lanes execute
      if (!((rem >> b) & 1ull)) rem |= Db;
    }
    unsigned long long kp = ~rem;
    if (c < 64){ if (lane == c) rem0 = rem; }
    else       { if (lane == c - 64) rem1 = rem; }
    if (lane == 0) keepW[c] = kp;
    // OR kept rows (that suppress anything) into the running removed words
    unsigned long long act = kp & __ballot(any != 0u);
    while (act){
      int b = __builtin_ctzll(act);
      act &= act - 1;
      int r2 = c * 64 + b;
      rem0 |= mask[(size_t)r2 * NW + lane];
      if (lane < NW - 64) rem1 |= mask[(size_t)r2 * NW + 64 + lane];
    }
  }
}

__device__ __forceinline__ float read_dim(const int* p){
  int iv = p[0];
  if (iv > 0 && iv < (1 << 24)) return (float)iv;   // stored as int
  return __int_as_float(iv);                        // stored as float bits
}

__global__ void output_kernel(const float* __restrict__ sscore, const int* __restrict__ slabel,
                              const float* __restrict__ sbox, const unsigned long long* __restrict__ keepW,
                              const int* __restrict__ imw, const int* __restrict__ imh,
                              float* __restrict__ out){
  int r = blockIdx.x * blockDim.x + threadIdx.x;
  if (r >= NTOT) return;
  float wv = read_dim(imw), hv = read_dim(imh);
  float sw = (float)(1.0 / (double)wv);   // match python 1.0/img_w (double) -> f32
  float sh = (float)(1.0 / (double)hv);
  float b0 = sbox[r * 4 + 0] * sw, b1 = sbox[r * 4 + 1] * sh;
  float b2 = sbox[r * 4 + 2] * sw, b3 = sbox[r * 4 + 3] * sh;
  out[r * 4 + 0] = fminf(fmaxf(b0, 0.0f), 1.0f);
  out[r * 4 + 1] = fminf(fmaxf(b1, 0.0f), 1.0f);
  out[r * 4 + 2] = fminf(fmaxf(b2, 0.0f), 1.0f);
  out[r * 4 + 3] = fminf(fmaxf(b3, 0.0f), 1.0f);
  out[NTOT * 4 + r] = sscore[r];
  out[NTOT * 5 + r] = (float)slabel[r];
  out[NTOT * 6 + r] = ((keepW[r >> 6] >> (r & 63)) & 1ull) ? 1.0f : 0.0f;
}

// ---- workspace layout (bytes) ----
#define WS_HIST     0u         // 3*65536*4 = 786432
#define WS_CANDCNT  786432u    // 16
#define WS_ROWANY   786448u    // 5600*4 = 22400  -> zero region ends 808848
#define WS_ZERO     808848u
#define WS_BSTAR    808848u    // 16
#define WS_CAND     808864u    // 3*8192*8 = 196608
#define WS_CKEY     1005472u   // 22400
#define WS_CSCORE   1027872u   // 22400
#define WS_CLABEL   1050272u   // 22400
#define WS_CBOX     1072672u   // 89600
#define WS_CVALID   1162272u   // 22400
#define WS_SSCORE   1184672u   // 22400
#define WS_SLABEL   1207072u   // 22400
#define WS_SBOX     1229472u   // 89600
#define WS_SOFF     1319072u   // 89600
#define WS_SVALID   1408672u   // 22400
#define WS_KEEPW    1431072u   // 88*8 = 704
#define WS_MASK     1431776u   // 5600*88*8 = 3942400 -> end 5374176

extern "C" void kernel_launch(void* const* d_in, const int* in_sizes, int n_in,
                              void* d_out, int out_size, void* d_ws, size_t ws_size,
                              hipStream_t stream) {
  (void)in_sizes; (void)n_in; (void)out_size; (void)ws_size;
  const float* cls0 = (const float*)d_in[0];
  const float* box0 = (const float*)d_in[1];
  const float* cls1 = (const float*)d_in[2];
  const float* box1 = (const float*)d_in[3];
  const float* cls2 = (const float*)d_in[4];
  const float* box2 = (const float*)d_in[5];
  const int* imw = (const int*)d_in[6];
  const int* imh = (const int*)d_in[7];
  char* w = (char*)d_ws;
  unsigned* hist    = (unsigned*)(w + WS_HIST);
  unsigned* candCnt = (unsigned*)(w + WS_CANDCNT);
  unsigned* rowAny  = (unsigned*)(w + WS_ROWANY);
  unsigned* bstar   = (unsigned*)(w + WS_BSTAR);
  unsigned long long* cand = (unsigned long long*)(w + WS_CAND);
  unsigned* ckey   = (unsigned*)(w + WS_CKEY);
  float* cscore    = (float*)(w + WS_CSCORE);
  int* clabel      = (int*)(w + WS_CLABEL);
  float* cbox      = (float*)(w + WS_CBOX);
  unsigned* cvalid = (unsigned*)(w + WS_CVALID);
  float* sscore    = (float*)(w + WS_SSCORE);
  int* slabel      = (int*)(w + WS_SLABEL);
  float* sbox      = (float*)(w + WS_SBOX);
  float* soff      = (float*)(w + WS_SOFF);
  unsigned* svalid = (unsigned*)(w + WS_SVALID);
  unsigned long long* keepW = (unsigned long long*)(w + WS_KEEPW);
  unsigned long long* mask  = (unsigned long long*)(w + WS_MASK);

  hipMemsetAsync(d_ws, 0, WS_ZERO, stream);
  hist_kernel<<<1024, 256, 0, stream>>>(cls0, cls1, cls2, hist);
  thresh_kernel<<<3, 1024, 0, stream>>>(hist, bstar);
  compact_kernel<<<1024, 256, 0, stream>>>(cls0, cls1, cls2, bstar, candCnt, cand);
  level_sort_kernel<<<3, 1024, 65536, stream>>>(box0, box1, box2, candCnt, cand,
                                                ckey, cscore, clabel, cbox, cvalid);
  global_sort_kernel<<<1, 1024, 65536, stream>>>(ckey, cscore, clabel, cbox, cvalid,
                                                 sscore, slabel, sbox, soff, svalid);
  nms_mask_kernel<<<dim3(88, 88), 64, 0, stream>>>(soff, slabel, rowAny, mask);
  nms_scan_kernel<<<1, 64, 0, stream>>>(mask, rowAny, svalid, keepW);
  output_kernel<<<22, 256, 0, stream>>>(sscore, slabel, sbox, keepW, imw, imh, (float*)d_out);
}

// Round 2
// 472.389 us; speedup vs baseline: 3.5979x; 3.5979x over previous
//
#include <hip/hip_runtime.h>
#include <math.h>

// ---- problem constants ----
#define L0T 2048000   // 160*160*80
#define L1T 512000    // 80*80*80
#define L2T 128000    // 40*40*80
#define LTOT 2688000
#define NTOT 5600     // 2000+2000+1600
#define NW 88         // ceil(5600/64)
#define NCB 2048      // coarse buckets = key >> 21
#define HB 128        // histogram/compact block count
#define CANDCAP 8192

// monotone order-preserving key for f32
__device__ __forceinline__ unsigned mkey(float f){
  unsigned u = __float_as_uint(f);
  return u ^ ((unsigned)(((int)u) >> 31) | 0x80000000u);
}

// per-block LDS histogram, no global atomics
__global__ __launch_bounds__(256) void hist_blocks(const float* __restrict__ c0,
                                                   const float* __restrict__ c1,
                                                   const float* __restrict__ c2,
                                                   unsigned* __restrict__ blockHist){
  __shared__ unsigned lh[3 * NCB];
  for (int i = threadIdx.x; i < 3 * NCB; i += 256) lh[i] = 0;
  __syncthreads();
  int g = blockIdx.x * 256 + threadIdx.x;
  const int Q = LTOT / 4;
  for (int q = g; q < Q; q += HB * 256){
    int e = q * 4;
    int lvl, idx; const float* p;
    if (e < L0T){ lvl = 0; idx = e; p = c0; }
    else if (e < L0T + L1T){ lvl = 1; idx = e - L0T; p = c1; }
    else { lvl = 2; idx = e - (L0T + L1T); p = c2; }
    float4 v = *(const float4*)(p + idx);
    unsigned* h = lh + lvl * NCB;
    atomicAdd(&h[mkey(v.x) >> 21], 1u);
    atomicAdd(&h[mkey(v.y) >> 21], 1u);
    atomicAdd(&h[mkey(v.z) >> 21], 1u);
    atomicAdd(&h[mkey(v.w) >> 21], 1u);
  }
  __syncthreads();
  unsigned* out = blockHist + (size_t)blockIdx.x * 3 * NCB;
  for (int i = threadIdx.x; i < 3 * NCB; i += 256) out[i] = lh[i];
}

__global__ __launch_bounds__(256) void reduce_hist(const unsigned* __restrict__ blockHist,
                                                   unsigned* __restrict__ hist){
  int c = blockIdx.x * 256 + threadIdx.x;   // < 3*NCB = 6144
  unsigned s = 0;
#pragma unroll 8
  for (int b = 0; b < HB; ++b) s += blockHist[(size_t)b * 3 * NCB + c];
  hist[c] = s;
}

// one wave per level: T = max bucket with suffix-count >= K
__global__ void thresh_kernel(const unsigned* __restrict__ hist, unsigned* __restrict__ T){
  int wv = threadIdx.x >> 6, lane = threadIdx.x & 63;
  if (wv >= 3) return;
  unsigned K = (wv == 2) ? 1600u : 2000u;
  const unsigned* h = hist + wv * NCB;
  unsigned p = 0;
  for (int b = lane * 32; b < lane * 32 + 32; ++b) p += h[b];
  unsigned sincl = p;                     // inclusive suffix scan across lanes
  for (int d = 1; d < 64; d <<= 1){
    unsigned t = __shfl_down(sincl, d);
    if (lane + d < 64) sincl += t;
  }
  unsigned s_after = sincl - p;
  if (s_after < K && s_after + p >= K){   // exactly one lane
    unsigned acc = s_after;
    for (int b = lane * 32 + 31; b >= lane * 32; --b){
      acc += h[b];
      if (acc >= K){ T[wv] = (unsigned)b; break; }
    }
  }
}

// two-sweep compact: per-block count -> one atomic per (block,level) -> write
__global__ __launch_bounds__(256) void compact_kernel(const float* __restrict__ c0,
                                                      const float* __restrict__ c1,
                                                      const float* __restrict__ c2,
                                                      const unsigned* __restrict__ T,
                                                      unsigned* __restrict__ candCnt,
                                                      unsigned long long* __restrict__ cand){
  __shared__ unsigned blkCnt[3], blkBase[3], blkRun[3];
  unsigned t0 = T[0], t1 = T[1], t2 = T[2];
  if (threadIdx.x < 3){ blkCnt[threadIdx.x] = 0; blkRun[threadIdx.x] = 0; }
  __syncthreads();
  int g0 = blockIdx.x * 256 + threadIdx.x;
  int lane = threadIdx.x & 63;
  // sweep 1: count (wave-uniform level; boundaries are multiples of 64)
  for (int e = g0; e < LTOT; e += HB * 256){
    int lvl, idx; const float* p; unsigned tt;
    if (e < L0T){ lvl = 0; idx = e; p = c0; tt = t0; }
    else if (e < L0T + L1T){ lvl = 1; idx = e - L0T; p = c1; tt = t1; }
    else { lvl = 2; idx = e - (L0T + L1T); p = c2; tt = t2; }
    bool c = (mkey(p[idx]) >> 21) >= tt;
    unsigned long long bal = __ballot(c);
    if (lane == 0 && bal) atomicAdd(&blkCnt[lvl], (unsigned)__popcll(bal));
  }
  __syncthreads();
  if (threadIdx.x < 3){
    unsigned n = blkCnt[threadIdx.x];
    blkBase[threadIdx.x] = n ? atomicAdd(&candCnt[threadIdx.x], n) : 0u;
  }
  __syncthreads();
  // sweep 2: write
  for (int e = g0; e < LTOT; e += HB * 256){
    int lvl, idx; const float* p; unsigned tt;
    if (e < L0T){ lvl = 0; idx = e; p = c0; tt = t0; }
    else if (e < L0T + L1T){ lvl = 1; idx = e - L0T; p = c1; tt = t1; }
    else { lvl = 2; idx = e - (L0T + L1T); p = c2; tt = t2; }
    unsigned key = mkey(p[idx]);
    bool c = (key >> 21) >= tt;
    unsigned long long bal = __ballot(c);
    if (bal){
      unsigned wbase = 0;
      if (lane == 0) wbase = atomicAdd(&blkRun[lvl], (unsigned)__popcll(bal));
      wbase = __shfl(wbase, 0);
      if (c){
        unsigned pos = blkBase[lvl] + wbase + (unsigned)__popcll(bal & ((1ull << lane) - 1ull));
        if (pos < CANDCAP)
          cand[lvl * CANDCAP + pos] = ((unsigned long long)key << 32) | (unsigned)(~(unsigned)idx);
      }
    }
  }
}

// per level: bitonic-sort candidates (desc key, asc idx), emit top-K into concat arrays
__global__ __launch_bounds__(1024) void level_sort_kernel(
    const float* __restrict__ box0, const float* __restrict__ box1, const float* __restrict__ box2,
    const unsigned* __restrict__ candCnt, const unsigned long long* __restrict__ cand,
    unsigned* __restrict__ ckey, float* __restrict__ cscore, int* __restrict__ clabel,
    float* __restrict__ cbox, unsigned* __restrict__ cvalid){
  extern __shared__ unsigned long long lds[];
  int lvl = blockIdx.x;
  int K = (lvl == 2) ? 1600 : 2000;
  int base = lvl * 2000;
  const float* bx = (lvl == 0) ? box0 : ((lvl == 1) ? box1 : box2);
  unsigned cnt = candCnt[lvl]; if (cnt > CANDCAP) cnt = CANDCAP;
  for (int i = threadIdx.x; i < CANDCAP; i += blockDim.x)
    lds[i] = (i < (int)cnt) ? cand[lvl * CANDCAP + i] : 0ull;
  __syncthreads();
  for (int kk = 2; kk <= CANDCAP; kk <<= 1){
    for (int j = kk >> 1; j > 0; j >>= 1){
      for (int i = threadIdx.x; i < CANDCAP; i += blockDim.x){
        int l = i ^ j;
        if (l > i){
          unsigned long long a = lds[i], b = lds[l];
          bool up = ((i & kk) == 0);
          if ((a > b) == up){ lds[i] = b; lds[l] = a; }
        }
      }
      __syncthreads();
    }
  }
  for (int r = threadIdx.x; r < K; r += blockDim.x){
    unsigned long long e = lds[CANDCAP - 1 - r];     // descending rank r
    unsigned key = (unsigned)(e >> 32);
    unsigned idx = ~(unsigned)e;
    int anchor = (int)(idx / 80u);
    int lbl = (int)(idx % 80u);
    unsigned fb = (key & 0x80000000u) ? (key ^ 0x80000000u) : ~key;
    float logit = __uint_as_float(fb);
    float sc = 1.0f / (1.0f + expf(-logit));
    int pos = base + r;
    ckey[pos] = key;
    cscore[pos] = sc;
    clabel[pos] = lbl;
    cvalid[pos] = (sc > 0.05f) ? 1u : 0u;
    const float* bp = bx + (size_t)anchor * 4;
    cbox[pos * 4 + 0] = bp[0]; cbox[pos * 4 + 1] = bp[1];
    cbox[pos * 4 + 2] = bp[2]; cbox[pos * 4 + 3] = bp[3];
  }
}

// global stable sort by (valid?key:0 desc, concat-pos asc); emit sorted arrays + offset boxes
__global__ __launch_bounds__(1024) void global_sort_kernel(
    const unsigned* __restrict__ ckey, const float* __restrict__ cscore,
    const int* __restrict__ clabel, const float* __restrict__ cbox,
    const unsigned* __restrict__ cvalid,
    float* __restrict__ sscore, int* __restrict__ slabel, float* __restrict__ sbox,
    float* __restrict__ soff, unsigned* __restrict__ svalid){
  extern __shared__ unsigned long long lds[];
  const int NP = 8192;
  for (int i = threadIdx.x; i < NP; i += blockDim.x){
    unsigned long long e = 0ull;
    if (i < NTOT){
      unsigned eff = cvalid[i] ? ckey[i] : 0u;
      e = ((unsigned long long)eff << 32) | (unsigned)(~(unsigned)i);
    }
    lds[i] = e;
  }
  __syncthreads();
  for (int kk = 2; kk <= NP; kk <<= 1){
    for (int j = kk >> 1; j > 0; j >>= 1){
      for (int i = threadIdx.x; i < NP; i += blockDim.x){
        int l = i ^ j;
        if (l > i){
          unsigned long long a = lds[i], b = lds[l];
          bool up = ((i & kk) == 0);
          if ((a > b) == up){ lds[i] = b; lds[l] = a; }
        }
      }
      __syncthreads();
    }
  }
  for (int r = threadIdx.x; r < NTOT; r += blockDim.x){
    unsigned long long e = lds[NP - 1 - r];
    int o = (int)(~(unsigned)e);
    int lbl = clabel[o];
    float off = (float)lbl * 10000.0f;
    sscore[r] = cscore[o];
    slabel[r] = lbl;
    svalid[r] = cvalid[o];
    float b0 = cbox[o * 4 + 0], b1 = cbox[o * 4 + 1], b2 = cbox[o * 4 + 2], b3 = cbox[o * 4 + 3];
    sbox[r * 4 + 0] = b0; sbox[r * 4 + 1] = b1; sbox[r * 4 + 2] = b2; sbox[r * 4 + 3] = b3;
    soff[r * 4 + 0] = b0 + off; soff[r * 4 + 1] = b1 + off;
    soff[r * 4 + 2] = b2 + off; soff[r * 4 + 3] = b3 + off;
  }
}

// suppression bitmask: mask[i][wj] bit jj = (j>i && iou(i,j)>0.6) with offset boxes
__global__ void nms_mask_kernel(const float* __restrict__ soff, const int* __restrict__ slabel,
                                unsigned* __restrict__ rowAny, unsigned long long* __restrict__ mask){
  __shared__ float cb[64][4];
  __shared__ float ca[64];
  __shared__ int cl[64];
  int wi = blockIdx.x, wj = blockIdx.y;
  int t = threadIdx.x;
  int i = wi * 64 + t;
  if (wj < wi){                      // all j < i: word is zero, but must be initialized
    if (i < NTOT) mask[(size_t)i * NW + wj] = 0ull;
    return;
  }
  int j0 = wj * 64;
  int j = j0 + t;
  if (j < NTOT){
    float x1 = soff[j * 4 + 0], y1 = soff[j * 4 + 1];
    float x2 = soff[j * 4 + 2], y2 = soff[j * 4 + 3];
    cb[t][0] = x1; cb[t][1] = y1; cb[t][2] = x2; cb[t][3] = y2;
    {
#pragma clang fp contract(off)
      ca[t] = fmaxf(x2 - x1, 0.0f) * fmaxf(y2 - y1, 0.0f);
    }
    cl[t] = slabel[j];
  } else {
    cl[t] = -1;
  }
  __syncthreads();
  if (i >= NTOT) return;
  float ax1 = soff[i * 4 + 0], ay1 = soff[i * 4 + 1];
  float ax2 = soff[i * 4 + 2], ay2 = soff[i * 4 + 3];
  int li = slabel[i];
  float areaA;
  {
#pragma clang fp contract(off)
    areaA = fmaxf(ax2 - ax1, 0.0f) * fmaxf(ay2 - ay1, 0.0f);
  }
  unsigned long long w = 0ull;
  for (int jj = 0; jj < 64; ++jj){
    int jg = j0 + jj;
    if (jg >= NTOT) break;
    if (jg <= i) continue;
    if (cl[jj] != li) continue;
    {
#pragma clang fp contract(off)
      float ltx = fmaxf(ax1, cb[jj][0]);
      float lty = fmaxf(ay1, cb[jj][1]);
      float rbx = fminf(ax2, cb[jj][2]);
      float rby = fminf(ay2, cb[jj][3]);
      float ww = fmaxf(rbx - ltx, 0.0f);
      float hh = fmaxf(rby - lty, 0.0f);
      float inter = ww * hh;
      float uni = (areaA + ca[jj]) - inter;
      float iou = inter / fmaxf(uni, 1e-9f);
      if (iou > 0.6f) w |= (1ull << jj);
    }
  }
  mask[(size_t)i * NW + wj] = w;
  if (w) rowAny[i] = 1u;
}

// single-wave sequential greedy scan; removed bits live in registers (word w: lane w / lane w-64)
__global__ void nms_scan_kernel(const unsigned long long* __restrict__ mask,
                                const unsigned* __restrict__ rowAny,
                                const unsigned* __restrict__ svalid,
                                unsigned long long* __restrict__ keepW){
  int lane = threadIdx.x;  // 64 threads
  unsigned long long rem0 = 0ull, rem1 = 0ull;
  for (int w = 0; w < NW; ++w){
    int e = w * 64 + lane;
    unsigned v = (e < NTOT) ? svalid[e] : 0u;
    unsigned long long bal = __ballot(v == 0u);   // invalid/out-of-range = pre-suppressed
    if (w == lane) rem0 = bal;
    if (w == 64 + lane) rem1 = bal;
  }
  for (int c = 0; c < NW; ++c){
    int row = c * 64 + lane;
    unsigned long long D = 0ull;
    unsigned any = 0u;
    if (row < NTOT){
      D = mask[(size_t)row * NW + c];   // diagonal word (intra-chunk bits, all > own pos)
      any = rowAny[row];
    }
    unsigned long long a0 = __shfl(rem0, c & 63);
    unsigned long long a1 = __shfl(rem1, c & 63);
    unsigned long long rem = (c < 64) ? a0 : a1;
    // serial resolve only over rows with intra-chunk suppression bits (usually none)
    unsigned long long nz = __ballot(D != 0ull);
    while (nz){
      int b = __builtin_ctzll(nz);
      nz &= nz - 1;
      unsigned long long Db = __shfl(D, b);       // uniform path: all lanes execute
      if (!((rem >> b) & 1ull)) rem |= Db;
    }
    unsigned long long kp = ~rem;
    if (c < 64){ if (lane == c) rem0 = rem; }
    else       { if (lane == c - 64) rem1 = rem; }
    if (lane == 0) keepW[c] = kp;
    // OR kept rows (that suppress anything) into the running removed words
    unsigned long long act = kp & __ballot(any != 0u);
    while (act){
      int b = __builtin_ctzll(act);
      act &= act - 1;
      int r2 = c * 64 + b;
      rem0 |= mask[(size_t)r2 * NW + lane];
      if (lane < NW - 64) rem1 |= mask[(size_t)r2 * NW + 64 + lane];
    }
  }
}

__device__ __forceinline__ float read_dim(const int* p){
  int iv = p[0];
  if (iv > 0 && iv < (1 << 24)) return (float)iv;   // stored as int
  return __int_as_float(iv);                        // stored as float bits
}

__global__ void output_kernel(const float* __restrict__ sscore, const int* __restrict__ slabel,
                              const float* __restrict__ sbox, const unsigned long long* __restrict__ keepW,
                              const int* __restrict__ imw, const int* __restrict__ imh,
                              float* __restrict__ out){
  int r = blockIdx.x * blockDim.x + threadIdx.x;
  if (r >= NTOT) return;
  float wv = read_dim(imw), hv = read_dim(imh);
  float sw = (float)(1.0 / (double)wv);   // match python 1.0/img_w (double) -> f32
  float sh = (float)(1.0 / (double)hv);
  float b0 = sbox[r * 4 + 0] * sw, b1 = sbox[r * 4 + 1] * sh;
  float b2 = sbox[r * 4 + 2] * sw, b3 = sbox[r * 4 + 3] * sh;
  out[r * 4 + 0] = fminf(fmaxf(b0, 0.0f), 1.0f);
  out[r * 4 + 1] = fminf(fmaxf(b1, 0.0f), 1.0f);
  out[r * 4 + 2] = fminf(fmaxf(b2, 0.0f), 1.0f);
  out[r * 4 + 3] = fminf(fmaxf(b3, 0.0f), 1.0f);
  out[NTOT * 4 + r] = sscore[r];
  out[NTOT * 5 + r] = (float)slabel[r];
  out[NTOT * 6 + r] = ((keepW[r >> 6] >> (r & 63)) & 1ull) ? 1.0f : 0.0f;
}

// ---- workspace layout (bytes) ----
#define WS_HIST     0u         // 3*2048*4 = 24576
#define WS_TVAL     24576u     // 16
#define WS_CANDCNT  24592u     // 16
#define WS_ROWANY   24608u     // 22400  -> zero region [24592, 47008)
#define WS_CAND     47008u     // 3*8192*8 = 196608
#define WS_CKEY     243616u    // 22400
#define WS_CSCORE   266016u    // 22400
#define WS_CLABEL   288416u    // 22400
#define WS_CBOX     310816u    // 89600
#define WS_CVALID   400416u    // 22400
#define WS_SSCORE   422816u    // 22400
#define WS_SLABEL   445216u    // 22400
#define WS_SBOX     467616u    // 89600
#define WS_SOFF     557216u    // 89600
#define WS_SVALID   646816u    // 22400
#define WS_KEEPW    669216u    // 704
#define WS_MASK     669920u    // 5600*88*8 = 3942400 -> end 4612320
#define WS_BLOCKHIST WS_MASK   // reuse: 128*3*2048*4 = 3145728 <= 3942400, dead before nms_mask

extern "C" void kernel_launch(void* const* d_in, const int* in_sizes, int n_in,
                              void* d_out, int out_size, void* d_ws, size_t ws_size,
                              hipStream_t stream) {
  (void)in_sizes; (void)n_in; (void)out_size; (void)ws_size;
  const float* cls0 = (const float*)d_in[0];
  const float* box0 = (const float*)d_in[1];
  const float* cls1 = (const float*)d_in[2];
  const float* box1 = (const float*)d_in[3];
  const float* cls2 = (const float*)d_in[4];
  const float* box2 = (const float*)d_in[5];
  const int* imw = (const int*)d_in[6];
  const int* imh = (const int*)d_in[7];
  char* w = (char*)d_ws;
  unsigned* hist      = (unsigned*)(w + WS_HIST);
  unsigned* tval      = (unsigned*)(w + WS_TVAL);
  unsigned* candCnt   = (unsigned*)(w + WS_CANDCNT);
  unsigned* rowAny    = (unsigned*)(w + WS_ROWANY);
  unsigned long long* cand = (unsigned long long*)(w + WS_CAND);
  unsigned* ckey   = (unsigned*)(w + WS_CKEY);
  float* cscore    = (float*)(w + WS_CSCORE);
  int* clabel      = (int*)(w + WS_CLABEL);
  float* cbox      = (float*)(w + WS_CBOX);
  unsigned* cvalid = (unsigned*)(w + WS_CVALID);
  float* sscore    = (float*)(w + WS_SSCORE);
  int* slabel      = (int*)(w + WS_SLABEL);
  float* sbox      = (float*)(w + WS_SBOX);
  float* soff      = (float*)(w + WS_SOFF);
  unsigned* svalid = (unsigned*)(w + WS_SVALID);
  unsigned long long* keepW = (unsigned long long*)(w + WS_KEEPW);
  unsigned long long* mask  = (unsigned long long*)(w + WS_MASK);
  unsigned* blockHist = (unsigned*)(w + WS_BLOCKHIST);

  hipMemsetAsync(w + WS_CANDCNT, 0, 16u + 22400u, stream);  // candCnt + rowAny
  hist_blocks<<<HB, 256, 0, stream>>>(cls0, cls1, cls2, blockHist);
  reduce_hist<<<24, 256, 0, stream>>>(blockHist, hist);
  thresh_kernel<<<1, 192, 0, stream>>>(hist, tval);
  compact_kernel<<<HB, 256, 0, stream>>>(cls0, cls1, cls2, tval, candCnt, cand);
  level_sort_kernel<<<3, 1024, 65536, stream>>>(box0, box1, box2, candCnt, cand,
                                                ckey, cscore, clabel, cbox, cvalid);
  global_sort_kernel<<<1, 1024, 65536, stream>>>(ckey, cscore, clabel, cbox, cvalid,
                                                 sscore, slabel, sbox, soff, svalid);
  nms_mask_kernel<<<dim3(88, 88), 64, 0, stream>>>(soff, slabel, rowAny, mask);
  nms_scan_kernel<<<1, 64, 0, stream>>>(mask, rowAny, svalid, keepW);
  output_kernel<<<22, 256, 0, stream>>>(sscore, slabel, sbox, keepW, imw, imh, (float*)d_out);
}

// Round 3
// 444.257 us; speedup vs baseline: 3.8257x; 1.0633x over previous
//
#include <hip/hip_runtime.h>
#include <math.h>

// ---- problem constants ----
#define L0T 2048000   // 160*160*80
#define L1T 512000    // 80*80*80
#define L2T 128000    // 40*40*80
#define LTOT 2688000
#define NTOT 5600     // 2000+2000+1600
#define NW 88         // ceil(5600/64)
#define NCB 2048      // coarse buckets = key >> 21
#define HB 128        // histogram/compact block count
#define LB 16         // rank blocks per level
#define CANDCAP 8192

// monotone order-preserving key for f32
__device__ __forceinline__ unsigned mkey(float f){
  unsigned u = __float_as_uint(f);
  return u ^ ((unsigned)(((int)u) >> 31) | 0x80000000u);
}

// per-block LDS histogram, no global atomics
__global__ __launch_bounds__(256) void hist_blocks(const float* __restrict__ c0,
                                                   const float* __restrict__ c1,
                                                   const float* __restrict__ c2,
                                                   unsigned* __restrict__ blockHist){
  __shared__ unsigned lh[3 * NCB];
  for (int i = threadIdx.x; i < 3 * NCB; i += 256) lh[i] = 0;
  __syncthreads();
  int g = blockIdx.x * 256 + threadIdx.x;
  const int Q = LTOT / 4;
  for (int q = g; q < Q; q += HB * 256){
    int e = q * 4;
    int lvl, idx; const float* p;
    if (e < L0T){ lvl = 0; idx = e; p = c0; }
    else if (e < L0T + L1T){ lvl = 1; idx = e - L0T; p = c1; }
    else { lvl = 2; idx = e - (L0T + L1T); p = c2; }
    float4 v = *(const float4*)(p + idx);
    unsigned* h = lh + lvl * NCB;
    atomicAdd(&h[mkey(v.x) >> 21], 1u);
    atomicAdd(&h[mkey(v.y) >> 21], 1u);
    atomicAdd(&h[mkey(v.z) >> 21], 1u);
    atomicAdd(&h[mkey(v.w) >> 21], 1u);
  }
  __syncthreads();
  unsigned* out = blockHist + (size_t)blockIdx.x * 3 * NCB;
  for (int i = threadIdx.x; i < 3 * NCB; i += 256) out[i] = lh[i];
}

// one block per level: reduce per-block histograms, then suffix-scan for threshold
__global__ __launch_bounds__(256) void reduce_thresh_kernel(const unsigned* __restrict__ blockHist,
                                                            unsigned* __restrict__ T){
  __shared__ unsigned h[NCB];
  int lvl = blockIdx.x;
  for (int c = threadIdx.x; c < NCB; c += 256){
    unsigned s = 0;
    const unsigned* p = blockHist + lvl * NCB + c;
#pragma unroll 8
    for (int b = 0; b < HB; ++b) s += p[(size_t)b * 3 * NCB];
    h[c] = s;
  }
  __syncthreads();
  if (threadIdx.x < 64){
    int lane = threadIdx.x;
    unsigned K = (lvl == 2) ? 1600u : 2000u;
    unsigned p = 0;
    for (int b = lane * 32; b < lane * 32 + 32; ++b) p += h[b];
    unsigned sincl = p;                     // inclusive suffix scan across lanes
    for (int d = 1; d < 64; d <<= 1){
      unsigned t = __shfl_down(sincl, d);
      if (lane + d < 64) sincl += t;
    }
    unsigned s_after = sincl - p;
    if (s_after < K && s_after + p >= K){   // exactly one lane
      unsigned acc = s_after;
      for (int b = lane * 32 + 31; b >= lane * 32; --b){
        acc += h[b];
        if (acc >= K){ T[lvl] = (unsigned)b; break; }
      }
    }
  }
}

// two-sweep compact: per-block count -> one atomic per (block,level) -> write
__global__ __launch_bounds__(256) void compact_kernel(const float* __restrict__ c0,
                                                      const float* __restrict__ c1,
                                                      const float* __restrict__ c2,
                                                      const unsigned* __restrict__ T,
                                                      unsigned* __restrict__ candCnt,
                                                      unsigned long long* __restrict__ cand){
  __shared__ unsigned blkCnt[3], blkBase[3], blkRun[3];
  unsigned t0 = T[0], t1 = T[1], t2 = T[2];
  if (threadIdx.x < 3){ blkCnt[threadIdx.x] = 0; blkRun[threadIdx.x] = 0; }
  __syncthreads();
  int g0 = blockIdx.x * 256 + threadIdx.x;
  int lane = threadIdx.x & 63;
  for (int e = g0; e < LTOT; e += HB * 256){
    int lvl, idx; const float* p; unsigned tt;
    if (e < L0T){ lvl = 0; idx = e; p = c0; tt = t0; }
    else if (e < L0T + L1T){ lvl = 1; idx = e - L0T; p = c1; tt = t1; }
    else { lvl = 2; idx = e - (L0T + L1T); p = c2; tt = t2; }
    bool c = (mkey(p[idx]) >> 21) >= tt;
    unsigned long long bal = __ballot(c);
    if (lane == 0 && bal) atomicAdd(&blkCnt[lvl], (unsigned)__popcll(bal));
  }
  __syncthreads();
  if (threadIdx.x < 3){
    unsigned n = blkCnt[threadIdx.x];
    blkBase[threadIdx.x] = n ? atomicAdd(&candCnt[threadIdx.x], n) : 0u;
  }
  __syncthreads();
  for (int e = g0; e < LTOT; e += HB * 256){
    int lvl, idx; const float* p; unsigned tt;
    if (e < L0T){ lvl = 0; idx = e; p = c0; tt = t0; }
    else if (e < L0T + L1T){ lvl = 1; idx = e - L0T; p = c1; tt = t1; }
    else { lvl = 2; idx = e - (L0T + L1T); p = c2; tt = t2; }
    unsigned key = mkey(p[idx]);
    bool c = (key >> 21) >= tt;
    unsigned long long bal = __ballot(c);
    if (bal){
      unsigned wbase = 0;
      if (lane == 0) wbase = atomicAdd(&blkRun[lvl], (unsigned)__popcll(bal));
      wbase = __shfl(wbase, 0);
      if (c){
        unsigned pos = blkBase[lvl] + wbase + (unsigned)__popcll(bal & ((1ull << lane) - 1ull));
        if (pos < CANDCAP)
          cand[lvl * CANDCAP + pos] = ((unsigned long long)key << 32) | (unsigned)(~(unsigned)idx);
      }
    }
  }
}

// per level: parallel rank-sort (count keys greater), write top-K at exact rank
__global__ __launch_bounds__(256) void level_rank_kernel(
    const float* __restrict__ box0, const float* __restrict__ box1, const float* __restrict__ box2,
    const unsigned* __restrict__ candCnt, const unsigned long long* __restrict__ cand,
    unsigned* __restrict__ ckey, float* __restrict__ cscore, int* __restrict__ clabel,
    float* __restrict__ cbox, unsigned* __restrict__ cvalid){
  extern __shared__ unsigned long long k[];
  int lvl = blockIdx.y;
  int K = (lvl == 2) ? 1600 : 2000;
  int base = lvl * 2000;
  const float* bx = (lvl == 0) ? box0 : ((lvl == 1) ? box1 : box2);
  unsigned cnt = candCnt[lvl]; if (cnt > CANDCAP) cnt = CANDCAP;
  for (unsigned i = threadIdx.x; i < cnt; i += 256) k[i] = cand[lvl * CANDCAP + i];
  __syncthreads();
  for (unsigned i = blockIdx.x * 256 + threadIdx.x; i < cnt; i += LB * 256){
    unsigned long long ki = k[i];
    int r = 0;
#pragma unroll 4
    for (unsigned j = 0; j < cnt; ++j) r += (k[j] > ki) ? 1 : 0;
    if (r < K){
      unsigned key = (unsigned)(ki >> 32);
      unsigned idx = ~(unsigned)ki;
      int anchor = (int)(idx / 80u);
      int lbl = (int)(idx % 80u);
      unsigned fb = (key & 0x80000000u) ? (key ^ 0x80000000u) : ~key;
      float logit = __uint_as_float(fb);
      float sc = 1.0f / (1.0f + expf(-logit));
      int pos = base + r;
      ckey[pos] = key;
      cscore[pos] = sc;
      clabel[pos] = lbl;
      cvalid[pos] = (sc > 0.05f) ? 1u : 0u;
      float4 b = *(const float4*)(bx + (size_t)anchor * 4);
      *(float4*)(cbox + pos * 4) = b;
    }
  }
}

// global stable rank-sort by (valid?key:0 desc, concat-pos asc)
__global__ __launch_bounds__(256) void global_rank_kernel(
    const unsigned* __restrict__ ckey, const float* __restrict__ cscore,
    const int* __restrict__ clabel, const float* __restrict__ cbox,
    const unsigned* __restrict__ cvalid,
    float* __restrict__ sscore, int* __restrict__ slabel, float* __restrict__ sbox,
    float* __restrict__ soff, unsigned* __restrict__ svalid){
  extern __shared__ unsigned long long k[];
  for (int i = threadIdx.x; i < NTOT; i += 256){
    unsigned eff = cvalid[i] ? ckey[i] : 0u;
    k[i] = ((unsigned long long)eff << 32) | (unsigned)(~(unsigned)i);
  }
  __syncthreads();
  int i = blockIdx.x * 256 + threadIdx.x;
  if (i >= NTOT) return;
  unsigned long long ki = k[i];
  int r = 0;
#pragma unroll 4
  for (int j = 0; j < NTOT; ++j) r += (k[j] > ki) ? 1 : 0;
  int lbl = clabel[i];
  float off = (float)lbl * 10000.0f;
  sscore[r] = cscore[i];
  slabel[r] = lbl;
  svalid[r] = cvalid[i];
  float4 b = *(const float4*)(cbox + (size_t)i * 4);
  *(float4*)(sbox + (size_t)r * 4) = b;
  float4 bo; bo.x = b.x + off; bo.y = b.y + off; bo.z = b.z + off; bo.w = b.w + off;
  *(float4*)(soff + (size_t)r * 4) = bo;
}

// suppression bitmask: mask[i][wj] bit jj = (j>i && iou(i,j)>0.6) with offset boxes
__global__ void nms_mask_kernel(const float* __restrict__ soff, const int* __restrict__ slabel,
                                unsigned* __restrict__ rowAny, unsigned long long* __restrict__ mask){
  __shared__ float cb[64][4];
  __shared__ float ca[64];
  __shared__ int cl[64];
  int wi = blockIdx.x, wj = blockIdx.y;
  int t = threadIdx.x;
  int i = wi * 64 + t;
  if (wj < wi){                      // all j < i: word is zero, but must be initialized
    if (i < NTOT) mask[(size_t)i * NW + wj] = 0ull;
    return;
  }
  int j0 = wj * 64;
  int j = j0 + t;
  if (j < NTOT){
    float x1 = soff[j * 4 + 0], y1 = soff[j * 4 + 1];
    float x2 = soff[j * 4 + 2], y2 = soff[j * 4 + 3];
    cb[t][0] = x1; cb[t][1] = y1; cb[t][2] = x2; cb[t][3] = y2;
    {
#pragma clang fp contract(off)
      ca[t] = fmaxf(x2 - x1, 0.0f) * fmaxf(y2 - y1, 0.0f);
    }
    cl[t] = slabel[j];
  } else {
    cl[t] = -1;
  }
  __syncthreads();
  if (i >= NTOT) return;
  float ax1 = soff[i * 4 + 0], ay1 = soff[i * 4 + 1];
  float ax2 = soff[i * 4 + 2], ay2 = soff[i * 4 + 3];
  int li = slabel[i];
  float areaA;
  {
#pragma clang fp contract(off)
    areaA = fmaxf(ax2 - ax1, 0.0f) * fmaxf(ay2 - ay1, 0.0f);
  }
  unsigned long long w = 0ull;
  for (int jj = 0; jj < 64; ++jj){
    int jg = j0 + jj;
    if (jg >= NTOT) break;
    if (jg <= i) continue;
    if (cl[jj] != li) continue;
    {
#pragma clang fp contract(off)
      float ltx = fmaxf(ax1, cb[jj][0]);
      float lty = fmaxf(ay1, cb[jj][1]);
      float rbx = fminf(ax2, cb[jj][2]);
      float rby = fminf(ay2, cb[jj][3]);
      float ww = fmaxf(rbx - ltx, 0.0f);
      float hh = fmaxf(rby - lty, 0.0f);
      float inter = ww * hh;
      float uni = (areaA + ca[jj]) - inter;
      float iou = inter / fmaxf(uni, 1e-9f);
      if (iou > 0.6f) w |= (1ull << jj);
    }
  }
  mask[(size_t)i * NW + wj] = w;
  if (w) rowAny[i] = 1u;
}

// single-wave sequential greedy scan; removed bits live in registers (word w: lane w / lane w-64)
__global__ void nms_scan_kernel(const unsigned long long* __restrict__ mask,
                                const unsigned* __restrict__ rowAny,
                                const unsigned* __restrict__ svalid,
                                unsigned long long* __restrict__ keepW){
  int lane = threadIdx.x;  // 64 threads
  unsigned long long rem0 = 0ull, rem1 = 0ull;
  for (int w = 0; w < NW; ++w){
    int e = w * 64 + lane;
    unsigned v = (e < NTOT) ? svalid[e] : 0u;
    unsigned long long bal = __ballot(v == 0u);   // invalid/out-of-range = pre-suppressed
    if (w == lane) rem0 = bal;
    if (w == 64 + lane) rem1 = bal;
  }
  for (int c = 0; c < NW; ++c){
    int row = c * 64 + lane;
    unsigned long long D = 0ull;
    unsigned any = 0u;
    if (row < NTOT){
      D = mask[(size_t)row * NW + c];   // diagonal word (intra-chunk bits, all > own pos)
      any = rowAny[row];
    }
    unsigned long long a0 = __shfl(rem0, c & 63);
    unsigned long long a1 = __shfl(rem1, c & 63);
    unsigned long long rem = (c < 64) ? a0 : a1;
    // serial resolve only over rows with intra-chunk suppression bits (usually none)
    unsigned long long nz = __ballot(D != 0ull);
    while (nz){
      int b = __builtin_ctzll(nz);
      nz &= nz - 1;
      unsigned long long Db = __shfl(D, b);       // uniform path: all lanes execute
      if (!((rem >> b) & 1ull)) rem |= Db;
    }
    unsigned long long kp = ~rem;
    if (c < 64){ if (lane == c) rem0 = rem; }
    else       { if (lane == c - 64) rem1 = rem; }
    if (lane == 0) keepW[c] = kp;
    // OR kept rows (that suppress anything) into the running removed words
    unsigned long long act = kp & __ballot(any != 0u);
    while (act){
      int b = __builtin_ctzll(act);
      act &= act - 1;
      int r2 = c * 64 + b;
      rem0 |= mask[(size_t)r2 * NW + lane];
      if (lane < NW - 64) rem1 |= mask[(size_t)r2 * NW + 64 + lane];
    }
  }
}

__device__ __forceinline__ float read_dim(const int* p){
  int iv = p[0];
  if (iv > 0 && iv < (1 << 24)) return (float)iv;   // stored as int
  return __int_as_float(iv);                        // stored as float bits
}

__global__ void output_kernel(const float* __restrict__ sscore, const int* __restrict__ slabel,
                              const float* __restrict__ sbox, const unsigned long long* __restrict__ keepW,
                              const int* __restrict__ imw, const int* __restrict__ imh,
                              float* __restrict__ out){
  int r = blockIdx.x * blockDim.x + threadIdx.x;
  if (r >= NTOT) return;
  float wv = read_dim(imw), hv = read_dim(imh);
  float sw = (float)(1.0 / (double)wv);   // match python 1.0/img_w (double) -> f32
  float sh = (float)(1.0 / (double)hv);
  float b0 = sbox[r * 4 + 0] * sw, b1 = sbox[r * 4 + 1] * sh;
  float b2 = sbox[r * 4 + 2] * sw, b3 = sbox[r * 4 + 3] * sh;
  out[r * 4 + 0] = fminf(fmaxf(b0, 0.0f), 1.0f);
  out[r * 4 + 1] = fminf(fmaxf(b1, 0.0f), 1.0f);
  out[r * 4 + 2] = fminf(fmaxf(b2, 0.0f), 1.0f);
  out[r * 4 + 3] = fminf(fmaxf(b3, 0.0f), 1.0f);
  out[NTOT * 4 + r] = sscore[r];
  out[NTOT * 5 + r] = (float)slabel[r];
  out[NTOT * 6 + r] = ((keepW[r >> 6] >> (r & 63)) & 1ull) ? 1.0f : 0.0f;
}

// ---- workspace layout (bytes) ----
#define WS_TVAL     0u         // 16
#define WS_CANDCNT  16u        // 16
#define WS_ROWANY   32u        // 22400  -> zero region [16, 22432)
#define WS_CAND     22432u     // 3*8192*8 = 196608
#define WS_CKEY     219040u    // 22400
#define WS_CSCORE   241440u    // 22400
#define WS_CLABEL   263840u    // 22400
#define WS_CBOX     286240u    // 89600   (286240 % 16 == 0)
#define WS_CVALID   375840u    // 22400
#define WS_SSCORE   398240u    // 22400
#define WS_SLABEL   420640u    // 22400
#define WS_SBOX     443040u    // 89600   (443040 % 16 == 0)
#define WS_SOFF     532640u    // 89600   (532640 % 16 == 0)
#define WS_SVALID   622240u    // 22400
#define WS_KEEPW    644640u    // 704
#define WS_MASK     645344u    // 5600*88*8 = 3942400 -> end 4587744
#define WS_BLOCKHIST WS_MASK   // reuse: 128*3*2048*4 = 3145728 <= 3942400, dead before nms_mask

extern "C" void kernel_launch(void* const* d_in, const int* in_sizes, int n_in,
                              void* d_out, int out_size, void* d_ws, size_t ws_size,
                              hipStream_t stream) {
  (void)in_sizes; (void)n_in; (void)out_size; (void)ws_size;
  const float* cls0 = (const float*)d_in[0];
  const float* box0 = (const float*)d_in[1];
  const float* cls1 = (const float*)d_in[2];
  const float* box1 = (const float*)d_in[3];
  const float* cls2 = (const float*)d_in[4];
  const float* box2 = (const float*)d_in[5];
  const int* imw = (const int*)d_in[6];
  const int* imh = (const int*)d_in[7];
  char* w = (char*)d_ws;
  unsigned* tval      = (unsigned*)(w + WS_TVAL);
  unsigned* candCnt   = (unsigned*)(w + WS_CANDCNT);
  unsigned* rowAny    = (unsigned*)(w + WS_ROWANY);
  unsigned long long* cand = (unsigned long long*)(w + WS_CAND);
  unsigned* ckey   = (unsigned*)(w + WS_CKEY);
  float* cscore    = (float*)(w + WS_CSCORE);
  int* clabel      = (int*)(w + WS_CLABEL);
  float* cbox      = (float*)(w + WS_CBOX);
  unsigned* cvalid = (unsigned*)(w + WS_CVALID);
  float* sscore    = (float*)(w + WS_SSCORE);
  int* slabel      = (int*)(w + WS_SLABEL);
  float* sbox      = (float*)(w + WS_SBOX);
  float* soff      = (float*)(w + WS_SOFF);
  unsigned* svalid = (unsigned*)(w + WS_SVALID);
  unsigned long long* keepW = (unsigned long long*)(w + WS_KEEPW);
  unsigned long long* mask  = (unsigned long long*)(w + WS_MASK);
  unsigned* blockHist = (unsigned*)(w + WS_BLOCKHIST);

  hipMemsetAsync(w + WS_CANDCNT, 0, 16u + 22400u, stream);  // candCnt + rowAny
  hist_blocks<<<HB, 256, 0, stream>>>(cls0, cls1, cls2, blockHist);
  reduce_thresh_kernel<<<3, 256, 0, stream>>>(blockHist, tval);
  compact_kernel<<<HB, 256, 0, stream>>>(cls0, cls1, cls2, tval, candCnt, cand);
  level_rank_kernel<<<dim3(LB, 3), 256, CANDCAP * 8, stream>>>(box0, box1, box2, candCnt, cand,
                                                               ckey, cscore, clabel, cbox, cvalid);
  global_rank_kernel<<<22, 256, NTOT * 8, stream>>>(ckey, cscore, clabel, cbox, cvalid,
                                                    sscore, slabel, sbox, soff, svalid);
  nms_mask_kernel<<<dim3(88, 88), 64, 0, stream>>>(soff, slabel, rowAny, mask);
  nms_scan_kernel<<<1, 64, 0, stream>>>(mask, rowAny, svalid, keepW);
  output_kernel<<<22, 256, 0, stream>>>(sscore, slabel, sbox, keepW, imw, imh, (float*)d_out);
}

// Round 4
// 437.542 us; speedup vs baseline: 3.8844x; 1.0153x over previous
//
#include <hip/hip_runtime.h>
#include <math.h>

// ---- problem constants ----
#define L0T 2048000   // 160*160*80
#define L1T 512000    // 80*80*80
#define L2T 128000    // 40*40*80
#define LTOT 2688000
#define NTOT 5600     // 2000+2000+1600
#define NW 88         // ceil(5600/64)
#define NCB 2048      // coarse buckets = key >> 21
#define HB 128        // histogram/compact block count
#define GRB 88        // global-rank blocks (352 waves)
#define LRB 32        // level-rank blocks per level (128 waves/level)
#define CANDCAP 8192

// monotone order-preserving key for f32
__device__ __forceinline__ unsigned mkey(float f){
  unsigned u = __float_as_uint(f);
  return u ^ ((unsigned)(((int)u) >> 31) | 0x80000000u);
}

// per-block LDS histogram, no global atomics
__global__ __launch_bounds__(256) void hist_blocks(const float* __restrict__ c0,
                                                   const float* __restrict__ c1,
                                                   const float* __restrict__ c2,
                                                   unsigned* __restrict__ blockHist){
  __shared__ unsigned lh[3 * NCB];
  for (int i = threadIdx.x; i < 3 * NCB; i += 256) lh[i] = 0;
  __syncthreads();
  int g = blockIdx.x * 256 + threadIdx.x;
  const int Q = LTOT / 4;
  for (int q = g; q < Q; q += HB * 256){
    int e = q * 4;
    int lvl, idx; const float* p;
    if (e < L0T){ lvl = 0; idx = e; p = c0; }
    else if (e < L0T + L1T){ lvl = 1; idx = e - L0T; p = c1; }
    else { lvl = 2; idx = e - (L0T + L1T); p = c2; }
    float4 v = *(const float4*)(p + idx);
    unsigned* h = lh + lvl * NCB;
    atomicAdd(&h[mkey(v.x) >> 21], 1u);
    atomicAdd(&h[mkey(v.y) >> 21], 1u);
    atomicAdd(&h[mkey(v.z) >> 21], 1u);
    atomicAdd(&h[mkey(v.w) >> 21], 1u);
  }
  __syncthreads();
  unsigned* out = blockHist + (size_t)blockIdx.x * 3 * NCB;
  for (int i = threadIdx.x; i < 3 * NCB; i += 256) out[i] = lh[i];
}

// one block per level: reduce per-block histograms, then suffix-scan for threshold
__global__ __launch_bounds__(256) void reduce_thresh_kernel(const unsigned* __restrict__ blockHist,
                                                            unsigned* __restrict__ T){
  __shared__ unsigned h[NCB];
  int lvl = blockIdx.x;
  for (int c = threadIdx.x; c < NCB; c += 256){
    unsigned s = 0;
    const unsigned* p = blockHist + lvl * NCB + c;
#pragma unroll 8
    for (int b = 0; b < HB; ++b) s += p[(size_t)b * 3 * NCB];
    h[c] = s;
  }
  __syncthreads();
  if (threadIdx.x < 64){
    int lane = threadIdx.x;
    unsigned K = (lvl == 2) ? 1600u : 2000u;
    unsigned p = 0;
    for (int b = lane * 32; b < lane * 32 + 32; ++b) p += h[b];
    unsigned sincl = p;                     // inclusive suffix scan across lanes
    for (int d = 1; d < 64; d <<= 1){
      unsigned t = __shfl_down(sincl, d);
      if (lane + d < 64) sincl += t;
    }
    unsigned s_after = sincl - p;
    if (s_after < K && s_after + p >= K){   // exactly one lane
      unsigned acc = s_after;
      for (int b = lane * 32 + 31; b >= lane * 32; --b){
        acc += h[b];
        if (acc >= K){ T[lvl] = (unsigned)b; break; }
      }
    }
  }
}

// two-sweep compact: per-block count -> one atomic per (block,level) -> write
__global__ __launch_bounds__(256) void compact_kernel(const float* __restrict__ c0,
                                                      const float* __restrict__ c1,
                                                      const float* __restrict__ c2,
                                                      const unsigned* __restrict__ T,
                                                      unsigned* __restrict__ candCnt,
                                                      unsigned long long* __restrict__ cand){
  __shared__ unsigned blkCnt[3], blkBase[3], blkRun[3];
  unsigned t0 = T[0], t1 = T[1], t2 = T[2];
  if (threadIdx.x < 3){ blkCnt[threadIdx.x] = 0; blkRun[threadIdx.x] = 0; }
  __syncthreads();
  int g0 = blockIdx.x * 256 + threadIdx.x;
  int lane = threadIdx.x & 63;
  for (int e = g0; e < LTOT; e += HB * 256){
    int lvl, idx; const float* p; unsigned tt;
    if (e < L0T){ lvl = 0; idx = e; p = c0; tt = t0; }
    else if (e < L0T + L1T){ lvl = 1; idx = e - L0T; p = c1; tt = t1; }
    else { lvl = 2; idx = e - (L0T + L1T); p = c2; tt = t2; }
    bool c = (mkey(p[idx]) >> 21) >= tt;
    unsigned long long bal = __ballot(c);
    if (lane == 0 && bal) atomicAdd(&blkCnt[lvl], (unsigned)__popcll(bal));
  }
  __syncthreads();
  if (threadIdx.x < 3){
    unsigned n = blkCnt[threadIdx.x];
    blkBase[threadIdx.x] = n ? atomicAdd(&candCnt[threadIdx.x], n) : 0u;
  }
  __syncthreads();
  for (int e = g0; e < LTOT; e += HB * 256){
    int lvl, idx; const float* p; unsigned tt;
    if (e < L0T){ lvl = 0; idx = e; p = c0; tt = t0; }
    else if (e < L0T + L1T){ lvl = 1; idx = e - L0T; p = c1; tt = t1; }
    else { lvl = 2; idx = e - (L0T + L1T); p = c2; tt = t2; }
    unsigned key = mkey(p[idx]);
    bool c = (key >> 21) >= tt;
    unsigned long long bal = __ballot(c);
    if (bal){
      unsigned wbase = 0;
      if (lane == 0) wbase = atomicAdd(&blkRun[lvl], (unsigned)__popcll(bal));
      wbase = __shfl(wbase, 0);
      if (c){
        unsigned pos = blkBase[lvl] + wbase + (unsigned)__popcll(bal & ((1ull << lane) - 1ull));
        if (pos < CANDCAP)
          cand[lvl * CANDCAP + pos] = ((unsigned long long)key << 32) | (unsigned)(~(unsigned)idx);
      }
    }
  }
}

// per level: wave-ballot rank-sort — wave handles item i, 64 lanes split the j sweep
__global__ __launch_bounds__(256) void level_rank_kernel(
    const float* __restrict__ box0, const float* __restrict__ box1, const float* __restrict__ box2,
    const unsigned* __restrict__ candCnt, const unsigned long long* __restrict__ cand,
    unsigned* __restrict__ ckey, float* __restrict__ cscore, int* __restrict__ clabel,
    float* __restrict__ cbox, unsigned* __restrict__ cvalid){
  extern __shared__ unsigned long long k[];
  int lvl = blockIdx.y;
  int K = (lvl == 2) ? 1600 : 2000;
  int base = lvl * 2000;
  const float* bx = (lvl == 0) ? box0 : ((lvl == 1) ? box1 : box2);
  unsigned cnt = candCnt[lvl]; if (cnt > CANDCAP) cnt = CANDCAP;
  for (unsigned i = threadIdx.x; i < cnt; i += 256) k[i] = cand[lvl * CANDCAP + i];
  __syncthreads();
  int lane = threadIdx.x & 63;
  int wid = (blockIdx.x << 2) | (threadIdx.x >> 6);   // wave id within level
  const int NWAVES = LRB * 4;
  int njb = ((int)cnt + 63) >> 6;
  for (int i = wid; i < (int)cnt; i += NWAVES){
    unsigned long long ki = k[i];
    int r = 0;
    for (int jb = 0; jb < njb; ++jb){
      int j = (jb << 6) + lane;
      bool pred = (j < (int)cnt) && (k[j] > ki);
      r += __popcll(__ballot(pred));
    }
    if (r < K && lane == 0){
      unsigned key = (unsigned)(ki >> 32);
      unsigned idx = ~(unsigned)ki;
      int anchor = (int)(idx / 80u);
      int lbl = (int)(idx % 80u);
      unsigned fb = (key & 0x80000000u) ? (key ^ 0x80000000u) : ~key;
      float logit = __uint_as_float(fb);
      float sc = 1.0f / (1.0f + expf(-logit));
      int pos = base + r;
      ckey[pos] = key;
      cscore[pos] = sc;
      clabel[pos] = lbl;
      cvalid[pos] = (sc > 0.05f) ? 1u : 0u;
      float4 b = *(const float4*)(bx + (size_t)anchor * 4);
      *(float4*)(cbox + pos * 4) = b;
    }
  }
}

// global stable rank-sort by (valid?key:0 desc, concat-pos asc), wave-ballot parallel
__global__ __launch_bounds__(256) void global_rank_kernel(
    const unsigned* __restrict__ ckey, const float* __restrict__ cscore,
    const int* __restrict__ clabel, const float* __restrict__ cbox,
    const unsigned* __restrict__ cvalid,
    float* __restrict__ sscore, int* __restrict__ slabel, float* __restrict__ sbox,
    float* __restrict__ soff, unsigned* __restrict__ svalid){
  __shared__ unsigned long long k[NTOT];
  for (int i = threadIdx.x; i < NTOT; i += 256){
    unsigned eff = cvalid[i] ? ckey[i] : 0u;
    k[i] = ((unsigned long long)eff << 32) | (unsigned)(~(unsigned)i);
  }
  __syncthreads();
  int lane = threadIdx.x & 63;
  int wid = (blockIdx.x << 2) | (threadIdx.x >> 6);
  const int NWAVES = GRB * 4;
  for (int i = wid; i < NTOT; i += NWAVES){
    unsigned long long ki = k[i];
    int r = 0;
#pragma unroll 4
    for (int jb = 0; jb < NW; ++jb){
      int j = (jb << 6) + lane;
      bool pred = (j < NTOT) && (k[j] > ki);
      r += __popcll(__ballot(pred));
    }
    if (lane == 0){
      int lbl = clabel[i];
      float off = (float)lbl * 10000.0f;
      sscore[r] = cscore[i];
      slabel[r] = lbl;
      svalid[r] = cvalid[i];
      float4 b = *(const float4*)(cbox + (size_t)i * 4);
      *(float4*)(sbox + (size_t)r * 4) = b;
      float4 bo; bo.x = b.x + off; bo.y = b.y + off; bo.z = b.z + off; bo.w = b.w + off;
      *(float4*)(soff + (size_t)r * 4) = bo;
    }
  }
}

// suppression bitmask: mask[i][wj] bit jj = (j>i && iou(i,j)>0.6) with offset boxes
__global__ void nms_mask_kernel(const float* __restrict__ soff, const int* __restrict__ slabel,
                                unsigned* __restrict__ rowAny, unsigned long long* __restrict__ mask){
  __shared__ float cb[64][4];
  __shared__ float ca[64];
  __shared__ int cl[64];
  int wi = blockIdx.x, wj = blockIdx.y;
  int t = threadIdx.x;
  int i = wi * 64 + t;
  if (wj < wi){                      // all j < i: word is zero, but must be initialized
    if (i < NTOT) mask[(size_t)i * NW + wj] = 0ull;
    return;
  }
  int j0 = wj * 64;
  int j = j0 + t;
  if (j < NTOT){
    float x1 = soff[j * 4 + 0], y1 = soff[j * 4 + 1];
    float x2 = soff[j * 4 + 2], y2 = soff[j * 4 + 3];
    cb[t][0] = x1; cb[t][1] = y1; cb[t][2] = x2; cb[t][3] = y2;
    {
#pragma clang fp contract(off)
      ca[t] = fmaxf(x2 - x1, 0.0f) * fmaxf(y2 - y1, 0.0f);
    }
    cl[t] = slabel[j];
  } else {
    cl[t] = -1;
  }
  __syncthreads();
  if (i >= NTOT) return;
  float ax1 = soff[i * 4 + 0], ay1 = soff[i * 4 + 1];
  float ax2 = soff[i * 4 + 2], ay2 = soff[i * 4 + 3];
  int li = slabel[i];
  float areaA;
  {
#pragma clang fp contract(off)
    areaA = fmaxf(ax2 - ax1, 0.0f) * fmaxf(ay2 - ay1, 0.0f);
  }
  unsigned long long w = 0ull;
  for (int jj = 0; jj < 64; ++jj){
    int jg = j0 + jj;
    if (jg >= NTOT) break;
    if (jg <= i) continue;
    if (cl[jj] != li) continue;
    {
#pragma clang fp contract(off)
      float ltx = fmaxf(ax1, cb[jj][0]);
      float lty = fmaxf(ay1, cb[jj][1]);
      float rbx = fminf(ax2, cb[jj][2]);
      float rby = fminf(ay2, cb[jj][3]);
      float ww = fmaxf(rbx - ltx, 0.0f);
      float hh = fmaxf(rby - lty, 0.0f);
      float inter = ww * hh;
      float uni = (areaA + ca[jj]) - inter;
      float iou = inter / fmaxf(uni, 1e-9f);
      if (iou > 0.6f) w |= (1ull << jj);
    }
  }
  mask[(size_t)i * NW + wj] = w;
  if (w) rowAny[i] = 1u;
}

// single-wave sequential greedy scan; removed bits live in registers (word w: lane w / lane w-64)
__global__ void nms_scan_kernel(const unsigned long long* __restrict__ mask,
                                const unsigned* __restrict__ rowAny,
                                const unsigned* __restrict__ svalid,
                                unsigned long long* __restrict__ keepW){
  int lane = threadIdx.x;  // 64 threads
  unsigned long long rem0 = 0ull, rem1 = 0ull;
  for (int w = 0; w < NW; ++w){
    int e = w * 64 + lane;
    unsigned v = (e < NTOT) ? svalid[e] : 0u;
    unsigned long long bal = __ballot(v == 0u);   // invalid/out-of-range = pre-suppressed
    if (w == lane) rem0 = bal;
    if (w == 64 + lane) rem1 = bal;
  }
  for (int c = 0; c < NW; ++c){
    int row = c * 64 + lane;
    unsigned long long D = 0ull;
    unsigned any = 0u;
    if (row < NTOT){
      D = mask[(size_t)row * NW + c];   // diagonal word (intra-chunk bits, all > own pos)
      any = rowAny[row];
    }
    unsigned long long a0 = __shfl(rem0, c & 63);
    unsigned long long a1 = __shfl(rem1, c & 63);
    unsigned long long rem = (c < 64) ? a0 : a1;
    // serial resolve only over rows with intra-chunk suppression bits (usually none)
    unsigned long long nz = __ballot(D != 0ull);
    while (nz){
      int b = __builtin_ctzll(nz);
      nz &= nz - 1;
      unsigned long long Db = __shfl(D, b);       // uniform path: all lanes execute
      if (!((rem >> b) & 1ull)) rem |= Db;
    }
    unsigned long long kp = ~rem;
    if (c < 64){ if (lane == c) rem0 = rem; }
    else       { if (lane == c - 64) rem1 = rem; }
    if (lane == 0) keepW[c] = kp;
    // OR kept rows (that suppress anything) into the running removed words
    unsigned long long act = kp & __ballot(any != 0u);
    while (act){
      int b = __builtin_ctzll(act);
      act &= act - 1;
      int r2 = c * 64 + b;
      rem0 |= mask[(size_t)r2 * NW + lane];
      if (lane < NW - 64) rem1 |= mask[(size_t)r2 * NW + 64 + lane];
    }
  }
}

__device__ __forceinline__ float read_dim(const int* p){
  int iv = p[0];
  if (iv > 0 && iv < (1 << 24)) return (float)iv;   // stored as int
  return __int_as_float(iv);                        // stored as float bits
}

__global__ void output_kernel(const float* __restrict__ sscore, const int* __restrict__ slabel,
                              const float* __restrict__ sbox, const unsigned long long* __restrict__ keepW,
                              const int* __restrict__ imw, const int* __restrict__ imh,
                              float* __restrict__ out){
  int r = blockIdx.x * blockDim.x + threadIdx.x;
  if (r >= NTOT) return;
  float wv = read_dim(imw), hv = read_dim(imh);
  float sw = (float)(1.0 / (double)wv);   // match python 1.0/img_w (double) -> f32
  float sh = (float)(1.0 / (double)hv);
  float b0 = sbox[r * 4 + 0] * sw, b1 = sbox[r * 4 + 1] * sh;
  float b2 = sbox[r * 4 + 2] * sw, b3 = sbox[r * 4 + 3] * sh;
  out[r * 4 + 0] = fminf(fmaxf(b0, 0.0f), 1.0f);
  out[r * 4 + 1] = fminf(fmaxf(b1, 0.0f), 1.0f);
  out[r * 4 + 2] = fminf(fmaxf(b2, 0.0f), 1.0f);
  out[r * 4 + 3] = fminf(fmaxf(b3, 0.0f), 1.0f);
  out[NTOT * 4 + r] = sscore[r];
  out[NTOT * 5 + r] = (float)slabel[r];
  out[NTOT * 6 + r] = ((keepW[r >> 6] >> (r & 63)) & 1ull) ? 1.0f : 0.0f;
}

// ---- workspace layout (bytes) ----
#define WS_TVAL     0u         // 16
#define WS_CANDCNT  16u        // 16
#define WS_ROWANY   32u        // 22400  -> zero region [16, 22432)
#define WS_CAND     22432u     // 3*8192*8 = 196608
#define WS_CKEY     219040u    // 22400
#define WS_CSCORE   241440u    // 22400
#define WS_CLABEL   263840u    // 22400
#define WS_CBOX     286240u    // 89600   (286240 % 16 == 0)
#define WS_CVALID   375840u    // 22400
#define WS_SSCORE   398240u    // 22400
#define WS_SLABEL   420640u    // 22400
#define WS_SBOX     443040u    // 89600   (443040 % 16 == 0)
#define WS_SOFF     532640u    // 89600   (532640 % 16 == 0)
#define WS_SVALID   622240u    // 22400
#define WS_KEEPW    644640u    // 704
#define WS_MASK     645344u    // 5600*88*8 = 3942400 -> end 4587744
#define WS_BLOCKHIST WS_MASK   // reuse: 128*3*2048*4 = 3145728 <= 3942400, dead before nms_mask

extern "C" void kernel_launch(void* const* d_in, const int* in_sizes, int n_in,
                              void* d_out, int out_size, void* d_ws, size_t ws_size,
                              hipStream_t stream) {
  (void)in_sizes; (void)n_in; (void)out_size; (void)ws_size;
  const float* cls0 = (const float*)d_in[0];
  const float* box0 = (const float*)d_in[1];
  const float* cls1 = (const float*)d_in[2];
  const float* box1 = (const float*)d_in[3];
  const float* cls2 = (const float*)d_in[4];
  const float* box2 = (const float*)d_in[5];
  const int* imw = (const int*)d_in[6];
  const int* imh = (const int*)d_in[7];
  char* w = (char*)d_ws;
  unsigned* tval      = (unsigned*)(w + WS_TVAL);
  unsigned* candCnt   = (unsigned*)(w + WS_CANDCNT);
  unsigned* rowAny    = (unsigned*)(w + WS_ROWANY);
  unsigned long long* cand = (unsigned long long*)(w + WS_CAND);
  unsigned* ckey   = (unsigned*)(w + WS_CKEY);
  float* cscore    = (float*)(w + WS_CSCORE);
  int* clabel      = (int*)(w + WS_CLABEL);
  float* cbox      = (float*)(w + WS_CBOX);
  unsigned* cvalid = (unsigned*)(w + WS_CVALID);
  float* sscore    = (float*)(w + WS_SSCORE);
  int* slabel      = (int*)(w + WS_SLABEL);
  float* sbox      = (float*)(w + WS_SBOX);
  float* soff      = (float*)(w + WS_SOFF);
  unsigned* svalid = (unsigned*)(w + WS_SVALID);
  unsigned long long* keepW = (unsigned long long*)(w + WS_KEEPW);
  unsigned long long* mask  = (unsigned long long*)(w + WS_MASK);
  unsigned* blockHist = (unsigned*)(w + WS_BLOCKHIST);

  hipMemsetAsync(w + WS_CANDCNT, 0, 16u + 22400u, stream);  // candCnt + rowAny
  hist_blocks<<<HB, 256, 0, stream>>>(cls0, cls1, cls2, blockHist);
  reduce_thresh_kernel<<<3, 256, 0, stream>>>(blockHist, tval);
  compact_kernel<<<HB, 256, 0, stream>>>(cls0, cls1, cls2, tval, candCnt, cand);
  level_rank_kernel<<<dim3(LRB, 3), 256, CANDCAP * 8, stream>>>(box0, box1, box2, candCnt, cand,
                                                                ckey, cscore, clabel, cbox, cvalid);
  global_rank_kernel<<<GRB, 256, 0, stream>>>(ckey, cscore, clabel, cbox, cvalid,
                                              sscore, slabel, sbox, soff, svalid);
  nms_mask_kernel<<<dim3(88, 88), 64, 0, stream>>>(soff, slabel, rowAny, mask);
  nms_scan_kernel<<<1, 64, 0, stream>>>(mask, rowAny, svalid, keepW);
  output_kernel<<<22, 256, 0, stream>>>(sscore, slabel, sbox, keepW, imw, imh, (float*)d_out);
}

// Round 5
// 338.183 us; speedup vs baseline: 5.0256x; 1.2938x over previous
//
#include <hip/hip_runtime.h>
#include <math.h>

// ---- problem constants ----
#define L0T 2048000   // 160*160*80
#define L1T 512000    // 80*80*80
#define L2T 128000    // 40*40*80
#define LTOT 2688000
#define NTOT 5600     // 2000+2000+1600
#define NW 88         // ceil(5600/64)
#define NCB 2048      // coarse buckets = key >> 21
#define HB 128        // histogram/compact block count
#define CANDCAP 8192

// monotone order-preserving key for f32
__device__ __forceinline__ unsigned mkey(float f){
  unsigned u = __float_as_uint(f);
  return u ^ ((unsigned)(((int)u) >> 31) | 0x80000000u);
}

// per-block LDS histogram, no global atomics
__global__ __launch_bounds__(256) void hist_blocks(const float* __restrict__ c0,
                                                   const float* __restrict__ c1,
                                                   const float* __restrict__ c2,
                                                   unsigned* __restrict__ blockHist){
  __shared__ unsigned lh[3 * NCB];
  for (int i = threadIdx.x; i < 3 * NCB; i += 256) lh[i] = 0;
  __syncthreads();
  int g = blockIdx.x * 256 + threadIdx.x;
  const int Q = LTOT / 4;
  for (int q = g; q < Q; q += HB * 256){
    int e = q * 4;
    int lvl, idx; const float* p;
    if (e < L0T){ lvl = 0; idx = e; p = c0; }
    else if (e < L0T + L1T){ lvl = 1; idx = e - L0T; p = c1; }
    else { lvl = 2; idx = e - (L0T + L1T); p = c2; }
    float4 v = *(const float4*)(p + idx);
    unsigned* h = lh + lvl * NCB;
    atomicAdd(&h[mkey(v.x) >> 21], 1u);
    atomicAdd(&h[mkey(v.y) >> 21], 1u);
    atomicAdd(&h[mkey(v.z) >> 21], 1u);
    atomicAdd(&h[mkey(v.w) >> 21], 1u);
  }
  __syncthreads();
  unsigned* out = blockHist + (size_t)blockIdx.x * 3 * NCB;
  for (int i = threadIdx.x; i < 3 * NCB; i += 256) out[i] = lh[i];
}

// 24 blocks: fold 128 per-block hists into one global hist (6144 counters)
__global__ __launch_bounds__(256) void reduce_hist24(const unsigned* __restrict__ blockHist,
                                                     unsigned* __restrict__ ghist){
  int c = blockIdx.x * 256 + threadIdx.x;   // < 6144
  unsigned s = 0;
#pragma unroll 8
  for (int b = 0; b < HB; ++b) s += blockHist[(size_t)b * 3 * NCB + c];
  ghist[c] = s;
}

// one block per level: find T, per-block suffix counts >= T, exclusive scan -> blockBase
__global__ __launch_bounds__(256) void threshbase_kernel(const unsigned* __restrict__ ghist,
                                                         const unsigned* __restrict__ blockHist,
                                                         unsigned* __restrict__ T,
                                                         unsigned* __restrict__ blockBase,
                                                         unsigned* __restrict__ candCnt){
  __shared__ unsigned h[NCB];
  __shared__ unsigned sT;
  __shared__ unsigned cb[HB];
  int lvl = blockIdx.x;
  for (int c = threadIdx.x; c < NCB; c += 256) h[c] = ghist[lvl * NCB + c];
  __syncthreads();
  if (threadIdx.x < 64){
    int lane = threadIdx.x;
    unsigned K = (lvl == 2) ? 1600u : 2000u;
    unsigned p = 0;
    for (int b = lane * 32; b < lane * 32 + 32; ++b) p += h[b];
    unsigned sincl = p;                     // inclusive suffix scan across lanes
    for (int d = 1; d < 64; d <<= 1){
      unsigned t = __shfl_down(sincl, d);
      if (lane + d < 64) sincl += t;
    }
    unsigned s_after = sincl - p;
    if (s_after < K && s_after + p >= K){   // exactly one lane
      unsigned acc = s_after;
      for (int b = lane * 32 + 31; b >= lane * 32; --b){
        acc += h[b];
        if (acc >= K){ sT = (unsigned)b; break; }
      }
    }
  }
  __syncthreads();
  unsigned tt = sT;
  if (threadIdx.x == 0) T[lvl] = tt;
  if (threadIdx.x < HB){
    const unsigned* bh = blockHist + (size_t)threadIdx.x * 3 * NCB + lvl * NCB;
    unsigned s = 0;
    for (unsigned c = tt; c < NCB; ++c) s += bh[c];
    cb[threadIdx.x] = s;
  }
  __syncthreads();
  if (threadIdx.x == 0){
    unsigned acc = 0;
    for (int b = 0; b < HB; ++b){ unsigned v = cb[b]; blockBase[lvl * HB + b] = acc; acc += v; }
    candCnt[lvl] = (acc > CANDCAP) ? CANDCAP : acc;
  }
}

// single-pass compact: positions from blockBase + intra-block LDS counter + ballot prefix
__global__ __launch_bounds__(256) void compact_kernel(const float* __restrict__ c0,
                                                      const float* __restrict__ c1,
                                                      const float* __restrict__ c2,
                                                      const unsigned* __restrict__ T,
                                                      const unsigned* __restrict__ blockBase,
                                                      unsigned long long* __restrict__ cand){
  __shared__ unsigned run[3];
  if (threadIdx.x < 3) run[threadIdx.x] = 0;
  __syncthreads();
  unsigned t0 = T[0], t1 = T[1], t2 = T[2];
  unsigned bb0 = blockBase[0 * HB + blockIdx.x];
  unsigned bb1 = blockBase[1 * HB + blockIdx.x];
  unsigned bb2 = blockBase[2 * HB + blockIdx.x];
  int lane = threadIdx.x & 63;
  unsigned long long ltmask = (lane == 0) ? 0ull : ((1ull << lane) - 1ull);
  const int Q = LTOT / 4;
  for (int q = blockIdx.x * 256 + threadIdx.x; q < Q; q += HB * 256){
    int e = q * 4;
    int lvl, idx; const float* p; unsigned tt, bb;
    if (e < L0T){ lvl = 0; idx = e; p = c0; tt = t0; bb = bb0; }
    else if (e < L0T + L1T){ lvl = 1; idx = e - L0T; p = c1; tt = t1; bb = bb1; }
    else { lvl = 2; idx = e - (L0T + L1T); p = c2; tt = t2; bb = bb2; }
    float4 v = *(const float4*)(p + idx);
    unsigned k0 = mkey(v.x), k1 = mkey(v.y), k2 = mkey(v.z), k3 = mkey(v.w);
    bool p0 = (k0 >> 21) >= tt, p1 = (k1 >> 21) >= tt, p2 = (k2 >> 21) >= tt, p3 = (k3 >> 21) >= tt;
    unsigned long long bal0 = __ballot(p0), bal1 = __ballot(p1), bal2 = __ballot(p2), bal3 = __ballot(p3);
    unsigned n0 = (unsigned)__popcll(bal0), n1 = (unsigned)__popcll(bal1),
             n2 = (unsigned)__popcll(bal2), n3 = (unsigned)__popcll(bal3);
    unsigned wtot = n0 + n1 + n2 + n3;
    if (wtot == 0) continue;
    unsigned wold = 0;
    if (lane == 0) wold = atomicAdd(&run[lvl], wtot);
    wold = __shfl(wold, 0);
    unsigned base = bb + wold;
    if (p0){ unsigned pos = base + (unsigned)__popcll(bal0 & ltmask);
      if (pos < CANDCAP) cand[lvl * CANDCAP + pos] = ((unsigned long long)k0 << 32) | (unsigned)(~(unsigned)idx); }
    if (p1){ unsigned pos = base + n0 + (unsigned)__popcll(bal1 & ltmask);
      if (pos < CANDCAP) cand[lvl * CANDCAP + pos] = ((unsigned long long)k1 << 32) | (unsigned)(~(unsigned)(idx + 1)); }
    if (p2){ unsigned pos = base + n0 + n1 + (unsigned)__popcll(bal2 & ltmask);
      if (pos < CANDCAP) cand[lvl * CANDCAP + pos] = ((unsigned long long)k2 << 32) | (unsigned)(~(unsigned)(idx + 2)); }
    if (p3){ unsigned pos = base + n0 + n1 + n2 + (unsigned)__popcll(bal3 & ltmask);
      if (pos < CANDCAP) cand[lvl * CANDCAP + pos] = ((unsigned long long)k3 << 32) | (unsigned)(~(unsigned)(idx + 3)); }
  }
}

// per level: thread-per-item rank via broadcast LDS reads, 8-wide unroll, 4 accumulators
__global__ __launch_bounds__(256) void level_rank_kernel(
    const float* __restrict__ box0, const float* __restrict__ box1, const float* __restrict__ box2,
    const unsigned* __restrict__ candCnt, const unsigned long long* __restrict__ cand,
    unsigned* __restrict__ ckey, float* __restrict__ cscore, int* __restrict__ clabel,
    float* __restrict__ cbox, unsigned* __restrict__ cvalid){
  extern __shared__ unsigned long long k[];
  int lvl = blockIdx.y;
  int cnt = (int)candCnt[lvl];
  if ((int)(blockIdx.x * 256) >= cnt) return;
  int K = (lvl == 2) ? 1600 : 2000;
  int base = lvl * 2000;
  const float* bx = (lvl == 0) ? box0 : ((lvl == 1) ? box1 : box2);
  int cntP = (cnt + 7) & ~7;
  for (int i = threadIdx.x; i < cntP; i += 256)
    k[i] = (i < cnt) ? cand[lvl * CANDCAP + i] : 0ull;
  __syncthreads();
  int i = blockIdx.x * 256 + threadIdx.x;
  if (i >= cnt) return;
  unsigned long long ki = k[i];
  int r0 = 0, r1 = 0, r2 = 0, r3 = 0;
  for (int j = 0; j < cntP; j += 8){
    unsigned long long a0 = k[j+0], a1 = k[j+1], a2 = k[j+2], a3 = k[j+3];
    unsigned long long a4 = k[j+4], a5 = k[j+5], a6 = k[j+6], a7 = k[j+7];
    r0 += (int)(a0 > ki) + (int)(a4 > ki);
    r1 += (int)(a1 > ki) + (int)(a5 > ki);
    r2 += (int)(a2 > ki) + (int)(a6 > ki);
    r3 += (int)(a3 > ki) + (int)(a7 > ki);
  }
  int r = r0 + r1 + r2 + r3;
  if (r < K){
    unsigned key = (unsigned)(ki >> 32);
    unsigned idxm = ~(unsigned)ki;
    int anchor = (int)(idxm / 80u);
    int lbl = (int)(idxm % 80u);
    unsigned fb = (key & 0x80000000u) ? (key ^ 0x80000000u) : ~key;
    float logit = __uint_as_float(fb);
    float sc = 1.0f / (1.0f + expf(-logit));
    int pos = base + r;
    ckey[pos] = key;
    cscore[pos] = sc;
    clabel[pos] = lbl;
    cvalid[pos] = (sc > 0.05f) ? 1u : 0u;
    float4 b = *(const float4*)(bx + (size_t)anchor * 4);
    *(float4*)(cbox + pos * 4) = b;
  }
}

// global stable rank by (valid?key:0 desc, concat-pos asc), thread-per-item broadcast
__global__ __launch_bounds__(256) void global_rank_kernel(
    const unsigned* __restrict__ ckey, const float* __restrict__ cscore,
    const int* __restrict__ clabel, const float* __restrict__ cbox,
    const unsigned* __restrict__ cvalid,
    float* __restrict__ sscore, int* __restrict__ slabel, float* __restrict__ sbox,
    float* __restrict__ soff, unsigned* __restrict__ svalid){
  __shared__ unsigned long long k[NTOT];
  for (int i = threadIdx.x; i < NTOT; i += 256){
    unsigned eff = cvalid[i] ? ckey[i] : 0u;
    k[i] = ((unsigned long long)eff << 32) | (unsigned)(~(unsigned)i);
  }
  __syncthreads();
  int i = blockIdx.x * 256 + threadIdx.x;
  if (i >= NTOT) return;
  unsigned long long ki = k[i];
  int r0 = 0, r1 = 0, r2 = 0, r3 = 0;
  for (int j = 0; j < NTOT; j += 8){   // NTOT % 8 == 0
    unsigned long long a0 = k[j+0], a1 = k[j+1], a2 = k[j+2], a3 = k[j+3];
    unsigned long long a4 = k[j+4], a5 = k[j+5], a6 = k[j+6], a7 = k[j+7];
    r0 += (int)(a0 > ki) + (int)(a4 > ki);
    r1 += (int)(a1 > ki) + (int)(a5 > ki);
    r2 += (int)(a2 > ki) + (int)(a6 > ki);
    r3 += (int)(a3 > ki) + (int)(a7 > ki);
  }
  int r = r0 + r1 + r2 + r3;
  int lbl = clabel[i];
  float off = (float)lbl * 10000.0f;
  sscore[r] = cscore[i];
  slabel[r] = lbl;
  svalid[r] = cvalid[i];
  float4 b = *(const float4*)(cbox + (size_t)i * 4);
  *(float4*)(sbox + (size_t)r * 4) = b;
  float4 bo; bo.x = b.x + off; bo.y = b.y + off; bo.z = b.z + off; bo.w = b.w + off;
  *(float4*)(soff + (size_t)r * 4) = bo;
}

// suppression bitmask: mask pre-zeroed by memset; only nonzero words stored.
// diagonal words additionally stored coalesced in diagT[c][lane] for the scan.
__global__ void nms_mask_kernel(const float* __restrict__ soff, const int* __restrict__ slabel,
                                unsigned* __restrict__ rowAny, unsigned long long* __restrict__ mask,
                                unsigned long long* __restrict__ diagT){
  __shared__ float cb[64][4];
  __shared__ float ca[64];
  __shared__ int cl[64];
  int wi = blockIdx.x, wj = blockIdx.y;
  if (wj < wi) return;                 // lower triangle: memset already zeroed
  int t = threadIdx.x;
  int i = wi * 64 + t;
  int j0 = wj * 64;
  int j = j0 + t;
  if (j < NTOT){
    float x1 = soff[j * 4 + 0], y1 = soff[j * 4 + 1];
    float x2 = soff[j * 4 + 2], y2 = soff[j * 4 + 3];
    cb[t][0] = x1; cb[t][1] = y1; cb[t][2] = x2; cb[t][3] = y2;
    {
#pragma clang fp contract(off)
      ca[t] = fmaxf(x2 - x1, 0.0f) * fmaxf(y2 - y1, 0.0f);
    }
    cl[t] = slabel[j];
  } else {
    cl[t] = -1;
  }
  __syncthreads();
  unsigned long long w = 0ull;
  if (i < NTOT){
    float ax1 = soff[i * 4 + 0], ay1 = soff[i * 4 + 1];
    float ax2 = soff[i * 4 + 2], ay2 = soff[i * 4 + 3];
    int li = slabel[i];
    float areaA;
    {
#pragma clang fp contract(off)
      areaA = fmaxf(ax2 - ax1, 0.0f) * fmaxf(ay2 - ay1, 0.0f);
    }
    for (int jj = 0; jj < 64; ++jj){
      int jg = j0 + jj;
      if (jg >= NTOT) break;
      if (jg <= i) continue;
      if (cl[jj] != li) continue;
      {
#pragma clang fp contract(off)
        float ltx = fmaxf(ax1, cb[jj][0]);
        float lty = fmaxf(ay1, cb[jj][1]);
        float rbx = fminf(ax2, cb[jj][2]);
        float rby = fminf(ay2, cb[jj][3]);
        float ww = fmaxf(rbx - ltx, 0.0f);
        float hh = fmaxf(rby - lty, 0.0f);
        float inter = ww * hh;
        float uni = (areaA + ca[jj]) - inter;
        float iou = inter / fmaxf(uni, 1e-9f);
        if (iou > 0.6f) w |= (1ull << jj);
      }
    }
  }
  if (wi == wj) diagT[wi * 64 + t] = w;
  if (w){
    mask[(size_t)i * NW + wj] = w;
    rowAny[i] = 1u;
  }
}

// single-wave sequential greedy scan; removed bits live in registers (word w: lane w / lane w-64)
__global__ void nms_scan_kernel(const unsigned long long* __restrict__ mask,
                                const unsigned long long* __restrict__ diagT,
                                const unsigned* __restrict__ rowAny,
                                const unsigned* __restrict__ svalid,
                                unsigned long long* __restrict__ keepW){
  int lane = threadIdx.x;  // 64 threads
  unsigned long long rem0 = 0ull, rem1 = 0ull;
  for (int w = 0; w < NW; ++w){
    int e = w * 64 + lane;
    unsigned v = (e < NTOT) ? svalid[e] : 0u;
    unsigned long long bal = __ballot(v == 0u);   // invalid/out-of-range = pre-suppressed
    if (w == lane) rem0 = bal;
    if (w == 64 + lane) rem1 = bal;
  }
  for (int c = 0; c < NW; ++c){
    int row = c * 64 + lane;
    unsigned long long D = diagT[c * 64 + lane];  // coalesced diagonal word
    unsigned any = (row < NTOT) ? rowAny[row] : 0u;
    unsigned long long a0 = __shfl(rem0, c & 63);
    unsigned long long a1 = __shfl(rem1, c & 63);
    unsigned long long rem = (c < 64) ? a0 : a1;
    // serial resolve only over rows with intra-chunk suppression bits (usually none)
    unsigned long long nz = __ballot(D != 0ull);
    while (nz){
      int b = __builtin_ctzll(nz);
      nz &= nz - 1;
      unsigned long long Db = __shfl(D, b);       // uniform path: all lanes execute
      if (!((rem >> b) & 1ull)) rem |= Db;
    }
    unsigned long long kp = ~rem;
    if (c < 64){ if (lane == c) rem0 = rem; }
    else       { if (lane == c - 64) rem1 = rem; }
    if (lane == 0) keepW[c] = kp;
    // OR kept rows (that suppress anything) into the running removed words
    unsigned long long act = kp & __ballot(any != 0u);
    while (act){
      int b = __builtin_ctzll(act);
      act &= act - 1;
      int r2 = c * 64 + b;
      rem0 |= mask[(size_t)r2 * NW + lane];
      if (lane < NW - 64) rem1 |= mask[(size_t)r2 * NW + 64 + lane];
    }
  }
}

__device__ __forceinline__ float read_dim(const int* p){
  int iv = p[0];
  if (iv > 0 && iv < (1 << 24)) return (float)iv;   // stored as int
  return __int_as_float(iv);                        // stored as float bits
}

__global__ void output_kernel(const float* __restrict__ sscore, const int* __restrict__ slabel,
                              const float* __restrict__ sbox, const unsigned long long* __restrict__ keepW,
                              const int* __restrict__ imw, const int* __restrict__ imh,
                              float* __restrict__ out){
  int r = blockIdx.x * blockDim.x + threadIdx.x;
  if (r >= NTOT) return;
  float wv = read_dim(imw), hv = read_dim(imh);
  float sw = (float)(1.0 / (double)wv);   // match python 1.0/img_w (double) -> f32
  float sh = (float)(1.0 / (double)hv);
  float b0 = sbox[r * 4 + 0] * sw, b1 = sbox[r * 4 + 1] * sh;
  float b2 = sbox[r * 4 + 2] * sw, b3 = sbox[r * 4 + 3] * sh;
  out[r * 4 + 0] = fminf(fmaxf(b0, 0.0f), 1.0f);
  out[r * 4 + 1] = fminf(fmaxf(b1, 0.0f), 1.0f);
  out[r * 4 + 2] = fminf(fmaxf(b2, 0.0f), 1.0f);
  out[r * 4 + 3] = fminf(fmaxf(b3, 0.0f), 1.0f);
  out[NTOT * 4 + r] = sscore[r];
  out[NTOT * 5 + r] = (float)slabel[r];
  out[NTOT * 6 + r] = ((keepW[r >> 6] >> (r & 63)) & 1ull) ? 1.0f : 0.0f;
}

// ---- workspace layout (bytes) ----
#define WS_TVAL      0u        // 16
#define WS_CANDCNT   16u       // 16
#define WS_ROWANY    32u       // 22400 -> 22432
#define WS_BLOCKBASE 22432u    // 3*128*4 = 1536 -> 23968
#define WS_GHIST     23968u    // 6144*4 = 24576 -> 48544
#define WS_DIAGT     48544u    // 88*64*8 = 45056 -> 93600
#define WS_CAND      93600u    // 3*8192*8 = 196608 -> 290208
#define WS_CKEY      290208u   // 22400 -> 312608
#define WS_CSCORE    312608u   // 22400 -> 335008
#define WS_CLABEL    335008u   // 22400 -> 357408
#define WS_CBOX      357408u   // 89600 -> 447008  (16-aligned)
#define WS_CVALID    447008u   // 22400 -> 469408
#define WS_SSCORE    469408u   // 22400 -> 491808
#define WS_SLABEL    491808u   // 22400 -> 514208
#define WS_SBOX      514208u   // 89600 -> 603808  (16-aligned)
#define WS_SOFF      603808u   // 89600 -> 693408  (16-aligned)
#define WS_SVALID    693408u   // 22400 -> 715808
#define WS_KEEPW     715808u   // 704 -> 716512
#define WS_MASK      716512u   // 5600*88*8 = 3942400 -> 4658912
#define WS_BLOCKHIST WS_MASK   // reuse: 128*3*2048*4 = 3145728 <= 3942400, dead before mask memset

extern "C" void kernel_launch(void* const* d_in, const int* in_sizes, int n_in,
                              void* d_out, int out_size, void* d_ws, size_t ws_size,
                              hipStream_t stream) {
  (void)in_sizes; (void)n_in; (void)out_size; (void)ws_size;
  const float* cls0 = (const float*)d_in[0];
  const float* box0 = (const float*)d_in[1];
  const float* cls1 = (const float*)d_in[2];
  const float* box1 = (const float*)d_in[3];
  const float* cls2 = (const float*)d_in[4];
  const float* box2 = (const float*)d_in[5];
  const int* imw = (const int*)d_in[6];
  const int* imh = (const int*)d_in[7];
  char* w = (char*)d_ws;
  unsigned* tval      = (unsigned*)(w + WS_TVAL);
  unsigned* candCnt   = (unsigned*)(w + WS_CANDCNT);
  unsigned* rowAny    = (unsigned*)(w + WS_ROWANY);
  unsigned* blockBase = (unsigned*)(w + WS_BLOCKBASE);
  unsigned* ghist     = (unsigned*)(w + WS_GHIST);
  unsigned long long* diagT = (unsigned long long*)(w + WS_DIAGT);
  unsigned long long* cand  = (unsigned long long*)(w + WS_CAND);
  unsigned* ckey   = (unsigned*)(w + WS_CKEY);
  float* cscore    = (float*)(w + WS_CSCORE);
  int* clabel      = (int*)(w + WS_CLABEL);
  float* cbox      = (float*)(w + WS_CBOX);
  unsigned* cvalid = (unsigned*)(w + WS_CVALID);
  float* sscore    = (float*)(w + WS_SSCORE);
  int* slabel      = (int*)(w + WS_SLABEL);
  float* sbox      = (float*)(w + WS_SBOX);
  float* soff      = (float*)(w + WS_SOFF);
  unsigned* svalid = (unsigned*)(w + WS_SVALID);
  unsigned long long* keepW = (unsigned long long*)(w + WS_KEEPW);
  unsigned long long* mask  = (unsigned long long*)(w + WS_MASK);
  unsigned* blockHist = (unsigned*)(w + WS_BLOCKHIST);

  hipMemsetAsync(w + WS_ROWANY, 0, 22400u, stream);
  hist_blocks<<<HB, 256, 0, stream>>>(cls0, cls1, cls2, blockHist);
  reduce_hist24<<<24, 256, 0, stream>>>(blockHist, ghist);
  threshbase_kernel<<<3, 256, 0, stream>>>(ghist, blockHist, tval, blockBase, candCnt);
  compact_kernel<<<HB, 256, 0, stream>>>(cls0, cls1, cls2, tval, blockBase, cand);
  hipMemsetAsync(w + WS_MASK, 0, 3942400u, stream);   // blockHist dead now
  level_rank_kernel<<<dim3(32, 3), 256, CANDCAP * 8, stream>>>(box0, box1, box2, candCnt, cand,
                                                               ckey, cscore, clabel, cbox, cvalid);
  global_rank_kernel<<<22, 256, 0, stream>>>(ckey, cscore, clabel, cbox, cvalid,
                                             sscore, slabel, sbox, soff, svalid);
  nms_mask_kernel<<<dim3(88, 88), 64, 0, stream>>>(soff, slabel, rowAny, mask, diagT);
  nms_scan_kernel<<<1, 64, 0, stream>>>(mask, diagT, rowAny, svalid, keepW);
  output_kernel<<<22, 256, 0, stream>>>(sscore, slabel, sbox, keepW, imw, imh, (float*)d_out);
}

// Round 6
// 311.976 us; speedup vs baseline: 5.4478x; 1.0840x over previous
//
#include <hip/hip_runtime.h>
#include <math.h>

// ---- problem constants ----
#define L0T 2048000   // 160*160*80
#define L1T 512000    // 80*80*80
#define L2T 128000    // 40*40*80
#define LTOT 2688000
#define NTOT 5600     // 2000+2000+1600
#define NW 88         // ceil(5600/64)
#define NCB 2048      // coarse buckets = key >> 21
#define HB 128        // histogram/compact block count
#define CANDCAP 8192

// monotone order-preserving key for f32
__device__ __forceinline__ unsigned mkey(float f){
  unsigned u = __float_as_uint(f);
  return u ^ ((unsigned)(((int)u) >> 31) | 0x80000000u);
}

// per-block LDS histogram, no global atomics
__global__ __launch_bounds__(256) void hist_blocks(const float* __restrict__ c0,
                                                   const float* __restrict__ c1,
                                                   const float* __restrict__ c2,
                                                   unsigned* __restrict__ blockHist){
  __shared__ unsigned lh[3 * NCB];
  for (int i = threadIdx.x; i < 3 * NCB; i += 256) lh[i] = 0;
  __syncthreads();
  int g = blockIdx.x * 256 + threadIdx.x;
  const int Q = LTOT / 4;
  for (int q = g; q < Q; q += HB * 256){
    int e = q * 4;
    int lvl, idx; const float* p;
    if (e < L0T){ lvl = 0; idx = e; p = c0; }
    else if (e < L0T + L1T){ lvl = 1; idx = e - L0T; p = c1; }
    else { lvl = 2; idx = e - (L0T + L1T); p = c2; }
    float4 v = *(const float4*)(p + idx);
    unsigned* h = lh + lvl * NCB;
    atomicAdd(&h[mkey(v.x) >> 21], 1u);
    atomicAdd(&h[mkey(v.y) >> 21], 1u);
    atomicAdd(&h[mkey(v.z) >> 21], 1u);
    atomicAdd(&h[mkey(v.w) >> 21], 1u);
  }
  __syncthreads();
  unsigned* out = blockHist + (size_t)blockIdx.x * 3 * NCB;
  for (int i = threadIdx.x; i < 3 * NCB; i += 256) out[i] = lh[i];
}

// 24 blocks: fold 128 per-block hists into one global hist (6144 counters)
__global__ __launch_bounds__(256) void reduce_hist24(const unsigned* __restrict__ blockHist,
                                                     unsigned* __restrict__ ghist){
  int c = blockIdx.x * 256 + threadIdx.x;   // < 6144
  unsigned s = 0;
#pragma unroll 8
  for (int b = 0; b < HB; ++b) s += blockHist[(size_t)b * 3 * NCB + c];
  ghist[c] = s;
}

// one block per level: find T, per-block suffix counts >= T, exclusive scan -> blockBase
__global__ __launch_bounds__(256) void threshbase_kernel(const unsigned* __restrict__ ghist,
                                                         const unsigned* __restrict__ blockHist,
                                                         unsigned* __restrict__ T,
                                                         unsigned* __restrict__ blockBase,
                                                         unsigned* __restrict__ candCnt){
  __shared__ unsigned h[NCB];
  __shared__ unsigned sT;
  __shared__ unsigned cb[HB];
  int lvl = blockIdx.x;
  for (int c = threadIdx.x; c < NCB; c += 256) h[c] = ghist[lvl * NCB + c];
  __syncthreads();
  if (threadIdx.x < 64){
    int lane = threadIdx.x;
    unsigned K = (lvl == 2) ? 1600u : 2000u;
    unsigned p = 0;
    for (int b = lane * 32; b < lane * 32 + 32; ++b) p += h[b];
    unsigned sincl = p;                     // inclusive suffix scan across lanes
    for (int d = 1; d < 64; d <<= 1){
      unsigned t = __shfl_down(sincl, d);
      if (lane + d < 64) sincl += t;
    }
    unsigned s_after = sincl - p;
    if (s_after < K && s_after + p >= K){   // exactly one lane
      unsigned acc = s_after;
      for (int b = lane * 32 + 31; b >= lane * 32; --b){
        acc += h[b];
        if (acc >= K){ sT = (unsigned)b; break; }
      }
    }
  }
  __syncthreads();
  unsigned tt = sT;
  if (threadIdx.x == 0) T[lvl] = tt;
  if (threadIdx.x < HB){
    const unsigned* bh = blockHist + (size_t)threadIdx.x * 3 * NCB + lvl * NCB;
    unsigned s = 0;
    for (unsigned c = tt; c < NCB; ++c) s += bh[c];
    cb[threadIdx.x] = s;
  }
  __syncthreads();
  if (threadIdx.x == 0){
    unsigned acc = 0;
    for (int b = 0; b < HB; ++b){ unsigned v = cb[b]; blockBase[lvl * HB + b] = acc; acc += v; }
    candCnt[lvl] = (acc > CANDCAP) ? CANDCAP : acc;
  }
}

// single-pass compact: positions from blockBase + intra-block LDS counter + ballot prefix
__global__ __launch_bounds__(256) void compact_kernel(const float* __restrict__ c0,
                                                      const float* __restrict__ c1,
                                                      const float* __restrict__ c2,
                                                      const unsigned* __restrict__ T,
                                                      const unsigned* __restrict__ blockBase,
                                                      unsigned long long* __restrict__ cand){
  __shared__ unsigned run[3];
  if (threadIdx.x < 3) run[threadIdx.x] = 0;
  __syncthreads();
  unsigned t0 = T[0], t1 = T[1], t2 = T[2];
  unsigned bb0 = blockBase[0 * HB + blockIdx.x];
  unsigned bb1 = blockBase[1 * HB + blockIdx.x];
  unsigned bb2 = blockBase[2 * HB + blockIdx.x];
  int lane = threadIdx.x & 63;
  unsigned long long ltmask = (lane == 0) ? 0ull : ((1ull << lane) - 1ull);
  const int Q = LTOT / 4;
  for (int q = blockIdx.x * 256 + threadIdx.x; q < Q; q += HB * 256){
    int e = q * 4;
    int lvl, idx; const float* p; unsigned tt, bb;
    if (e < L0T){ lvl = 0; idx = e; p = c0; tt = t0; bb = bb0; }
    else if (e < L0T + L1T){ lvl = 1; idx = e - L0T; p = c1; tt = t1; bb = bb1; }
    else { lvl = 2; idx = e - (L0T + L1T); p = c2; tt = t2; bb = bb2; }
    float4 v = *(const float4*)(p + idx);
    unsigned k0 = mkey(v.x), k1 = mkey(v.y), k2 = mkey(v.z), k3 = mkey(v.w);
    bool p0 = (k0 >> 21) >= tt, p1 = (k1 >> 21) >= tt, p2 = (k2 >> 21) >= tt, p3 = (k3 >> 21) >= tt;
    unsigned long long bal0 = __ballot(p0), bal1 = __ballot(p1), bal2 = __ballot(p2), bal3 = __ballot(p3);
    unsigned n0 = (unsigned)__popcll(bal0), n1 = (unsigned)__popcll(bal1),
             n2 = (unsigned)__popcll(bal2), n3 = (unsigned)__popcll(bal3);
    unsigned wtot = n0 + n1 + n2 + n3;
    if (wtot == 0) continue;
    unsigned wold = 0;
    if (lane == 0) wold = atomicAdd(&run[lvl], wtot);
    wold = __shfl(wold, 0);
    unsigned base = bb + wold;
    if (p0){ unsigned pos = base + (unsigned)__popcll(bal0 & ltmask);
      if (pos < CANDCAP) cand[lvl * CANDCAP + pos] = ((unsigned long long)k0 << 32) | (unsigned)(~(unsigned)idx); }
    if (p1){ unsigned pos = base + n0 + (unsigned)__popcll(bal1 & ltmask);
      if (pos < CANDCAP) cand[lvl * CANDCAP + pos] = ((unsigned long long)k1 << 32) | (unsigned)(~(unsigned)(idx + 1)); }
    if (p2){ unsigned pos = base + n0 + n1 + (unsigned)__popcll(bal2 & ltmask);
      if (pos < CANDCAP) cand[lvl * CANDCAP + pos] = ((unsigned long long)k2 << 32) | (unsigned)(~(unsigned)(idx + 2)); }
    if (p3){ unsigned pos = base + n0 + n1 + n2 + (unsigned)__popcll(bal3 & ltmask);
      if (pos < CANDCAP) cand[lvl * CANDCAP + pos] = ((unsigned long long)k3 << 32) | (unsigned)(~(unsigned)(idx + 3)); }
  }
}

// per level: thread-per-item rank via broadcast LDS reads, 8-wide unroll, 4 accumulators
__global__ __launch_bounds__(256) void level_rank_kernel(
    const float* __restrict__ box0, const float* __restrict__ box1, const float* __restrict__ box2,
    const unsigned* __restrict__ candCnt, const unsigned long long* __restrict__ cand,
    unsigned* __restrict__ ckey, float* __restrict__ cscore, int* __restrict__ clabel,
    float* __restrict__ cbox, unsigned* __restrict__ cvalid){
  extern __shared__ unsigned long long k[];
  int lvl = blockIdx.y;
  int cnt = (int)candCnt[lvl];
  if ((int)(blockIdx.x * 256) >= cnt) return;
  int K = (lvl == 2) ? 1600 : 2000;
  int base = lvl * 2000;
  const float* bx = (lvl == 0) ? box0 : ((lvl == 1) ? box1 : box2);
  int cntP = (cnt + 7) & ~7;
  for (int i = threadIdx.x; i < cntP; i += 256)
    k[i] = (i < cnt) ? cand[lvl * CANDCAP + i] : 0ull;
  __syncthreads();
  int i = blockIdx.x * 256 + threadIdx.x;
  if (i >= cnt) return;
  unsigned long long ki = k[i];
  int r0 = 0, r1 = 0, r2 = 0, r3 = 0;
  for (int j = 0; j < cntP; j += 8){
    unsigned long long a0 = k[j+0], a1 = k[j+1], a2 = k[j+2], a3 = k[j+3];
    unsigned long long a4 = k[j+4], a5 = k[j+5], a6 = k[j+6], a7 = k[j+7];
    r0 += (int)(a0 > ki) + (int)(a4 > ki);
    r1 += (int)(a1 > ki) + (int)(a5 > ki);
    r2 += (int)(a2 > ki) + (int)(a6 > ki);
    r3 += (int)(a3 > ki) + (int)(a7 > ki);
  }
  int r = r0 + r1 + r2 + r3;
  if (r < K){
    unsigned key = (unsigned)(ki >> 32);
    unsigned idxm = ~(unsigned)ki;
    int anchor = (int)(idxm / 80u);
    int lbl = (int)(idxm % 80u);
    unsigned fb = (key & 0x80000000u) ? (key ^ 0x80000000u) : ~key;
    float logit = __uint_as_float(fb);
    float sc = 1.0f / (1.0f + expf(-logit));
    int pos = base + r;
    ckey[pos] = key;
    cscore[pos] = sc;
    clabel[pos] = lbl;
    cvalid[pos] = (sc > 0.05f) ? 1u : 0u;
    float4 b = *(const float4*)(bx + (size_t)anchor * 4);
    *(float4*)(cbox + pos * 4) = b;
  }
}

// global stable rank by (valid?key:0 desc, concat-pos asc), thread-per-item broadcast
__global__ __launch_bounds__(256) void global_rank_kernel(
    const unsigned* __restrict__ ckey, const float* __restrict__ cscore,
    const int* __restrict__ clabel, const float* __restrict__ cbox,
    const unsigned* __restrict__ cvalid,
    float* __restrict__ sscore, int* __restrict__ slabel, float* __restrict__ sbox,
    float* __restrict__ soff, unsigned* __restrict__ svalid){
  __shared__ unsigned long long k[NTOT];
  for (int i = threadIdx.x; i < NTOT; i += 256){
    unsigned eff = cvalid[i] ? ckey[i] : 0u;
    k[i] = ((unsigned long long)eff << 32) | (unsigned)(~(unsigned)i);
  }
  __syncthreads();
  int i = blockIdx.x * 256 + threadIdx.x;
  if (i >= NTOT) return;
  unsigned long long ki = k[i];
  int r0 = 0, r1 = 0, r2 = 0, r3 = 0;
  for (int j = 0; j < NTOT; j += 8){   // NTOT % 8 == 0
    unsigned long long a0 = k[j+0], a1 = k[j+1], a2 = k[j+2], a3 = k[j+3];
    unsigned long long a4 = k[j+4], a5 = k[j+5], a6 = k[j+6], a7 = k[j+7];
    r0 += (int)(a0 > ki) + (int)(a4 > ki);
    r1 += (int)(a1 > ki) + (int)(a5 > ki);
    r2 += (int)(a2 > ki) + (int)(a6 > ki);
    r3 += (int)(a3 > ki) + (int)(a7 > ki);
  }
  int r = r0 + r1 + r2 + r3;
  int lbl = clabel[i];
  float off = (float)lbl * 10000.0f;
  sscore[r] = cscore[i];
  slabel[r] = lbl;
  svalid[r] = cvalid[i];
  float4 b = *(const float4*)(cbox + (size_t)i * 4);
  *(float4*)(sbox + (size_t)r * 4) = b;
  float4 bo; bo.x = b.x + off; bo.y = b.y + off; bo.z = b.z + off; bo.w = b.w + off;
  *(float4*)(soff + (size_t)r * 4) = bo;
}

// suppression bitmask: mask pre-zeroed by memset; only nonzero words stored.
// diagonal words additionally stored coalesced in diagT[c][lane] for the scan.
__global__ void nms_mask_kernel(const float* __restrict__ soff, const int* __restrict__ slabel,
                                unsigned* __restrict__ rowAny, unsigned long long* __restrict__ mask,
                                unsigned long long* __restrict__ diagT){
  __shared__ float cb[64][4];
  __shared__ float ca[64];
  __shared__ int cl[64];
  int wi = blockIdx.x, wj = blockIdx.y;
  if (wj < wi) return;                 // lower triangle: memset already zeroed
  int t = threadIdx.x;
  int i = wi * 64 + t;
  int j0 = wj * 64;
  int j = j0 + t;
  if (j < NTOT){
    float x1 = soff[j * 4 + 0], y1 = soff[j * 4 + 1];
    float x2 = soff[j * 4 + 2], y2 = soff[j * 4 + 3];
    cb[t][0] = x1; cb[t][1] = y1; cb[t][2] = x2; cb[t][3] = y2;
    {
#pragma clang fp contract(off)
      ca[t] = fmaxf(x2 - x1, 0.0f) * fmaxf(y2 - y1, 0.0f);
    }
    cl[t] = slabel[j];
  } else {
    cl[t] = -1;
  }
  __syncthreads();
  unsigned long long w = 0ull;
  if (i < NTOT){
    float ax1 = soff[i * 4 + 0], ay1 = soff[i * 4 + 1];
    float ax2 = soff[i * 4 + 2], ay2 = soff[i * 4 + 3];
    int li = slabel[i];
    float areaA;
    {
#pragma clang fp contract(off)
      areaA = fmaxf(ax2 - ax1, 0.0f) * fmaxf(ay2 - ay1, 0.0f);
    }
    for (int jj = 0; jj < 64; ++jj){
      int jg = j0 + jj;
      if (jg >= NTOT) break;
      if (jg <= i) continue;
      if (cl[jj] != li) continue;
      {
#pragma clang fp contract(off)
        float ltx = fmaxf(ax1, cb[jj][0]);
        float lty = fmaxf(ay1, cb[jj][1]);
        float rbx = fminf(ax2, cb[jj][2]);
        float rby = fminf(ay2, cb[jj][3]);
        float ww = fmaxf(rbx - ltx, 0.0f);
        float hh = fmaxf(rby - lty, 0.0f);
        float inter = ww * hh;
        float uni = (areaA + ca[jj]) - inter;
        float iou = inter / fmaxf(uni, 1e-9f);
        if (iou > 0.6f) w |= (1ull << jj);
      }
    }
  }
  if (wi == wj) diagT[wi * 64 + t] = w;
  if (w){
    mask[(size_t)i * NW + wj] = w;
    rowAny[i] = 1u;
  }
}

// greedy scan: 4 waves stage diagT(45KB)+bitmasks into LDS, wave 0 runs the
// serial 88-chunk scan entirely from LDS; rare act-loop rows read from global.
__global__ __launch_bounds__(256) void nms_scan_kernel(
    const unsigned long long* __restrict__ mask,
    const unsigned long long* __restrict__ diagT,
    const unsigned* __restrict__ rowAny,
    const unsigned* __restrict__ svalid,
    unsigned long long* __restrict__ keepW){
  __shared__ unsigned long long sdiag[NW * 64];     // 45056 B
  __shared__ unsigned long long activeW[NW];        // rowAny && valid, per 64-row word
  __shared__ unsigned long long reminit[NW];        // ~ballot(valid) per word
  int tid = threadIdx.x;
  int lane = tid & 63;
  int wv = tid >> 6;
  for (int i = tid; i < NW * 64; i += 256) sdiag[i] = diagT[i];
  for (int wd = wv; wd < NW; wd += 4){
    int e = wd * 64 + lane;
    unsigned a = (e < NTOT) ? rowAny[e] : 0u;
    unsigned v = (e < NTOT) ? svalid[e] : 0u;
    unsigned long long balv = __ballot(v != 0u);
    unsigned long long bala = __ballot(a != 0u && v != 0u);
    if (lane == 0){ activeW[wd] = bala; reminit[wd] = ~balv; }
  }
  __syncthreads();
  if (wv != 0) return;
  // wave-0 serial scan; removed bits in registers (word w: lane w / lane w-64)
  unsigned long long rem0 = reminit[lane];
  unsigned long long rem1 = (lane < NW - 64) ? reminit[64 + lane] : ~0ull;
  for (int c = 0; c < NW; ++c){
    unsigned long long D = sdiag[c * 64 + lane];
    unsigned long long aw = activeW[c];
    unsigned long long a0 = __shfl(rem0, c & 63);
    unsigned long long a1 = __shfl(rem1, c & 63);
    unsigned long long rem = (c < 64) ? a0 : a1;
    // serial resolve only over rows with intra-chunk suppression bits (usually none)
    unsigned long long nz = __ballot(D != 0ull);
    while (nz){
      int b = __builtin_ctzll(nz);
      nz &= nz - 1;
      unsigned long long Db = __shfl(D, b);       // uniform path: all lanes execute
      if (!((rem >> b) & 1ull)) rem |= Db;
    }
    unsigned long long kp = ~rem;
    if (c < 64){ if (lane == c) rem0 = rem; }
    else       { if (lane == c - 64) rem1 = rem; }
    if (lane == 0) keepW[c] = kp;
    // OR kept suppressing rows into the running removed words (rare)
    unsigned long long act = kp & aw;
    while (act){
      int b = __builtin_ctzll(act);
      act &= act - 1;
      int r2 = c * 64 + b;
      rem0 |= mask[(size_t)r2 * NW + lane];
      if (lane < NW - 64) rem1 |= mask[(size_t)r2 * NW + 64 + lane];
    }
  }
}

__device__ __forceinline__ float read_dim(const int* p){
  int iv = p[0];
  if (iv > 0 && iv < (1 << 24)) return (float)iv;   // stored as int
  return __int_as_float(iv);                        // stored as float bits
}

__global__ void output_kernel(const float* __restrict__ sscore, const int* __restrict__ slabel,
                              const float* __restrict__ sbox, const unsigned long long* __restrict__ keepW,
                              const int* __restrict__ imw, const int* __restrict__ imh,
                              float* __restrict__ out){
  int r = blockIdx.x * blockDim.x + threadIdx.x;
  if (r >= NTOT) return;
  float wv = read_dim(imw), hv = read_dim(imh);
  float sw = (float)(1.0 / (double)wv);   // match python 1.0/img_w (double) -> f32
  float sh = (float)(1.0 / (double)hv);
  float b0 = sbox[r * 4 + 0] * sw, b1 = sbox[r * 4 + 1] * sh;
  float b2 = sbox[r * 4 + 2] * sw, b3 = sbox[r * 4 + 3] * sh;
  out[r * 4 + 0] = fminf(fmaxf(b0, 0.0f), 1.0f);
  out[r * 4 + 1] = fminf(fmaxf(b1, 0.0f), 1.0f);
  out[r * 4 + 2] = fminf(fmaxf(b2, 0.0f), 1.0f);
  out[r * 4 + 3] = fminf(fmaxf(b3, 0.0f), 1.0f);
  out[NTOT * 4 + r] = sscore[r];
  out[NTOT * 5 + r] = (float)slabel[r];
  out[NTOT * 6 + r] = ((keepW[r >> 6] >> (r & 63)) & 1ull) ? 1.0f : 0.0f;
}

// ---- workspace layout (bytes) ----
#define WS_TVAL      0u        // 16
#define WS_CANDCNT   16u       // 16
#define WS_ROWANY    32u       // 22400 -> 22432
#define WS_BLOCKBASE 22432u    // 3*128*4 = 1536 -> 23968
#define WS_GHIST     23968u    // 6144*4 = 24576 -> 48544
#define WS_DIAGT     48544u    // 88*64*8 = 45056 -> 93600
#define WS_CAND      93600u    // 3*8192*8 = 196608 -> 290208
#define WS_CKEY      290208u   // 22400 -> 312608
#define WS_CSCORE    312608u   // 22400 -> 335008
#define WS_CLABEL    335008u   // 22400 -> 357408
#define WS_CBOX      357408u   // 89600 -> 447008  (16-aligned)
#define WS_CVALID    447008u   // 22400 -> 469408
#define WS_SSCORE    469408u   // 22400 -> 491808
#define WS_SLABEL    491808u   // 22400 -> 514208
#define WS_SBOX      514208u   // 89600 -> 603808  (16-aligned)
#define WS_SOFF      603808u   // 89600 -> 693408  (16-aligned)
#define WS_SVALID    693408u   // 22400 -> 715808
#define WS_KEEPW     715808u   // 704 -> 716512
#define WS_MASK      716512u   // 5600*88*8 = 3942400 -> 4658912
#define WS_BLOCKHIST WS_MASK   // reuse: 128*3*2048*4 = 3145728 <= 3942400, dead before mask memset

extern "C" void kernel_launch(void* const* d_in, const int* in_sizes, int n_in,
                              void* d_out, int out_size, void* d_ws, size_t ws_size,
                              hipStream_t stream) {
  (void)in_sizes; (void)n_in; (void)out_size; (void)ws_size;
  const float* cls0 = (const float*)d_in[0];
  const float* box0 = (const float*)d_in[1];
  const float* cls1 = (const float*)d_in[2];
  const float* box1 = (const float*)d_in[3];
  const float* cls2 = (const float*)d_in[4];
  const float* box2 = (const float*)d_in[5];
  const int* imw = (const int*)d_in[6];
  const int* imh = (const int*)d_in[7];
  char* w = (char*)d_ws;
  unsigned* tval      = (unsigned*)(w + WS_TVAL);
  unsigned* candCnt   = (unsigned*)(w + WS_CANDCNT);
  unsigned* rowAny    = (unsigned*)(w + WS_ROWANY);
  unsigned* blockBase = (unsigned*)(w + WS_BLOCKBASE);
  unsigned* ghist     = (unsigned*)(w + WS_GHIST);
  unsigned long long* diagT = (unsigned long long*)(w + WS_DIAGT);
  unsigned long long* cand  = (unsigned long long*)(w + WS_CAND);
  unsigned* ckey   = (unsigned*)(w + WS_CKEY);
  float* cscore    = (float*)(w + WS_CSCORE);
  int* clabel      = (int*)(w + WS_CLABEL);
  float* cbox      = (float*)(w + WS_CBOX);
  unsigned* cvalid = (unsigned*)(w + WS_CVALID);
  float* sscore    = (float*)(w + WS_SSCORE);
  int* slabel      = (int*)(w + WS_SLABEL);
  float* sbox      = (float*)(w + WS_SBOX);
  float* soff      = (float*)(w + WS_SOFF);
  unsigned* svalid = (unsigned*)(w + WS_SVALID);
  unsigned long long* keepW = (unsigned long long*)(w + WS_KEEPW);
  unsigned long long* mask  = (unsigned long long*)(w + WS_MASK);
  unsigned* blockHist = (unsigned*)(w + WS_BLOCKHIST);

  hipMemsetAsync(w + WS_ROWANY, 0, 22400u, stream);
  hist_blocks<<<HB, 256, 0, stream>>>(cls0, cls1, cls2, blockHist);
  reduce_hist24<<<24, 256, 0, stream>>>(blockHist, ghist);
  threshbase_kernel<<<3, 256, 0, stream>>>(ghist, blockHist, tval, blockBase, candCnt);
  compact_kernel<<<HB, 256, 0, stream>>>(cls0, cls1, cls2, tval, blockBase, cand);
  hipMemsetAsync(w + WS_MASK, 0, 3942400u, stream);   // blockHist dead now
  level_rank_kernel<<<dim3(32, 3), 256, CANDCAP * 8, stream>>>(box0, box1, box2, candCnt, cand,
                                                               ckey, cscore, clabel, cbox, cvalid);
  global_rank_kernel<<<22, 256, 0, stream>>>(ckey, cscore, clabel, cbox, cvalid,
                                             sscore, slabel, sbox, soff, svalid);
  nms_mask_kernel<<<dim3(88, 88), 64, 0, stream>>>(soff, slabel, rowAny, mask, diagT);
  nms_scan_kernel<<<1, 256, 0, stream>>>(mask, diagT, rowAny, svalid, keepW);
  output_kernel<<<22, 256, 0, stream>>>(sscore, slabel, sbox, keepW, imw, imh, (float*)d_out);
}

// Round 8
// 259.222 us; speedup vs baseline: 6.5565x; 1.2035x over previous
//
#include <hip/hip_runtime.h>
#include <math.h>

// ---- problem constants ----
#define L0T 2048000   // 160*160*80
#define L1T 512000    // 80*80*80
#define L2T 128000    // 40*40*80
#define LTOT 2688000
#define NTOT 5600     // 2000+2000+1600
#define NW 88         // ceil(5600/64)
#define NCB 2048      // coarse buckets = key >> 21
#define HB 128        // histogram/compact block count
#define CANDCAP 8192
#define LCHUNK 1024   // level-rank j-chunk (8 chunks cover CANDCAP)
#define GCHUNK 700    // global-rank j-chunk (8 chunks cover NTOT)

// monotone order-preserving key for f32
__device__ __forceinline__ unsigned mkey(float f){
  unsigned u = __float_as_uint(f);
  return u ^ ((unsigned)(((int)u) >> 31) | 0x80000000u);
}

// per-block LDS histogram, no global atomics
__global__ __launch_bounds__(256) void hist_blocks(const float* __restrict__ c0,
                                                   const float* __restrict__ c1,
                                                   const float* __restrict__ c2,
                                                   unsigned* __restrict__ blockHist){
  __shared__ unsigned lh[3 * NCB];
  for (int i = threadIdx.x; i < 3 * NCB; i += 256) lh[i] = 0;
  __syncthreads();
  int g = blockIdx.x * 256 + threadIdx.x;
  const int Q = LTOT / 4;
  for (int q = g; q < Q; q += HB * 256){
    int e = q * 4;
    int lvl, idx; const float* p;
    if (e < L0T){ lvl = 0; idx = e; p = c0; }
    else if (e < L0T + L1T){ lvl = 1; idx = e - L0T; p = c1; }
    else { lvl = 2; idx = e - (L0T + L1T); p = c2; }
    float4 v = *(const float4*)(p + idx);
    unsigned* h = lh + lvl * NCB;
    atomicAdd(&h[mkey(v.x) >> 21], 1u);
    atomicAdd(&h[mkey(v.y) >> 21], 1u);
    atomicAdd(&h[mkey(v.z) >> 21], 1u);
    atomicAdd(&h[mkey(v.w) >> 21], 1u);
  }
  __syncthreads();
  unsigned* out = blockHist + (size_t)blockIdx.x * 3 * NCB;
  for (int i = threadIdx.x; i < 3 * NCB; i += 256) out[i] = lh[i];
}

// 24 blocks: fold 128 per-block hists into one global hist (6144 counters)
__global__ __launch_bounds__(256) void reduce_hist24(const unsigned* __restrict__ blockHist,
                                                     unsigned* __restrict__ ghist){
  int c = blockIdx.x * 256 + threadIdx.x;   // < 6144
  unsigned s = 0;
#pragma unroll 8
  for (int b = 0; b < HB; ++b) s += blockHist[(size_t)b * 3 * NCB + c];
  ghist[c] = s;
}

// one block per level: find T, per-block suffix counts >= T, exclusive scan -> blockBase
__global__ __launch_bounds__(256) void threshbase_kernel(const unsigned* __restrict__ ghist,
                                                         const unsigned* __restrict__ blockHist,
                                                         unsigned* __restrict__ T,
                                                         unsigned* __restrict__ blockBase,
                                                         unsigned* __restrict__ candCnt){
  __shared__ unsigned h[NCB];
  __shared__ unsigned sT;
  __shared__ unsigned cb[HB];
  int lvl = blockIdx.x;
  for (int c = threadIdx.x; c < NCB; c += 256) h[c] = ghist[lvl * NCB + c];
  __syncthreads();
  if (threadIdx.x < 64){
    int lane = threadIdx.x;
    unsigned K = (lvl == 2) ? 1600u : 2000u;
    unsigned p = 0;
    for (int b = lane * 32; b < lane * 32 + 32; ++b) p += h[b];
    unsigned sincl = p;                     // inclusive suffix scan across lanes
    for (int d = 1; d < 64; d <<= 1){
      unsigned t = __shfl_down(sincl, d);
      if (lane + d < 64) sincl += t;
    }
    unsigned s_after = sincl - p;
    if (s_after < K && s_after + p >= K){   // exactly one lane
      unsigned acc = s_after;
      for (int b = lane * 32 + 31; b >= lane * 32; --b){
        acc += h[b];
        if (acc >= K){ sT = (unsigned)b; break; }
      }
    }
  }
  __syncthreads();
  unsigned tt = sT;
  if (threadIdx.x == 0) T[lvl] = tt;
  if (threadIdx.x < HB){
    const unsigned* bh = blockHist + (size_t)threadIdx.x * 3 * NCB + lvl * NCB;
    unsigned s = 0;
    for (unsigned c = tt; c < NCB; ++c) s += bh[c];
    cb[threadIdx.x] = s;
  }
  __syncthreads();
  if (threadIdx.x == 0){
    unsigned acc = 0;
    for (int b = 0; b < HB; ++b){ unsigned v = cb[b]; blockBase[lvl * HB + b] = acc; acc += v; }
    candCnt[lvl] = (acc > CANDCAP) ? CANDCAP : acc;
  }
}

// single-pass compact: positions from blockBase + intra-block LDS counter + ballot prefix
__global__ __launch_bounds__(256) void compact_kernel(const float* __restrict__ c0,
                                                      const float* __restrict__ c1,
                                                      const float* __restrict__ c2,
                                                      const unsigned* __restrict__ T,
                                                      const unsigned* __restrict__ blockBase,
                                                      unsigned long long* __restrict__ cand){
  __shared__ unsigned run[3];
  if (threadIdx.x < 3) run[threadIdx.x] = 0;
  __syncthreads();
  unsigned t0 = T[0], t1 = T[1], t2 = T[2];
  unsigned bb0 = blockBase[0 * HB + blockIdx.x];
  unsigned bb1 = blockBase[1 * HB + blockIdx.x];
  unsigned bb2 = blockBase[2 * HB + blockIdx.x];
  int lane = threadIdx.x & 63;
  unsigned long long ltmask = (lane == 0) ? 0ull : ((1ull << lane) - 1ull);
  const int Q = LTOT / 4;
  for (int q = blockIdx.x * 256 + threadIdx.x; q < Q; q += HB * 256){
    int e = q * 4;
    int lvl, idx; const float* p; unsigned tt, bb;
    if (e < L0T){ lvl = 0; idx = e; p = c0; tt = t0; bb = bb0; }
    else if (e < L0T + L1T){ lvl = 1; idx = e - L0T; p = c1; tt = t1; bb = bb1; }
    else { lvl = 2; idx = e - (L0T + L1T); p = c2; tt = t2; bb = bb2; }
    float4 v = *(const float4*)(p + idx);
    unsigned k0 = mkey(v.x), k1 = mkey(v.y), k2 = mkey(v.z), k3 = mkey(v.w);
    bool p0 = (k0 >> 21) >= tt, p1 = (k1 >> 21) >= tt, p2 = (k2 >> 21) >= tt, p3 = (k3 >> 21) >= tt;
    unsigned long long bal0 = __ballot(p0), bal1 = __ballot(p1), bal2 = __ballot(p2), bal3 = __ballot(p3);
    unsigned n0 = (unsigned)__popcll(bal0), n1 = (unsigned)__popcll(bal1),
             n2 = (unsigned)__popcll(bal2), n3 = (unsigned)__popcll(bal3);
    unsigned wtot = n0 + n1 + n2 + n3;
    if (wtot == 0) continue;
    unsigned wold = 0;
    if (lane == 0) wold = atomicAdd(&run[lvl], wtot);
    wold = __shfl(wold, 0);
    unsigned base = bb + wold;
    if (p0){ unsigned pos = base + (unsigned)__popcll(bal0 & ltmask);
      if (pos < CANDCAP) cand[lvl * CANDCAP + pos] = ((unsigned long long)k0 << 32) | (unsigned)(~(unsigned)idx); }
    if (p1){ unsigned pos = base + n0 + (unsigned)__popcll(bal1 & ltmask);
      if (pos < CANDCAP) cand[lvl * CANDCAP + pos] = ((unsigned long long)k1 << 32) | (unsigned)(~(unsigned)(idx + 1)); }
    if (p2){ unsigned pos = base + n0 + n1 + (unsigned)__popcll(bal2 & ltmask);
      if (pos < CANDCAP) cand[lvl * CANDCAP + pos] = ((unsigned long long)k2 << 32) | (unsigned)(~(unsigned)(idx + 2)); }
    if (p3){ unsigned pos = base + n0 + n1 + n2 + (unsigned)__popcll(bal3 & ltmask);
      if (pos < CANDCAP) cand[lvl * CANDCAP + pos] = ((unsigned long long)k3 << 32) | (unsigned)(~(unsigned)(idx + 3)); }
  }
}

// level rank, j-split: each block counts one 1024-key chunk for 256 items; atomic partial
__global__ __launch_bounds__(256) void level_rank_partial(
    const unsigned* __restrict__ candCnt, const unsigned long long* __restrict__ cand,
    unsigned* __restrict__ lrank){
  __shared__ unsigned long long ch[LCHUNK];
  int lvl = blockIdx.z;
  int cnt = (int)candCnt[lvl];
  int j0 = blockIdx.y * LCHUNK;
  int i = blockIdx.x * 256 + threadIdx.x;
  if (j0 >= cnt || (int)(blockIdx.x * 256) >= cnt) return;
  int jn = cnt - j0; if (jn > LCHUNK) jn = LCHUNK;
  int jnP = (jn + 7) & ~7;
  for (int j = threadIdx.x; j < jn; j += 256) ch[j] = cand[lvl * CANDCAP + j0 + j];
  for (int j = jn + threadIdx.x; j < jnP; j += 256) ch[j] = 0ull;  // 0 never > any key
  __syncthreads();
  if (i >= cnt) return;
  unsigned long long ki = cand[lvl * CANDCAP + i];
  int r0 = 0, r1 = 0, r2 = 0, r3 = 0;
  for (int j = 0; j < jnP; j += 8){
    unsigned long long a0 = ch[j+0], a1 = ch[j+1], a2 = ch[j+2], a3 = ch[j+3];
    unsigned long long a4 = ch[j+4], a5 = ch[j+5], a6 = ch[j+6], a7 = ch[j+7];
    r0 += (int)(a0 > ki) + (int)(a4 > ki);
    r1 += (int)(a1 > ki) + (int)(a5 > ki);
    r2 += (int)(a2 > ki) + (int)(a6 > ki);
    r3 += (int)(a3 > ki) + (int)(a7 > ki);
  }
  unsigned r = (unsigned)(r0 + r1 + r2 + r3);
  if (r) atomicAdd(&lrank[lvl * CANDCAP + i], r);
}

// place rank<K candidates at concat position base+r; compute sigmoid/valid/box
__global__ __launch_bounds__(256) void level_scatter(
    const float* __restrict__ box0, const float* __restrict__ box1, const float* __restrict__ box2,
    const unsigned* __restrict__ candCnt, const unsigned long long* __restrict__ cand,
    const unsigned* __restrict__ lrank,
    unsigned* __restrict__ ckey, float* __restrict__ cscore, int* __restrict__ clabel,
    float* __restrict__ cbox, unsigned* __restrict__ cvalid){
  int lvl = blockIdx.y;
  int cnt = (int)candCnt[lvl];
  int i = blockIdx.x * 256 + threadIdx.x;
  if (i >= cnt) return;
  unsigned K = (lvl == 2) ? 1600u : 2000u;
  unsigned r = lrank[lvl * CANDCAP + i];
  if (r >= K) return;
  const float* bx = (lvl == 0) ? box0 : ((lvl == 1) ? box1 : box2);
  unsigned long long ki = cand[lvl * CANDCAP + i];
  unsigned key = (unsigned)(ki >> 32);
  unsigned idxm = ~(unsigned)ki;
  int anchor = (int)(idxm / 80u);
  int lbl = (int)(idxm % 80u);
  unsigned fb = (key & 0x80000000u) ? (key ^ 0x80000000u) : ~key;
  float logit = __uint_as_float(fb);
  float sc = 1.0f / (1.0f + expf(-logit));
  int pos = lvl * 2000 + (int)r;
  ckey[pos] = key;
  cscore[pos] = sc;
  clabel[pos] = lbl;
  cvalid[pos] = (sc > 0.05f) ? 1u : 0u;
  float4 b = *(const float4*)(bx + (size_t)anchor * 4);
  *(float4*)(cbox + pos * 4) = b;
}

// global stable rank, j-split (key = (valid?key:0)<<32 | ~concat_pos)
__global__ __launch_bounds__(256) void global_rank_partial(
    const unsigned* __restrict__ ckey, const unsigned* __restrict__ cvalid,
    unsigned* __restrict__ grank){
  __shared__ unsigned long long ch[GCHUNK + 4];   // pad 700 -> 704
  int j0 = blockIdx.y * GCHUNK;
  for (int j = threadIdx.x; j < GCHUNK; j += 256){
    int g = j0 + j;
    unsigned eff = cvalid[g] ? ckey[g] : 0u;
    ch[j] = ((unsigned long long)eff << 32) | (unsigned)(~(unsigned)g);
  }
  if (threadIdx.x < 4) ch[GCHUNK + threadIdx.x] = 0ull;
  __syncthreads();
  int i = blockIdx.x * 256 + threadIdx.x;
  if (i >= NTOT) return;
  unsigned effi = cvalid[i] ? ckey[i] : 0u;
  unsigned long long ki = ((unsigned long long)effi << 32) | (unsigned)(~(unsigned)i);
  int r0 = 0, r1 = 0, r2 = 0, r3 = 0;
  for (int j = 0; j < GCHUNK + 4; j += 8){
    unsigned long long a0 = ch[j+0], a1 = ch[j+1], a2 = ch[j+2], a3 = ch[j+3];
    unsigned long long a4 = ch[j+4], a5 = ch[j+5], a6 = ch[j+6], a7 = ch[j+7];
    r0 += (int)(a0 > ki) + (int)(a4 > ki);
    r1 += (int)(a1 > ki) + (int)(a5 > ki);
    r2 += (int)(a2 > ki) + (int)(a6 > ki);
    r3 += (int)(a3 > ki) + (int)(a7 > ki);
  }
  unsigned r = (unsigned)(r0 + r1 + r2 + r3);
  if (r) atomicAdd(&grank[i], r);
}

__device__ __forceinline__ float read_dim(const int* p){
  int iv = p[0];
  if (iv > 0 && iv < (1 << 24)) return (float)iv;   // stored as int
  return __int_as_float(iv);                        // stored as float bits
}

// scatter into sorted order; writes bbox/score/label straight into d_out + nms inputs
__global__ __launch_bounds__(256) void global_scatter(
    const unsigned* __restrict__ ckey, const float* __restrict__ cscore,
    const int* __restrict__ clabel, const float* __restrict__ cbox,
    const unsigned* __restrict__ cvalid, const unsigned* __restrict__ grank,
    const int* __restrict__ imw, const int* __restrict__ imh,
    float* __restrict__ out, int* __restrict__ slabel,
    float* __restrict__ soff, unsigned* __restrict__ svalid){
  int i = blockIdx.x * 256 + threadIdx.x;
  if (i >= NTOT) return;
  int r = (int)grank[i];
  int lbl = clabel[i];
  float off = (float)lbl * 10000.0f;
  slabel[r] = lbl;
  svalid[r] = cvalid[i];
  float4 b = *(const float4*)(cbox + (size_t)i * 4);
  float4 bo; bo.x = b.x + off; bo.y = b.y + off; bo.z = b.z + off; bo.w = b.w + off;
  *(float4*)(soff + (size_t)r * 4) = bo;
  float wv = read_dim(imw), hv = read_dim(imh);
  float sw = (float)(1.0 / (double)wv);   // match python 1.0/img_w (double) -> f32
  float sh = (float)(1.0 / (double)hv);
  out[r * 4 + 0] = fminf(fmaxf(b.x * sw, 0.0f), 1.0f);
  out[r * 4 + 1] = fminf(fmaxf(b.y * sh, 0.0f), 1.0f);
  out[r * 4 + 2] = fminf(fmaxf(b.z * sw, 0.0f), 1.0f);
  out[r * 4 + 3] = fminf(fmaxf(b.w * sh, 0.0f), 1.0f);
  out[NTOT * 4 + r] = cscore[i];
  out[NTOT * 5 + r] = (float)lbl;
}

// suppression bitmask: upper-tri words written UNCONDITIONALLY (no memset needed);
// lower-tri never written and never read (scan guards word >= chunk).
__global__ void nms_mask_kernel(const float* __restrict__ soff, const int* __restrict__ slabel,
                                unsigned* __restrict__ rowAny, unsigned long long* __restrict__ mask,
                                unsigned long long* __restrict__ diagT){
  __shared__ float cb[64][4];
  __shared__ float ca[64];
  __shared__ int cl[64];
  int wi = blockIdx.x, wj = blockIdx.y;
  if (wj < wi) return;
  int t = threadIdx.x;
  int i = wi * 64 + t;
  int j0 = wj * 64;
  int j = j0 + t;
  if (j < NTOT){
    float x1 = soff[j * 4 + 0], y1 = soff[j * 4 + 1];
    float x2 = soff[j * 4 + 2], y2 = soff[j * 4 + 3];
    cb[t][0] = x1; cb[t][1] = y1; cb[t][2] = x2; cb[t][3] = y2;
    {
#pragma clang fp contract(off)
      ca[t] = fmaxf(x2 - x1, 0.0f) * fmaxf(y2 - y1, 0.0f);
    }
    cl[t] = slabel[j];
  } else {
    cl[t] = -1;
  }
  __syncthreads();
  unsigned long long w = 0ull;
  if (i < NTOT){
    float ax1 = soff[i * 4 + 0], ay1 = soff[i * 4 + 1];
    float ax2 = soff[i * 4 + 2], ay2 = soff[i * 4 + 3];
    int li = slabel[i];
    float areaA;
    {
#pragma clang fp contract(off)
      areaA = fmaxf(ax2 - ax1, 0.0f) * fmaxf(ay2 - ay1, 0.0f);
    }
    for (int jj = 0; jj < 64; ++jj){
      int jg = j0 + jj;
      if (jg >= NTOT) break;
      if (jg <= i) continue;
      if (cl[jj] != li) continue;
      {
#pragma clang fp contract(off)
        float ltx = fmaxf(ax1, cb[jj][0]);
        float lty = fmaxf(ay1, cb[jj][1]);
        float rbx = fminf(ax2, cb[jj][2]);
        float rby = fminf(ay2, cb[jj][3]);
        float ww = fmaxf(rbx - ltx, 0.0f);
        float hh = fmaxf(rby - lty, 0.0f);
        float inter = ww * hh;
        float uni = (areaA + ca[jj]) - inter;
        float iou = inter / fmaxf(uni, 1e-9f);
        if (iou > 0.6f) w |= (1ull << jj);
      }
    }
    mask[(size_t)i * NW + wj] = w;       // unconditional: upper-tri fully defined
    if (w) rowAny[i] = 1u;
  }
  if (wi == wj) diagT[wi * 64 + t] = w;
}

// greedy scan: 4 waves stage diagT(45KB)+bitmasks into LDS, wave 0 runs the
// serial 88-chunk scan from LDS; act-loop reads only words >= chunk (defined region).
__global__ __launch_bounds__(256) void nms_scan_kernel(
    const unsigned long long* __restrict__ mask,
    const unsigned long long* __restrict__ diagT,
    const unsigned* __restrict__ rowAny,
    const unsigned* __restrict__ svalid,
    unsigned long long* __restrict__ keepW){
  __shared__ unsigned long long sdiag[NW * 64];     // 45056 B
  __shared__ unsigned long long activeW[NW];
  __shared__ unsigned long long reminit[NW];
  int tid = threadIdx.x;
  int lane = tid & 63;
  int wv = tid >> 6;
  for (int i = tid; i < NW * 64; i += 256) sdiag[i] = diagT[i];
  for (int wd = wv; wd < NW; wd += 4){
    int e = wd * 64 + lane;
    unsigned a = (e < NTOT) ? rowAny[e] : 0u;
    unsigned v = (e < NTOT) ? svalid[e] : 0u;
    unsigned long long balv = __ballot(v != 0u);
    unsigned long long bala = __ballot(a != 0u && v != 0u);
    if (lane == 0){ activeW[wd] = bala; reminit[wd] = ~balv; }
  }
  __syncthreads();
  if (wv != 0) return;
  unsigned long long rem0 = reminit[lane];
  unsigned long long rem1 = (lane < NW - 64) ? reminit[64 + lane] : ~0ull;
  for (int c = 0; c < NW; ++c){
    unsigned long long D = sdiag[c * 64 + lane];
    unsigned long long aw = activeW[c];
    unsigned long long a0 = __shfl(rem0, c & 63);
    unsigned long long a1 = __shfl(rem1, c & 63);
    unsigned long long rem = (c < 64) ? a0 : a1;
    unsigned long long nz = __ballot(D != 0ull);
    while (nz){
      int b = __builtin_ctzll(nz);
      nz &= nz - 1;
      unsigned long long Db = __shfl(D, b);
      if (!((rem >> b) & 1ull)) rem |= Db;
    }
    unsigned long long kp = ~rem;
    if (c < 64){ if (lane == c) rem0 = rem; }
    else       { if (lane == c - 64) rem1 = rem; }
    if (lane == 0) keepW[c] = kp;
    unsigned long long act = kp & aw;
    while (act){
      int b = __builtin_ctzll(act);
      act &= act - 1;
      int r2 = c * 64 + b;
      const unsigned long long* mrow = mask + (size_t)r2 * NW;
      if (lane >= c) rem0 |= mrow[lane];                       // words < c are zero by construction
      if (lane < NW - 64 && 64 + lane >= c) rem1 |= mrow[64 + lane];
    }
  }
}

__global__ void output_keep(const unsigned long long* __restrict__ keepW,
                            float* __restrict__ out){
  int r = blockIdx.x * blockDim.x + threadIdx.x;
  if (r >= NTOT) return;
  out[NTOT * 6 + r] = ((keepW[r >> 6] >> (r & 63)) & 1ull) ? 1.0f : 0.0f;
}

// ---- workspace layout (bytes) ----
#define WS_TVAL      0u        // 16
#define WS_CANDCNT   16u       // 16
#define WS_ROWANY    32u       // 22400 -> 22432   (zero region start)
#define WS_LRANK     22432u    // 3*8192*4 = 98304 -> 120736
#define WS_GRANK     120736u   // 22400 -> 143136  (zero region end)
#define WS_ZEROSZ    143104u
#define WS_BLOCKBASE 143136u   // 1536 -> 144672
#define WS_GHIST     144672u   // 24576 -> 169248
#define WS_DIAGT     169248u   // 45056 -> 214304
#define WS_CAND      214304u   // 196608 -> 410912
#define WS_CKEY      410912u   // 22400 -> 433312
#define WS_CSCORE    433312u   // 22400 -> 455712
#define WS_CLABEL    455712u   // 22400 -> 478112
#define WS_CBOX      478112u   // 89600 -> 567712  (16-aligned)
#define WS_CVALID    567712u   // 22400 -> 590112
#define WS_SLABEL    590112u   // 22400 -> 612512
#define WS_SOFF      612512u   // 89600 -> 702112  (16-aligned)
#define WS_SVALID    702112u   // 22400 -> 724512
#define WS_KEEPW     724512u   // 704 -> 725216
#define WS_MASK      725216u   // 5600*88*8 = 3942400 -> 4667616
#define WS_BLOCKHIST WS_MASK   // reuse: 128*3*2048*4 = 3145728 <= 3942400, dead before nms_mask

extern "C" void kernel_launch(void* const* d_in, const int* in_sizes, int n_in,
                              void* d_out, int out_size, void* d_ws, size_t ws_size,
                              hipStream_t stream) {
  (void)in_sizes; (void)n_in; (void)out_size; (void)ws_size;
  const float* cls0 = (const float*)d_in[0];
  const float* box0 = (const float*)d_in[1];
  const float* cls1 = (const float*)d_in[2];
  const float* box1 = (const float*)d_in[3];
  const float* cls2 = (const float*)d_in[4];
  const float* box2 = (const float*)d_in[5];
  const int* imw = (const int*)d_in[6];
  const int* imh = (const int*)d_in[7];
  char* w = (char*)d_ws;
  unsigned* tval      = (unsigned*)(w + WS_TVAL);
  unsigned* candCnt   = (unsigned*)(w + WS_CANDCNT);
  unsigned* rowAny    = (unsigned*)(w + WS_ROWANY);
  unsigned* lrank     = (unsigned*)(w + WS_LRANK);
  unsigned* grank     = (unsigned*)(w + WS_GRANK);
  unsigned* blockBase = (unsigned*)(w + WS_BLOCKBASE);
  unsigned* ghist     = (unsigned*)(w + WS_GHIST);
  unsigned long long* diagT = (unsigned long long*)(w + WS_DIAGT);
  unsigned long long* cand  = (unsigned long long*)(w + WS_CAND);
  unsigned* ckey   = (unsigned*)(w + WS_CKEY);
  float* cscore    = (float*)(w + WS_CSCORE);
  int* clabel      = (int*)(w + WS_CLABEL);
  float* cbox      = (float*)(w + WS_CBOX);
  unsigned* cvalid = (unsigned*)(w + WS_CVALID);
  int* slabel      = (int*)(w + WS_SLABEL);
  float* soff      = (float*)(w + WS_SOFF);
  unsigned* svalid = (unsigned*)(w + WS_SVALID);
  unsigned long long* keepW = (unsigned long long*)(w + WS_KEEPW);
  unsigned long long* mask  = (unsigned long long*)(w + WS_MASK);
  unsigned* blockHist = (unsigned*)(w + WS_BLOCKHIST);

  hipMemsetAsync(w + WS_ROWANY, 0, WS_ZEROSZ, stream);   // rowAny + lrank + grank
  hist_blocks<<<HB, 256, 0, stream>>>(cls0, cls1, cls2, blockHist);
  reduce_hist24<<<24, 256, 0, stream>>>(blockHist, ghist);
  threshbase_kernel<<<3, 256, 0, stream>>>(ghist, blockHist, tval, blockBase, candCnt);
  compact_kernel<<<HB, 256, 0, stream>>>(cls0, cls1, cls2, tval, blockBase, cand);
  level_rank_partial<<<dim3(32, 8, 3), 256, 0, stream>>>(candCnt, cand, lrank);
  level_scatter<<<dim3(32, 3), 256, 0, stream>>>(box0, box1, box2, candCnt, cand, lrank,
                                                 ckey, cscore, clabel, cbox, cvalid);
  global_rank_partial<<<dim3(22, 8), 256, 0, stream>>>(ckey, cvalid, grank);
  global_scatter<<<22, 256, 0, stream>>>(ckey, cscore, clabel, cbox, cvalid, grank,
                                         imw, imh, (float*)d_out, slabel, soff, svalid);
  nms_mask_kernel<<<dim3(88, 88), 64, 0, stream>>>(soff, slabel, rowAny, mask, diagT);
  nms_scan_kernel<<<1, 256, 0, stream>>>(mask, diagT, rowAny, svalid, keepW);
  output_keep<<<22, 256, 0, stream>>>(keepW, (float*)d_out);
}

// Round 9
// 240.352 us; speedup vs baseline: 7.0712x; 1.0785x over previous
//
#include <hip/hip_runtime.h>
#include <math.h>

// ---- problem constants ----
#define L0T 2048000   // 160*160*80
#define L1T 512000    // 80*80*80
#define L2T 128000    // 40*40*80
#define LTOT 2688000
#define NTOT 5600     // 2000+2000+1600
#define NW 88         // ceil(5600/64)
#define NCB 2048      // coarse buckets = key >> 21
#define HB 128        // histogram/compact block count
#define CANDCAP 8192
#define LCHUNK 1024   // level-rank j-chunk (8 chunks cover CANDCAP)
#define GCHUNK 700    // global-rank j-chunk (8 chunks cover NTOT)

// monotone order-preserving key for f32
__device__ __forceinline__ unsigned mkey(float f){
  unsigned u = __float_as_uint(f);
  return u ^ ((unsigned)(((int)u) >> 31) | 0x80000000u);
}

// per-block LDS histogram, no global atomics
__global__ __launch_bounds__(256) void hist_blocks(const float* __restrict__ c0,
                                                   const float* __restrict__ c1,
                                                   const float* __restrict__ c2,
                                                   unsigned* __restrict__ blockHist){
  __shared__ unsigned lh[3 * NCB];
  for (int i = threadIdx.x; i < 3 * NCB; i += 256) lh[i] = 0;
  __syncthreads();
  int g = blockIdx.x * 256 + threadIdx.x;
  const int Q = LTOT / 4;
  for (int q = g; q < Q; q += HB * 256){
    int e = q * 4;
    int lvl, idx; const float* p;
    if (e < L0T){ lvl = 0; idx = e; p = c0; }
    else if (e < L0T + L1T){ lvl = 1; idx = e - L0T; p = c1; }
    else { lvl = 2; idx = e - (L0T + L1T); p = c2; }
    float4 v = *(const float4*)(p + idx);
    unsigned* h = lh + lvl * NCB;
    atomicAdd(&h[mkey(v.x) >> 21], 1u);
    atomicAdd(&h[mkey(v.y) >> 21], 1u);
    atomicAdd(&h[mkey(v.z) >> 21], 1u);
    atomicAdd(&h[mkey(v.w) >> 21], 1u);
  }
  __syncthreads();
  unsigned* out = blockHist + (size_t)blockIdx.x * 3 * NCB;
  for (int i = threadIdx.x; i < 3 * NCB; i += 256) out[i] = lh[i];
}

// 24 blocks: fold 128 per-block hists into one global hist (6144 counters)
__global__ __launch_bounds__(256) void reduce_hist24(const unsigned* __restrict__ blockHist,
                                                     unsigned* __restrict__ ghist){
  int c = blockIdx.x * 256 + threadIdx.x;   // < 6144
  unsigned s = 0;
#pragma unroll 8
  for (int b = 0; b < HB; ++b) s += blockHist[(size_t)b * 3 * NCB + c];
  ghist[c] = s;
}

// one block per level: find T, per-block suffix counts >= T, exclusive scan -> blockBase
__global__ __launch_bounds__(256) void threshbase_kernel(const unsigned* __restrict__ ghist,
                                                         const unsigned* __restrict__ blockHist,
                                                         unsigned* __restrict__ T,
                                                         unsigned* __restrict__ blockBase,
                                                         unsigned* __restrict__ candCnt){
  __shared__ unsigned h[NCB];
  __shared__ unsigned sT;
  __shared__ unsigned cb[HB];
  int lvl = blockIdx.x;
  for (int c = threadIdx.x; c < NCB; c += 256) h[c] = ghist[lvl * NCB + c];
  __syncthreads();
  if (threadIdx.x < 64){
    int lane = threadIdx.x;
    unsigned K = (lvl == 2) ? 1600u : 2000u;
    unsigned p = 0;
    for (int b = lane * 32; b < lane * 32 + 32; ++b) p += h[b];
    unsigned sincl = p;                     // inclusive suffix scan across lanes
    for (int d = 1; d < 64; d <<= 1){
      unsigned t = __shfl_down(sincl, d);
      if (lane + d < 64) sincl += t;
    }
    unsigned s_after = sincl - p;
    if (s_after < K && s_after + p >= K){   // exactly one lane
      unsigned acc = s_after;
      for (int b = lane * 32 + 31; b >= lane * 32; --b){
        acc += h[b];
        if (acc >= K){ sT = (unsigned)b; break; }
      }
    }
  }
  __syncthreads();
  unsigned tt = sT;
  if (threadIdx.x == 0) T[lvl] = tt;
  if (threadIdx.x < HB){
    const unsigned* bh = blockHist + (size_t)threadIdx.x * 3 * NCB + lvl * NCB;
    unsigned s = 0;
    for (unsigned c = tt; c < NCB; ++c) s += bh[c];
    cb[threadIdx.x] = s;
  }
  __syncthreads();
  if (threadIdx.x == 0){
    unsigned acc = 0;
    for (int b = 0; b < HB; ++b){ unsigned v = cb[b]; blockBase[lvl * HB + b] = acc; acc += v; }
    candCnt[lvl] = (acc > CANDCAP) ? CANDCAP : acc;
  }
}

// single-pass compact: positions from blockBase + intra-block LDS counter + ballot prefix
__global__ __launch_bounds__(256) void compact_kernel(const float* __restrict__ c0,
                                                      const float* __restrict__ c1,
                                                      const float* __restrict__ c2,
                                                      const unsigned* __restrict__ T,
                                                      const unsigned* __restrict__ blockBase,
                                                      unsigned long long* __restrict__ cand){
  __shared__ unsigned run[3];
  if (threadIdx.x < 3) run[threadIdx.x] = 0;
  __syncthreads();
  unsigned t0 = T[0], t1 = T[1], t2 = T[2];
  unsigned bb0 = blockBase[0 * HB + blockIdx.x];
  unsigned bb1 = blockBase[1 * HB + blockIdx.x];
  unsigned bb2 = blockBase[2 * HB + blockIdx.x];
  int lane = threadIdx.x & 63;
  unsigned long long ltmask = (lane == 0) ? 0ull : ((1ull << lane) - 1ull);
  const int Q = LTOT / 4;
  for (int q = blockIdx.x * 256 + threadIdx.x; q < Q; q += HB * 256){
    int e = q * 4;
    int lvl, idx; const float* p; unsigned tt, bb;
    if (e < L0T){ lvl = 0; idx = e; p = c0; tt = t0; bb = bb0; }
    else if (e < L0T + L1T){ lvl = 1; idx = e - L0T; p = c1; tt = t1; bb = bb1; }
    else { lvl = 2; idx = e - (L0T + L1T); p = c2; tt = t2; bb = bb2; }
    float4 v = *(const float4*)(p + idx);
    unsigned k0 = mkey(v.x), k1 = mkey(v.y), k2 = mkey(v.z), k3 = mkey(v.w);
    bool p0 = (k0 >> 21) >= tt, p1 = (k1 >> 21) >= tt, p2 = (k2 >> 21) >= tt, p3 = (k3 >> 21) >= tt;
    unsigned long long bal0 = __ballot(p0), bal1 = __ballot(p1), bal2 = __ballot(p2), bal3 = __ballot(p3);
    unsigned n0 = (unsigned)__popcll(bal0), n1 = (unsigned)__popcll(bal1),
             n2 = (unsigned)__popcll(bal2), n3 = (unsigned)__popcll(bal3);
    unsigned wtot = n0 + n1 + n2 + n3;
    if (wtot == 0) continue;
    unsigned wold = 0;
    if (lane == 0) wold = atomicAdd(&run[lvl], wtot);
    wold = __shfl(wold, 0);
    unsigned base = bb + wold;
    if (p0){ unsigned pos = base + (unsigned)__popcll(bal0 & ltmask);
      if (pos < CANDCAP) cand[lvl * CANDCAP + pos] = ((unsigned long long)k0 << 32) | (unsigned)(~(unsigned)idx); }
    if (p1){ unsigned pos = base + n0 + (unsigned)__popcll(bal1 & ltmask);
      if (pos < CANDCAP) cand[lvl * CANDCAP + pos] = ((unsigned long long)k1 << 32) | (unsigned)(~(unsigned)(idx + 1)); }
    if (p2){ unsigned pos = base + n0 + n1 + (unsigned)__popcll(bal2 & ltmask);
      if (pos < CANDCAP) cand[lvl * CANDCAP + pos] = ((unsigned long long)k2 << 32) | (unsigned)(~(unsigned)(idx + 2)); }
    if (p3){ unsigned pos = base + n0 + n1 + n2 + (unsigned)__popcll(bal3 & ltmask);
      if (pos < CANDCAP) cand[lvl * CANDCAP + pos] = ((unsigned long long)k3 << 32) | (unsigned)(~(unsigned)(idx + 3)); }
  }
}

// level rank, j-split: each block counts one 1024-key chunk for 256 items; atomic partial
__global__ __launch_bounds__(256) void level_rank_partial(
    const unsigned* __restrict__ candCnt, const unsigned long long* __restrict__ cand,
    unsigned* __restrict__ lrank){
  __shared__ unsigned long long ch[LCHUNK];
  int lvl = blockIdx.z;
  int cnt = (int)candCnt[lvl];
  int j0 = blockIdx.y * LCHUNK;
  int i = blockIdx.x * 256 + threadIdx.x;
  if (j0 >= cnt || (int)(blockIdx.x * 256) >= cnt) return;
  int jn = cnt - j0; if (jn > LCHUNK) jn = LCHUNK;
  int jnP = (jn + 7) & ~7;
  for (int j = threadIdx.x; j < jn; j += 256) ch[j] = cand[lvl * CANDCAP + j0 + j];
  for (int j = jn + threadIdx.x; j < jnP; j += 256) ch[j] = 0ull;  // 0 never > any key
  __syncthreads();
  if (i >= cnt) return;
  unsigned long long ki = cand[lvl * CANDCAP + i];
  int r0 = 0, r1 = 0, r2 = 0, r3 = 0;
  for (int j = 0; j < jnP; j += 8){
    unsigned long long a0 = ch[j+0], a1 = ch[j+1], a2 = ch[j+2], a3 = ch[j+3];
    unsigned long long a4 = ch[j+4], a5 = ch[j+5], a6 = ch[j+6], a7 = ch[j+7];
    r0 += (int)(a0 > ki) + (int)(a4 > ki);
    r1 += (int)(a1 > ki) + (int)(a5 > ki);
    r2 += (int)(a2 > ki) + (int)(a6 > ki);
    r3 += (int)(a3 > ki) + (int)(a7 > ki);
  }
  unsigned r = (unsigned)(r0 + r1 + r2 + r3);
  if (r) atomicAdd(&lrank[lvl * CANDCAP + i], r);
}

// place rank<K candidates at concat position base+r; compute sigmoid/valid/box
__global__ __launch_bounds__(256) void level_scatter(
    const float* __restrict__ box0, const float* __restrict__ box1, const float* __restrict__ box2,
    const unsigned* __restrict__ candCnt, const unsigned long long* __restrict__ cand,
    const unsigned* __restrict__ lrank,
    unsigned* __restrict__ ckey, float* __restrict__ cscore, int* __restrict__ clabel,
    float* __restrict__ cbox, unsigned* __restrict__ cvalid){
  int lvl = blockIdx.y;
  int cnt = (int)candCnt[lvl];
  int i = blockIdx.x * 256 + threadIdx.x;
  if (i >= cnt) return;
  unsigned K = (lvl == 2) ? 1600u : 2000u;
  unsigned r = lrank[lvl * CANDCAP + i];
  if (r >= K) return;
  const float* bx = (lvl == 0) ? box0 : ((lvl == 1) ? box1 : box2);
  unsigned long long ki = cand[lvl * CANDCAP + i];
  unsigned key = (unsigned)(ki >> 32);
  unsigned idxm = ~(unsigned)ki;
  int anchor = (int)(idxm / 80u);
  int lbl = (int)(idxm % 80u);
  unsigned fb = (key & 0x80000000u) ? (key ^ 0x80000000u) : ~key;
  float logit = __uint_as_float(fb);
  float sc = 1.0f / (1.0f + expf(-logit));
  int pos = lvl * 2000 + (int)r;
  ckey[pos] = key;
  cscore[pos] = sc;
  clabel[pos] = lbl;
  cvalid[pos] = (sc > 0.05f) ? 1u : 0u;
  float4 b = *(const float4*)(bx + (size_t)anchor * 4);
  *(float4*)(cbox + pos * 4) = b;
}

// global stable rank, j-split (key = (valid?key:0)<<32 | ~concat_pos)
__global__ __launch_bounds__(256) void global_rank_partial(
    const unsigned* __restrict__ ckey, const unsigned* __restrict__ cvalid,
    unsigned* __restrict__ grank){
  __shared__ unsigned long long ch[GCHUNK + 4];   // pad 700 -> 704
  int j0 = blockIdx.y * GCHUNK;
  for (int j = threadIdx.x; j < GCHUNK; j += 256){
    int g = j0 + j;
    unsigned eff = cvalid[g] ? ckey[g] : 0u;
    ch[j] = ((unsigned long long)eff << 32) | (unsigned)(~(unsigned)g);
  }
  if (threadIdx.x < 4) ch[GCHUNK + threadIdx.x] = 0ull;
  __syncthreads();
  int i = blockIdx.x * 256 + threadIdx.x;
  if (i >= NTOT) return;
  unsigned effi = cvalid[i] ? ckey[i] : 0u;
  unsigned long long ki = ((unsigned long long)effi << 32) | (unsigned)(~(unsigned)i);
  int r0 = 0, r1 = 0, r2 = 0, r3 = 0;
  for (int j = 0; j < GCHUNK + 4; j += 8){
    unsigned long long a0 = ch[j+0], a1 = ch[j+1], a2 = ch[j+2], a3 = ch[j+3];
    unsigned long long a4 = ch[j+4], a5 = ch[j+5], a6 = ch[j+6], a7 = ch[j+7];
    r0 += (int)(a0 > ki) + (int)(a4 > ki);
    r1 += (int)(a1 > ki) + (int)(a5 > ki);
    r2 += (int)(a2 > ki) + (int)(a6 > ki);
    r3 += (int)(a3 > ki) + (int)(a7 > ki);
  }
  unsigned r = (unsigned)(r0 + r1 + r2 + r3);
  if (r) atomicAdd(&grank[i], r);
}

__device__ __forceinline__ float read_dim(const int* p){
  int iv = p[0];
  if (iv > 0 && iv < (1 << 24)) return (float)iv;   // stored as int
  return __int_as_float(iv);                        // stored as float bits
}

// scatter into sorted order; writes bbox/score/label straight into d_out + nms inputs
__global__ __launch_bounds__(256) void global_scatter(
    const unsigned* __restrict__ ckey, const float* __restrict__ cscore,
    const int* __restrict__ clabel, const float* __restrict__ cbox,
    const unsigned* __restrict__ cvalid, const unsigned* __restrict__ grank,
    const int* __restrict__ imw, const int* __restrict__ imh,
    float* __restrict__ out, int* __restrict__ slabel,
    float* __restrict__ soff, unsigned* __restrict__ svalid){
  int i = blockIdx.x * 256 + threadIdx.x;
  if (i >= NTOT) return;
  int r = (int)grank[i];
  int lbl = clabel[i];
  float off = (float)lbl * 10000.0f;
  slabel[r] = lbl;
  svalid[r] = cvalid[i];
  float4 b = *(const float4*)(cbox + (size_t)i * 4);
  float4 bo; bo.x = b.x + off; bo.y = b.y + off; bo.z = b.z + off; bo.w = b.w + off;
  *(float4*)(soff + (size_t)r * 4) = bo;
  float wv = read_dim(imw), hv = read_dim(imh);
  float sw = (float)(1.0 / (double)wv);   // match python 1.0/img_w (double) -> f32
  float sh = (float)(1.0 / (double)hv);
  out[r * 4 + 0] = fminf(fmaxf(b.x * sw, 0.0f), 1.0f);
  out[r * 4 + 1] = fminf(fmaxf(b.y * sh, 0.0f), 1.0f);
  out[r * 4 + 2] = fminf(fmaxf(b.z * sw, 0.0f), 1.0f);
  out[r * 4 + 3] = fminf(fmaxf(b.w * sh, 0.0f), 1.0f);
  out[NTOT * 4 + r] = cscore[i];
  out[NTOT * 5 + r] = (float)lbl;
}

// suppression bitmask: upper-tri words written UNCONDITIONALLY (no memset needed);
// lower-tri never written and never read (scan guards word >= chunk).
__global__ void nms_mask_kernel(const float* __restrict__ soff, const int* __restrict__ slabel,
                                unsigned* __restrict__ rowAny, unsigned long long* __restrict__ mask,
                                unsigned long long* __restrict__ diagT){
  __shared__ float cb[64][4];
  __shared__ float ca[64];
  __shared__ int cl[64];
  int wi = blockIdx.x, wj = blockIdx.y;
  if (wj < wi) return;
  int t = threadIdx.x;
  int i = wi * 64 + t;
  int j0 = wj * 64;
  int j = j0 + t;
  if (j < NTOT){
    float x1 = soff[j * 4 + 0], y1 = soff[j * 4 + 1];
    float x2 = soff[j * 4 + 2], y2 = soff[j * 4 + 3];
    cb[t][0] = x1; cb[t][1] = y1; cb[t][2] = x2; cb[t][3] = y2;
    {
#pragma clang fp contract(off)
      ca[t] = fmaxf(x2 - x1, 0.0f) * fmaxf(y2 - y1, 0.0f);
    }
    cl[t] = slabel[j];
  } else {
    cl[t] = -1;
  }
  __syncthreads();
  unsigned long long w = 0ull;
  if (i < NTOT){
    float ax1 = soff[i * 4 + 0], ay1 = soff[i * 4 + 1];
    float ax2 = soff[i * 4 + 2], ay2 = soff[i * 4 + 3];
    int li = slabel[i];
    float areaA;
    {
#pragma clang fp contract(off)
      areaA = fmaxf(ax2 - ax1, 0.0f) * fmaxf(ay2 - ay1, 0.0f);
    }
    for (int jj = 0; jj < 64; ++jj){
      int jg = j0 + jj;
      if (jg >= NTOT) break;
      if (jg <= i) continue;
      if (cl[jj] != li) continue;
      {
#pragma clang fp contract(off)
        float ltx = fmaxf(ax1, cb[jj][0]);
        float lty = fmaxf(ay1, cb[jj][1]);
        float rbx = fminf(ax2, cb[jj][2]);
        float rby = fminf(ay2, cb[jj][3]);
        float ww = fmaxf(rbx - ltx, 0.0f);
        float hh = fmaxf(rby - lty, 0.0f);
        float inter = ww * hh;
        float uni = (areaA + ca[jj]) - inter;
        float iou = inter / fmaxf(uni, 1e-9f);
        if (iou > 0.6f) w |= (1ull << jj);
      }
    }
    mask[(size_t)i * NW + wj] = w;       // unconditional: upper-tri fully defined
    if (w) rowAny[i] = 1u;
  }
  if (wi == wj) diagT[wi * 64 + t] = w;
}

// greedy scan: stage diagT+bitmasks to LDS; wave 0 scans with 4-wide ILP-batched
// act-row loads (OR is commutative; kp already resolved intra-chunk order).
// Keep bits -> LDS; all 256 threads write the keep outputs at the end.
__global__ __launch_bounds__(256) void nms_scan_kernel(
    const unsigned long long* __restrict__ mask,
    const unsigned long long* __restrict__ diagT,
    const unsigned* __restrict__ rowAny,
    const unsigned* __restrict__ svalid,
    float* __restrict__ out){
  __shared__ unsigned long long sdiag[NW * 64];     // 45056 B
  __shared__ unsigned long long activeW[NW];
  __shared__ unsigned long long reminit[NW];
  __shared__ unsigned long long keepL[NW];
  int tid = threadIdx.x;
  int lane = tid & 63;
  int wv = tid >> 6;
  for (int i = tid; i < NW * 64; i += 256) sdiag[i] = diagT[i];
  for (int wd = wv; wd < NW; wd += 4){
    int e = wd * 64 + lane;
    unsigned a = (e < NTOT) ? rowAny[e] : 0u;
    unsigned v = (e < NTOT) ? svalid[e] : 0u;
    unsigned long long balv = __ballot(v != 0u);
    unsigned long long bala = __ballot(a != 0u && v != 0u);
    if (lane == 0){ activeW[wd] = bala; reminit[wd] = ~balv; }
  }
  __syncthreads();
  if (wv == 0){
    unsigned long long rem0 = reminit[lane];
    unsigned long long rem1 = (lane < NW - 64) ? reminit[64 + lane] : ~0ull;
    for (int c = 0; c < NW; ++c){
      unsigned long long D = sdiag[c * 64 + lane];
      unsigned long long aw = activeW[c];
      unsigned long long a0 = __shfl(rem0, c & 63);
      unsigned long long a1 = __shfl(rem1, c & 63);
      unsigned long long rem = (c < 64) ? a0 : a1;
      unsigned long long nz = __ballot(D != 0ull);
      while (nz){
        int b = __builtin_ctzll(nz);
        nz &= nz - 1;
        unsigned long long Db = __shfl(D, b);
        if (!((rem >> b) & 1ull)) rem |= Db;
      }
      unsigned long long kp = ~rem;
      if (c < 64){ if (lane == c) rem0 = rem; }
      else       { if (lane == c - 64) rem1 = rem; }
      if (lane == 0) keepL[c] = kp;
      bool lo = (lane >= c);
      bool hi = (lane < NW - 64) && (64 + lane >= c);
      unsigned long long act = kp & aw;   // wave-uniform
      while (act){
        int b0 = __builtin_ctzll(act); act &= act - 1;
        const unsigned long long* p0 = mask + (size_t)(c * 64 + b0) * NW;
        unsigned long long l0a = lo ? p0[lane] : 0ull;
        unsigned long long l0b = hi ? p0[64 + lane] : 0ull;
        unsigned long long l1a = 0, l1b = 0, l2a = 0, l2b = 0, l3a = 0, l3b = 0;
        if (act){
          int b1 = __builtin_ctzll(act); act &= act - 1;
          const unsigned long long* p1 = mask + (size_t)(c * 64 + b1) * NW;
          l1a = lo ? p1[lane] : 0ull;
          l1b = hi ? p1[64 + lane] : 0ull;
          if (act){
            int b2 = __builtin_ctzll(act); act &= act - 1;
            const unsigned long long* p2 = mask + (size_t)(c * 64 + b2) * NW;
            l2a = lo ? p2[lane] : 0ull;
            l2b = hi ? p2[64 + lane] : 0ull;
            if (act){
              int b3 = __builtin_ctzll(act); act &= act - 1;
              const unsigned long long* p3 = mask + (size_t)(c * 64 + b3) * NW;
              l3a = lo ? p3[lane] : 0ull;
              l3b = hi ? p3[64 + lane] : 0ull;
            }
          }
        }
        rem0 |= l0a | l1a | l2a | l3a;
        rem1 |= l0b | l1b | l2b | l3b;
      }
    }
  }
  __syncthreads();
  for (int r = tid; r < NTOT; r += 256)
    out[NTOT * 6 + r] = ((keepL[r >> 6] >> (r & 63)) & 1ull) ? 1.0f : 0.0f;
}

// ---- workspace layout (bytes) ----
#define WS_TVAL      0u        // 16
#define WS_CANDCNT   16u       // 16
#define WS_ROWANY    32u       // 22400 -> 22432   (zero region start)
#define WS_LRANK     22432u    // 3*8192*4 = 98304 -> 120736
#define WS_GRANK     120736u   // 22400 -> 143136  (zero region end)
#define WS_ZEROSZ    143104u
#define WS_BLOCKBASE 143136u   // 1536 -> 144672
#define WS_GHIST     144672u   // 24576 -> 169248
#define WS_DIAGT     169248u   // 45056 -> 214304
#define WS_CAND      214304u   // 196608 -> 410912
#define WS_CKEY      410912u   // 22400 -> 433312
#define WS_CSCORE    433312u   // 22400 -> 455712
#define WS_CLABEL    455712u   // 22400 -> 478112
#define WS_CBOX      478112u   // 89600 -> 567712  (16-aligned)
#define WS_CVALID    567712u   // 22400 -> 590112
#define WS_SLABEL    590112u   // 22400 -> 612512
#define WS_SOFF      612512u   // 89600 -> 702112  (16-aligned)
#define WS_SVALID    702112u   // 22400 -> 724512
#define WS_MASK      724512u   // 5600*88*8 = 3942400 -> 4666912
#define WS_BLOCKHIST WS_MASK   // reuse: 128*3*2048*4 = 3145728 <= 3942400, dead before nms_mask

extern "C" void kernel_launch(void* const* d_in, const int* in_sizes, int n_in,
                              void* d_out, int out_size, void* d_ws, size_t ws_size,
                              hipStream_t stream) {
  (void)in_sizes; (void)n_in; (void)out_size; (void)ws_size;
  const float* cls0 = (const float*)d_in[0];
  const float* box0 = (const float*)d_in[1];
  const float* cls1 = (const float*)d_in[2];
  const float* box1 = (const float*)d_in[3];
  const float* cls2 = (const float*)d_in[4];
  const float* box2 = (const float*)d_in[5];
  const int* imw = (const int*)d_in[6];
  const int* imh = (const int*)d_in[7];
  char* w = (char*)d_ws;
  unsigned* tval      = (unsigned*)(w + WS_TVAL);
  unsigned* candCnt   = (unsigned*)(w + WS_CANDCNT);
  unsigned* rowAny    = (unsigned*)(w + WS_ROWANY);
  unsigned* lrank     = (unsigned*)(w + WS_LRANK);
  unsigned* grank     = (unsigned*)(w + WS_GRANK);
  unsigned* blockBase = (unsigned*)(w + WS_BLOCKBASE);
  unsigned* ghist     = (unsigned*)(w + WS_GHIST);
  unsigned long long* diagT = (unsigned long long*)(w + WS_DIAGT);
  unsigned long long* cand  = (unsigned long long*)(w + WS_CAND);
  unsigned* ckey   = (unsigned*)(w + WS_CKEY);
  float* cscore    = (float*)(w + WS_CSCORE);
  int* clabel      = (int*)(w + WS_CLABEL);
  float* cbox      = (float*)(w + WS_CBOX);
  unsigned* cvalid = (unsigned*)(w + WS_CVALID);
  int* slabel      = (int*)(w + WS_SLABEL);
  float* soff      = (float*)(w + WS_SOFF);
  unsigned* svalid = (unsigned*)(w + WS_SVALID);
  unsigned long long* mask  = (unsigned long long*)(w + WS_MASK);
  unsigned* blockHist = (unsigned*)(w + WS_BLOCKHIST);

  hipMemsetAsync(w + WS_ROWANY, 0, WS_ZEROSZ, stream);   // rowAny + lrank + grank
  hist_blocks<<<HB, 256, 0, stream>>>(cls0, cls1, cls2, blockHist);
  reduce_hist24<<<24, 256, 0, stream>>>(blockHist, ghist);
  threshbase_kernel<<<3, 256, 0, stream>>>(ghist, blockHist, tval, blockBase, candCnt);
  compact_kernel<<<HB, 256, 0, stream>>>(cls0, cls1, cls2, tval, blockBase, cand);
  level_rank_partial<<<dim3(32, 8, 3), 256, 0, stream>>>(candCnt, cand, lrank);
  level_scatter<<<dim3(32, 3), 256, 0, stream>>>(box0, box1, box2, candCnt, cand, lrank,
                                                 ckey, cscore, clabel, cbox, cvalid);
  global_rank_partial<<<dim3(22, 8), 256, 0, stream>>>(ckey, cvalid, grank);
  global_scatter<<<22, 256, 0, stream>>>(ckey, cscore, clabel, cbox, cvalid, grank,
                                         imw, imh, (float*)d_out, slabel, soff, svalid);
  nms_mask_kernel<<<dim3(88, 88), 64, 0, stream>>>(soff, slabel, rowAny, mask, diagT);
  nms_scan_kernel<<<1, 256, 0, stream>>>(mask, diagT, rowAny, svalid, (float*)d_out);
}

// Round 10
// 229.443 us; speedup vs baseline: 7.4074x; 1.0475x over previous
//
#include <hip/hip_runtime.h>
#include <math.h>

// ---- problem constants ----
#define L0T 2048000   // 160*160*80
#define L1T 512000    // 80*80*80
#define L2T 128000    // 40*40*80
#define LTOT 2688000
#define NTOT 5600     // 2000+2000+1600
#define NW 88         // ceil(5600/64)
#define NCB 2048      // coarse buckets = key >> 21
#define HB 128        // histogram/compact block count
#define CANDCAP 8192
#define LCHUNK 1024   // level-rank j-chunk
#define GCHUNK 700    // global-rank j-chunk
#define PAIRCAP 4096  // suppression-pair list capacity (fallback if exceeded)

// monotone order-preserving key for f32
__device__ __forceinline__ unsigned mkey(float f){
  unsigned u = __float_as_uint(f);
  return u ^ ((unsigned)(((int)u) >> 31) | 0x80000000u);
}

// per-block LDS histogram; level-0 4x wave-replicated (hot-bucket atomic serialization)
__global__ __launch_bounds__(256) void hist_blocks(const float* __restrict__ c0,
                                                   const float* __restrict__ c1,
                                                   const float* __restrict__ c2,
                                                   unsigned* __restrict__ blockHist){
  __shared__ unsigned lh[6 * NCB];   // [0,4*NCB): lvl0 x4 replicas; [4N,5N): lvl1; [5N,6N): lvl2
  for (int i = threadIdx.x; i < 6 * NCB; i += 256) lh[i] = 0;
  __syncthreads();
  int wv = threadIdx.x >> 6;
  unsigned* h0 = lh + wv * NCB;
  unsigned* h1 = lh + 4 * NCB;
  unsigned* h2 = lh + 5 * NCB;
  int g = blockIdx.x * 256 + threadIdx.x;
  const int Q = LTOT / 4;
  for (int q = g; q < Q; q += HB * 256){
    int e = q * 4;
    int idx; const float* p; unsigned* h;
    if (e < L0T){ idx = e; p = c0; h = h0; }
    else if (e < L0T + L1T){ idx = e - L0T; p = c1; h = h1; }
    else { idx = e - (L0T + L1T); p = c2; h = h2; }
    float4 v = *(const float4*)(p + idx);
    atomicAdd(&h[mkey(v.x) >> 21], 1u);
    atomicAdd(&h[mkey(v.y) >> 21], 1u);
    atomicAdd(&h[mkey(v.z) >> 21], 1u);
    atomicAdd(&h[mkey(v.w) >> 21], 1u);
  }
  __syncthreads();
  unsigned* out = blockHist + (size_t)blockIdx.x * 3 * NCB;
  for (int i = threadIdx.x; i < 3 * NCB; i += 256){
    unsigned s;
    if (i < NCB)            s = lh[i] + lh[NCB + i] + lh[2 * NCB + i] + lh[3 * NCB + i];
    else if (i < 2 * NCB)   s = lh[4 * NCB + (i - NCB)];
    else                    s = lh[5 * NCB + (i - 2 * NCB)];
    out[i] = s;
  }
}

// 24 blocks: fold 128 per-block hists into one global hist (6144 counters)
__global__ __launch_bounds__(256) void reduce_hist24(const unsigned* __restrict__ blockHist,
                                                     unsigned* __restrict__ ghist){
  int c = blockIdx.x * 256 + threadIdx.x;   // < 6144
  unsigned s = 0;
#pragma unroll 8
  for (int b = 0; b < HB; ++b) s += blockHist[(size_t)b * 3 * NCB + c];
  ghist[c] = s;
}

// one block per level: find T, per-block suffix counts >= T, exclusive scan -> blockBase
__global__ __launch_bounds__(256) void threshbase_kernel(const unsigned* __restrict__ ghist,
                                                         const unsigned* __restrict__ blockHist,
                                                         unsigned* __restrict__ T,
                                                         unsigned* __restrict__ blockBase,
                                                         unsigned* __restrict__ candCnt){
  __shared__ unsigned h[NCB];
  __shared__ unsigned sT;
  __shared__ unsigned cb[HB];
  int lvl = blockIdx.x;
  for (int c = threadIdx.x; c < NCB; c += 256) h[c] = ghist[lvl * NCB + c];
  __syncthreads();
  if (threadIdx.x < 64){
    int lane = threadIdx.x;
    unsigned K = (lvl == 2) ? 1600u : 2000u;
    unsigned p = 0;
    for (int b = lane * 32; b < lane * 32 + 32; ++b) p += h[b];
    unsigned sincl = p;
    for (int d = 1; d < 64; d <<= 1){
      unsigned t = __shfl_down(sincl, d);
      if (lane + d < 64) sincl += t;
    }
    unsigned s_after = sincl - p;
    if (s_after < K && s_after + p >= K){
      unsigned acc = s_after;
      for (int b = lane * 32 + 31; b >= lane * 32; --b){
        acc += h[b];
        if (acc >= K){ sT = (unsigned)b; break; }
      }
    }
  }
  __syncthreads();
  unsigned tt = sT;
  if (threadIdx.x == 0) T[lvl] = tt;
  if (threadIdx.x < HB){
    const unsigned* bh = blockHist + (size_t)threadIdx.x * 3 * NCB + lvl * NCB;
    unsigned s = 0;
    for (unsigned c = tt; c < NCB; ++c) s += bh[c];
    cb[threadIdx.x] = s;
  }
  __syncthreads();
  if (threadIdx.x == 0){
    unsigned acc = 0;
    for (int b = 0; b < HB; ++b){ unsigned v = cb[b]; blockBase[lvl * HB + b] = acc; acc += v; }
    candCnt[lvl] = (acc > CANDCAP) ? CANDCAP : acc;
  }
}

// single-pass compact: positions from blockBase + intra-block LDS counter + ballot prefix
__global__ __launch_bounds__(256) void compact_kernel(const float* __restrict__ c0,
                                                      const float* __restrict__ c1,
                                                      const float* __restrict__ c2,
                                                      const unsigned* __restrict__ T,
                                                      const unsigned* __restrict__ blockBase,
                                                      unsigned long long* __restrict__ cand){
  __shared__ unsigned run[3];
  if (threadIdx.x < 3) run[threadIdx.x] = 0;
  __syncthreads();
  unsigned t0 = T[0], t1 = T[1], t2 = T[2];
  unsigned bb0 = blockBase[0 * HB + blockIdx.x];
  unsigned bb1 = blockBase[1 * HB + blockIdx.x];
  unsigned bb2 = blockBase[2 * HB + blockIdx.x];
  int lane = threadIdx.x & 63;
  unsigned long long ltmask = (lane == 0) ? 0ull : ((1ull << lane) - 1ull);
  const int Q = LTOT / 4;
  for (int q = blockIdx.x * 256 + threadIdx.x; q < Q; q += HB * 256){
    int e = q * 4;
    int lvl, idx; const float* p; unsigned tt, bb;
    if (e < L0T){ lvl = 0; idx = e; p = c0; tt = t0; bb = bb0; }
    else if (e < L0T + L1T){ lvl = 1; idx = e - L0T; p = c1; tt = t1; bb = bb1; }
    else { lvl = 2; idx = e - (L0T + L1T); p = c2; tt = t2; bb = bb2; }
    float4 v = *(const float4*)(p + idx);
    unsigned k0 = mkey(v.x), k1 = mkey(v.y), k2 = mkey(v.z), k3 = mkey(v.w);
    bool p0 = (k0 >> 21) >= tt, p1 = (k1 >> 21) >= tt, p2 = (k2 >> 21) >= tt, p3 = (k3 >> 21) >= tt;
    unsigned long long bal0 = __ballot(p0), bal1 = __ballot(p1), bal2 = __ballot(p2), bal3 = __ballot(p3);
    unsigned n0 = (unsigned)__popcll(bal0), n1 = (unsigned)__popcll(bal1),
             n2 = (unsigned)__popcll(bal2), n3 = (unsigned)__popcll(bal3);
    unsigned wtot = n0 + n1 + n2 + n3;
    if (wtot == 0) continue;
    unsigned wold = 0;
    if (lane == 0) wold = atomicAdd(&run[lvl], wtot);
    wold = __shfl(wold, 0);
    unsigned base = bb + wold;
    if (p0){ unsigned pos = base + (unsigned)__popcll(bal0 & ltmask);
      if (pos < CANDCAP) cand[lvl * CANDCAP + pos] = ((unsigned long long)k0 << 32) | (unsigned)(~(unsigned)idx); }
    if (p1){ unsigned pos = base + n0 + (unsigned)__popcll(bal1 & ltmask);
      if (pos < CANDCAP) cand[lvl * CANDCAP + pos] = ((unsigned long long)k1 << 32) | (unsigned)(~(unsigned)(idx + 1)); }
    if (p2){ unsigned pos = base + n0 + n1 + (unsigned)__popcll(bal2 & ltmask);
      if (pos < CANDCAP) cand[lvl * CANDCAP + pos] = ((unsigned long long)k2 << 32) | (unsigned)(~(unsigned)(idx + 2)); }
    if (p3){ unsigned pos = base + n0 + n1 + n2 + (unsigned)__popcll(bal3 & ltmask);
      if (pos < CANDCAP) cand[lvl * CANDCAP + pos] = ((unsigned long long)k3 << 32) | (unsigned)(~(unsigned)(idx + 3)); }
  }
}

// level rank, j-split: each block counts one 1024-key chunk for 256 items; atomic partial
__global__ __launch_bounds__(256) void level_rank_partial(
    const unsigned* __restrict__ candCnt, const unsigned long long* __restrict__ cand,
    unsigned* __restrict__ lrank){
  __shared__ unsigned long long ch[LCHUNK];
  int lvl = blockIdx.z;
  int cnt = (int)candCnt[lvl];
  int j0 = blockIdx.y * LCHUNK;
  int i = blockIdx.x * 256 + threadIdx.x;
  if (j0 >= cnt || (int)(blockIdx.x * 256) >= cnt) return;
  int jn = cnt - j0; if (jn > LCHUNK) jn = LCHUNK;
  int jnP = (jn + 7) & ~7;
  for (int j = threadIdx.x; j < jn; j += 256) ch[j] = cand[lvl * CANDCAP + j0 + j];
  for (int j = jn + threadIdx.x; j < jnP; j += 256) ch[j] = 0ull;
  __syncthreads();
  if (i >= cnt) return;
  unsigned long long ki = cand[lvl * CANDCAP + i];
  int r0 = 0, r1 = 0, r2 = 0, r3 = 0;
  for (int j = 0; j < jnP; j += 8){
    unsigned long long a0 = ch[j+0], a1 = ch[j+1], a2 = ch[j+2], a3 = ch[j+3];
    unsigned long long a4 = ch[j+4], a5 = ch[j+5], a6 = ch[j+6], a7 = ch[j+7];
    r0 += (int)(a0 > ki) + (int)(a4 > ki);
    r1 += (int)(a1 > ki) + (int)(a5 > ki);
    r2 += (int)(a2 > ki) + (int)(a6 > ki);
    r3 += (int)(a3 > ki) + (int)(a7 > ki);
  }
  unsigned r = (unsigned)(r0 + r1 + r2 + r3);
  if (r) atomicAdd(&lrank[lvl * CANDCAP + i], r);
}

// place rank<K candidates at concat position base+r; compute sigmoid/valid/box
__global__ __launch_bounds__(256) void level_scatter(
    const float* __restrict__ box0, const float* __restrict__ box1, const float* __restrict__ box2,
    const unsigned* __restrict__ candCnt, const unsigned long long* __restrict__ cand,
    const unsigned* __restrict__ lrank,
    unsigned* __restrict__ ckey, float* __restrict__ cscore, int* __restrict__ clabel,
    float* __restrict__ cbox, unsigned* __restrict__ cvalid){
  int lvl = blockIdx.y;
  int cnt = (int)candCnt[lvl];
  int i = blockIdx.x * 256 + threadIdx.x;
  if (i >= cnt) return;
  unsigned K = (lvl == 2) ? 1600u : 2000u;
  unsigned r = lrank[lvl * CANDCAP + i];
  if (r >= K) return;
  const float* bx = (lvl == 0) ? box0 : ((lvl == 1) ? box1 : box2);
  unsigned long long ki = cand[lvl * CANDCAP + i];
  unsigned key = (unsigned)(ki >> 32);
  unsigned idxm = ~(unsigned)ki;
  int anchor = (int)(idxm / 80u);
  int lbl = (int)(idxm % 80u);
  unsigned fb = (key & 0x80000000u) ? (key ^ 0x80000000u) : ~key;
  float logit = __uint_as_float(fb);
  float sc = 1.0f / (1.0f + expf(-logit));
  int pos = lvl * 2000 + (int)r;
  ckey[pos] = key;
  cscore[pos] = sc;
  clabel[pos] = lbl;
  cvalid[pos] = (sc > 0.05f) ? 1u : 0u;
  float4 b = *(const float4*)(bx + (size_t)anchor * 4);
  *(float4*)(cbox + pos * 4) = b;
}

// global stable rank, j-split (key = (valid?key:0)<<32 | ~concat_pos)
__global__ __launch_bounds__(256) void global_rank_partial(
    const unsigned* __restrict__ ckey, const unsigned* __restrict__ cvalid,
    unsigned* __restrict__ grank){
  __shared__ unsigned long long ch[GCHUNK + 4];
  int j0 = blockIdx.y * GCHUNK;
  for (int j = threadIdx.x; j < GCHUNK; j += 256){
    int g = j0 + j;
    unsigned eff = cvalid[g] ? ckey[g] : 0u;
    ch[j] = ((unsigned long long)eff << 32) | (unsigned)(~(unsigned)g);
  }
  if (threadIdx.x < 4) ch[GCHUNK + threadIdx.x] = 0ull;
  __syncthreads();
  int i = blockIdx.x * 256 + threadIdx.x;
  if (i >= NTOT) return;
  unsigned effi = cvalid[i] ? ckey[i] : 0u;
  unsigned long long ki = ((unsigned long long)effi << 32) | (unsigned)(~(unsigned)i);
  int r0 = 0, r1 = 0, r2 = 0, r3 = 0;
  for (int j = 0; j < GCHUNK + 4; j += 8){
    unsigned long long a0 = ch[j+0], a1 = ch[j+1], a2 = ch[j+2], a3 = ch[j+3];
    unsigned long long a4 = ch[j+4], a5 = ch[j+5], a6 = ch[j+6], a7 = ch[j+7];
    r0 += (int)(a0 > ki) + (int)(a4 > ki);
    r1 += (int)(a1 > ki) + (int)(a5 > ki);
    r2 += (int)(a2 > ki) + (int)(a6 > ki);
    r3 += (int)(a3 > ki) + (int)(a7 > ki);
  }
  unsigned r = (unsigned)(r0 + r1 + r2 + r3);
  if (r) atomicAdd(&grank[i], r);
}

__device__ __forceinline__ float read_dim(const int* p){
  int iv = p[0];
  if (iv > 0 && iv < (1 << 24)) return (float)iv;
  return __int_as_float(iv);
}

// scatter into sorted order; writes bbox/score/label straight into d_out + nms inputs
__global__ __launch_bounds__(256) void global_scatter(
    const unsigned* __restrict__ ckey, const float* __restrict__ cscore,
    const int* __restrict__ clabel, const float* __restrict__ cbox,
    const unsigned* __restrict__ cvalid, const unsigned* __restrict__ grank,
    const int* __restrict__ imw, const int* __restrict__ imh,
    float* __restrict__ out, int* __restrict__ slabel,
    float* __restrict__ soff, unsigned* __restrict__ svalid){
  int i = blockIdx.x * 256 + threadIdx.x;
  if (i >= NTOT) return;
  int r = (int)grank[i];
  int lbl = clabel[i];
  float off = (float)lbl * 10000.0f;
  slabel[r] = lbl;
  svalid[r] = cvalid[i];
  float4 b = *(const float4*)(cbox + (size_t)i * 4);
  float4 bo; bo.x = b.x + off; bo.y = b.y + off; bo.z = b.z + off; bo.w = b.w + off;
  *(float4*)(soff + (size_t)r * 4) = bo;
  float wv = read_dim(imw), hv = read_dim(imh);
  float sw = (float)(1.0 / (double)wv);
  float sh = (float)(1.0 / (double)hv);
  out[r * 4 + 0] = fminf(fmaxf(b.x * sw, 0.0f), 1.0f);
  out[r * 4 + 1] = fminf(fmaxf(b.y * sh, 0.0f), 1.0f);
  out[r * 4 + 2] = fminf(fmaxf(b.z * sw, 0.0f), 1.0f);
  out[r * 4 + 3] = fminf(fmaxf(b.w * sh, 0.0f), 1.0f);
  out[NTOT * 4 + r] = cscore[i];
  out[NTOT * 5 + r] = (float)lbl;
}

// suppression bitmask + explicit sparse pair list (i<<13|j).
// mask upper-tri written unconditionally (fallback path); pairs power the fast scan.
__global__ void nms_mask_kernel(const float* __restrict__ soff, const int* __restrict__ slabel,
                                unsigned* __restrict__ rowAny, unsigned long long* __restrict__ mask,
                                unsigned long long* __restrict__ diagT,
                                unsigned* __restrict__ pairsG, unsigned* __restrict__ pairCnt){
  __shared__ float cb[64][4];
  __shared__ float ca[64];
  __shared__ int cl[64];
  int wi = blockIdx.x, wj = blockIdx.y;
  if (wj < wi) return;
  int t = threadIdx.x;
  int i = wi * 64 + t;
  int j0 = wj * 64;
  int j = j0 + t;
  if (j < NTOT){
    float x1 = soff[j * 4 + 0], y1 = soff[j * 4 + 1];
    float x2 = soff[j * 4 + 2], y2 = soff[j * 4 + 3];
    cb[t][0] = x1; cb[t][1] = y1; cb[t][2] = x2; cb[t][3] = y2;
    {
#pragma clang fp contract(off)
      ca[t] = fmaxf(x2 - x1, 0.0f) * fmaxf(y2 - y1, 0.0f);
    }
    cl[t] = slabel[j];
  } else {
    cl[t] = -1;
  }
  __syncthreads();
  unsigned long long w = 0ull;
  if (i < NTOT){
    float ax1 = soff[i * 4 + 0], ay1 = soff[i * 4 + 1];
    float ax2 = soff[i * 4 + 2], ay2 = soff[i * 4 + 3];
    int li = slabel[i];
    float areaA;
    {
#pragma clang fp contract(off)
      areaA = fmaxf(ax2 - ax1, 0.0f) * fmaxf(ay2 - ay1, 0.0f);
    }
    for (int jj = 0; jj < 64; ++jj){
      int jg = j0 + jj;
      if (jg >= NTOT) break;
      if (jg <= i) continue;
      if (cl[jj] != li) continue;
      {
#pragma clang fp contract(off)
        float ltx = fmaxf(ax1, cb[jj][0]);
        float lty = fmaxf(ay1, cb[jj][1]);
        float rbx = fminf(ax2, cb[jj][2]);
        float rby = fminf(ay2, cb[jj][3]);
        float ww = fmaxf(rbx - ltx, 0.0f);
        float hh = fmaxf(rby - lty, 0.0f);
        float inter = ww * hh;
        float uni = (areaA + ca[jj]) - inter;
        float iou = inter / fmaxf(uni, 1e-9f);
        if (iou > 0.6f) w |= (1ull << jj);
      }
    }
    mask[(size_t)i * NW + wj] = w;
    if (w){
      rowAny[i] = 1u;
      int np = __popcll(w);
      unsigned base = atomicAdd(pairCnt, (unsigned)np);
      unsigned long long t2 = w; unsigned k = 0;
      while (t2){
        int b = __builtin_ctzll(t2); t2 &= t2 - 1;
        unsigned pos = base + k++;
        if (pos < PAIRCAP) pairsG[pos] = ((unsigned)i << 13) | (unsigned)(j0 + b);
      }
    }
  }
  if (wi == wj) diagT[wi * 64 + t] = w;
}

// greedy scan, fast path: LDS-bucketed sparse pairs; serial chain is pure LDS.
// Fallback (pair overflow): round-9 global-mask act-loop. Bit-identical semantics.
__global__ __launch_bounds__(256) void nms_scan_kernel(
    const unsigned long long* __restrict__ mask,
    const unsigned long long* __restrict__ diagT,
    const unsigned* __restrict__ rowAny,
    const unsigned* __restrict__ svalid,
    const unsigned* __restrict__ pairsG,
    const unsigned* __restrict__ pairCnt,
    float* __restrict__ out){
  __shared__ unsigned long long sdiag[NW * 64];     // 45056 B
  __shared__ unsigned long long remW[NW];           // running removed words
  __shared__ unsigned long long keepL[NW];
  __shared__ unsigned long long activeW[NW];        // fallback only
  __shared__ unsigned spair[PAIRCAP];               // 16384 B
  __shared__ unsigned bstart[NW];
  __shared__ unsigned bcnt[NW];
  __shared__ unsigned bcur[NW];
  int tid = threadIdx.x;
  int lane = tid & 63;
  int wv = tid >> 6;
  for (int i = tid; i < NW * 64; i += 256) sdiag[i] = diagT[i];
  for (int wd = wv; wd < NW; wd += 4){
    int e = wd * 64 + lane;
    unsigned a = (e < NTOT) ? rowAny[e] : 0u;
    unsigned v = (e < NTOT) ? svalid[e] : 0u;
    unsigned long long balv = __ballot(v != 0u);
    unsigned long long bala = __ballot(a != 0u && v != 0u);
    if (lane == 0){ remW[wd] = ~balv; activeW[wd] = bala; }
  }
  if (tid < NW) bcnt[tid] = 0;
  __syncthreads();
  unsigned np = *pairCnt;
  bool fast = (np <= PAIRCAP);
  if (fast){
    for (unsigned t = tid; t < np; t += 256) atomicAdd(&bcnt[pairsG[t] >> 19], 1u);
    __syncthreads();
    if (tid == 0){
      unsigned acc = 0;
      for (int b = 0; b < NW; ++b){ bstart[b] = acc; acc += bcnt[b]; }
    }
    if (tid < NW) bcur[tid] = 0;
    __syncthreads();
    for (unsigned t = tid; t < np; t += 256){
      unsigned pr = pairsG[t];
      unsigned b = pr >> 19;
      unsigned o = atomicAdd(&bcur[b], 1u);
      spair[bstart[b] + o] = pr;
    }
  }
  __syncthreads();
  if (wv == 0){
    if (fast){
      for (int c = 0; c < NW; ++c){
        unsigned long long rem = remW[c];            // uniform LDS broadcast
        unsigned long long D = sdiag[c * 64 + lane];
        unsigned long long nz = __ballot(D != 0ull);
        while (nz){
          int b = __builtin_ctzll(nz);
          nz &= nz - 1;
          unsigned long long Db = __shfl(D, b);
          if (!((rem >> b) & 1ull)) rem |= Db;
        }
        unsigned long long kp = ~rem;
        if (lane == 0) keepL[c] = kp;
        unsigned bs = bstart[c], bn = bcnt[c];
        for (unsigned t = lane; t < bn; t += 64){
          unsigned pr = spair[bs + t];
          unsigned ii = (pr >> 13) & 8191u;
          unsigned jj = pr & 8191u;
          if ((kp >> (ii & 63u)) & 1ull)
            atomicOr(&remW[jj >> 6], 1ull << (jj & 63u));
        }
        asm volatile("s_waitcnt lgkmcnt(0)" ::: "memory");
      }
    } else {
      // fallback: register rem + batched global mask-row loads (round-9 path)
      unsigned long long rem0 = remW[lane];
      unsigned long long rem1 = (lane < NW - 64) ? remW[64 + lane] : ~0ull;
      for (int c = 0; c < NW; ++c){
        unsigned long long D = sdiag[c * 64 + lane];
        unsigned long long aw = activeW[c];
        unsigned long long a0 = __shfl(rem0, c & 63);
        unsigned long long a1 = __shfl(rem1, c & 63);
        unsigned long long rem = (c < 64) ? a0 : a1;
        unsigned long long nz = __ballot(D != 0ull);
        while (nz){
          int b = __builtin_ctzll(nz);
          nz &= nz - 1;
          unsigned long long Db = __shfl(D, b);
          if (!((rem >> b) & 1ull)) rem |= Db;
        }
        unsigned long long kp = ~rem;
        if (c < 64){ if (lane == c) rem0 = rem; }
        else       { if (lane == c - 64) rem1 = rem; }
        if (lane == 0) keepL[c] = kp;
        bool lo = (lane >= c);
        bool hi = (lane < NW - 64) && (64 + lane >= c);
        unsigned long long act = kp & aw;
        while (act){
          int b0 = __builtin_ctzll(act); act &= act - 1;
          const unsigned long long* p0 = mask + (size_t)(c * 64 + b0) * NW;
          unsigned long long l0a = lo ? p0[lane] : 0ull;
          unsigned long long l0b = hi ? p0[64 + lane] : 0ull;
          unsigned long long l1a = 0, l1b = 0, l2a = 0, l2b = 0, l3a = 0, l3b = 0;
          if (act){
            int b1 = __builtin_ctzll(act); act &= act - 1;
            const unsigned long long* p1 = mask + (size_t)(c * 64 + b1) * NW;
            l1a = lo ? p1[lane] : 0ull;
            l1b = hi ? p1[64 + lane] : 0ull;
            if (act){
              int b2 = __builtin_ctzll(act); act &= act - 1;
              const unsigned long long* p2 = mask + (size_t)(c * 64 + b2) * NW;
              l2a = lo ? p2[lane] : 0ull;
              l2b = hi ? p2[64 + lane] : 0ull;
              if (act){
                int b3 = __builtin_ctzll(act); act &= act - 1;
                const unsigned long long* p3 = mask + (size_t)(c * 64 + b3) * NW;
                l3a = lo ? p3[lane] : 0ull;
                l3b = hi ? p3[64 + lane] : 0ull;
              }
            }
          }
          rem0 |= l0a | l1a | l2a | l3a;
          rem1 |= l0b | l1b | l2b | l3b;
        }
      }
    }
  }
  __syncthreads();
  for (int r = tid; r < NTOT; r += 256)
    out[NTOT * 6 + r] = ((keepL[r >> 6] >> (r & 63)) & 1ull) ? 1.0f : 0.0f;
}

// ---- workspace layout (bytes) ----
#define WS_TVAL      0u        // 16
#define WS_CANDCNT   16u       // 16
#define WS_ROWANY    32u       // 22400 -> 22432   (zero region start)
#define WS_PAIRCNT   22432u    // 16 -> 22448
#define WS_LRANK     22448u    // 98304 -> 120752
#define WS_GRANK     120752u   // 22400 -> 143152  (zero region end)
#define WS_ZEROSZ    143120u   // [32, 143152)
#define WS_BLOCKBASE 143152u   // 1536 -> 144688
#define WS_GHIST     144688u   // 24576 -> 169264
#define WS_PAIRS     169264u   // 4096*4 = 16384 -> 185648
#define WS_DIAGT     185648u   // 45056 -> 230704  (8-aligned)
#define WS_CAND      230704u   // 196608 -> 427312 (8-aligned)
#define WS_CKEY      427312u   // 22400 -> 449712
#define WS_CSCORE    449712u   // 22400 -> 472112
#define WS_CLABEL    472112u   // 22400 -> 494512
#define WS_CBOX      494512u   // 89600 -> 584112  (16-aligned)
#define WS_CVALID    584112u   // 22400 -> 606512
#define WS_SLABEL    606512u   // 22400 -> 628912
#define WS_SOFF      628912u   // 89600 -> 718512  (16-aligned)
#define WS_SVALID    718512u   // 22400 -> 740912
#define WS_MASK      740912u   // 3942400 -> 4683312 (8-aligned)
#define WS_BLOCKHIST WS_MASK   // reuse: 3145728 <= 3942400, dead before nms_mask

extern "C" void kernel_launch(void* const* d_in, const int* in_sizes, int n_in,
                              void* d_out, int out_size, void* d_ws, size_t ws_size,
                              hipStream_t stream) {
  (void)in_sizes; (void)n_in; (void)out_size; (void)ws_size;
  const float* cls0 = (const float*)d_in[0];
  const float* box0 = (const float*)d_in[1];
  const float* cls1 = (const float*)d_in[2];
  const float* box1 = (const float*)d_in[3];
  const float* cls2 = (const float*)d_in[4];
  const float* box2 = (const float*)d_in[5];
  const int* imw = (const int*)d_in[6];
  const int* imh = (const int*)d_in[7];
  char* w = (char*)d_ws;
  unsigned* tval      = (unsigned*)(w + WS_TVAL);
  unsigned* candCnt   = (unsigned*)(w + WS_CANDCNT);
  unsigned* rowAny    = (unsigned*)(w + WS_ROWANY);
  unsigned* pairCnt   = (unsigned*)(w + WS_PAIRCNT);
  unsigned* lrank     = (unsigned*)(w + WS_LRANK);
  unsigned* grank     = (unsigned*)(w + WS_GRANK);
  unsigned* blockBase = (unsigned*)(w + WS_BLOCKBASE);
  unsigned* ghist     = (unsigned*)(w + WS_GHIST);
  unsigned* pairsG    = (unsigned*)(w + WS_PAIRS);
  unsigned long long* diagT = (unsigned long long*)(w + WS_DIAGT);
  unsigned long long* cand  = (unsigned long long*)(w + WS_CAND);
  unsigned* ckey   = (unsigned*)(w + WS_CKEY);
  float* cscore    = (float*)(w + WS_CSCORE);
  int* clabel      = (int*)(w + WS_CLABEL);
  float* cbox      = (float*)(w + WS_CBOX);
  unsigned* cvalid = (unsigned*)(w + WS_CVALID);
  int* slabel      = (int*)(w + WS_SLABEL);
  float* soff      = (float*)(w + WS_SOFF);
  unsigned* svalid = (unsigned*)(w + WS_SVALID);
  unsigned long long* mask  = (unsigned long long*)(w + WS_MASK);
  unsigned* blockHist = (unsigned*)(w + WS_BLOCKHIST);

  hipMemsetAsync(w + WS_ROWANY, 0, WS_ZEROSZ, stream);   // rowAny + pairCnt + lrank + grank
  hist_blocks<<<HB, 256, 0, stream>>>(cls0, cls1, cls2, blockHist);
  reduce_hist24<<<24, 256, 0, stream>>>(blockHist, ghist);
  threshbase_kernel<<<3, 256, 0, stream>>>(ghist, blockHist, tval, blockBase, candCnt);
  compact_kernel<<<HB, 256, 0, stream>>>(cls0, cls1, cls2, tval, blockBase, cand);
  level_rank_partial<<<dim3(32, 8, 3), 256, 0, stream>>>(candCnt, cand, lrank);
  level_scatter<<<dim3(32, 3), 256, 0, stream>>>(box0, box1, box2, candCnt, cand, lrank,
                                                 ckey, cscore, clabel, cbox, cvalid);
  global_rank_partial<<<dim3(22, 8), 256, 0, stream>>>(ckey, cvalid, grank);
  global_scatter<<<22, 256, 0, stream>>>(ckey, cscore, clabel, cbox, cvalid, grank,
                                         imw, imh, (float*)d_out, slabel, soff, svalid);
  nms_mask_kernel<<<dim3(88, 88), 64, 0, stream>>>(soff, slabel, rowAny, mask, diagT,
                                                   pairsG, pairCnt);
  nms_scan_kernel<<<1, 256, 0, stream>>>(mask, diagT, rowAny, svalid, pairsG, pairCnt,
                                         (float*)d_out);
}

// Round 11
// 206.785 us; speedup vs baseline: 8.2191x; 1.1096x over previous
//
#include <hip/hip_runtime.h>
#include <math.h>

// ---- problem constants ----
#define L0T 2048000   // 160*160*80
#define L1T 512000    // 80*80*80
#define L2T 128000    // 40*40*80
#define LTOT 2688000
#define NTOT 5600     // 2000+2000+1600
#define NW 88         // ceil(5600/64)
#define NCB 2048      // coarse buckets = key >> 21
#define HB 128        // histogram/compact block count
#define CANDCAP 8192
#define LCHUNK 1024   // level-rank j-chunk
#define GCHUNK 700    // global-rank j-chunk
#define PAIRCAP 4096  // suppression-pair list capacity (fallback if exceeded)

// monotone order-preserving key for f32
__device__ __forceinline__ unsigned mkey(float f){
  unsigned u = __float_as_uint(f);
  return u ^ ((unsigned)(((int)u) >> 31) | 0x80000000u);
}

// per-block LDS histogram; LANE-salted replicas (intra-wave same-address relief):
// lvl0 x4 (lane&3), lvl1 x2 (lane&1), lvl2 x1. 7*NCB*4 = 56KB LDS.
__global__ __launch_bounds__(256) void hist_blocks(const float* __restrict__ c0,
                                                   const float* __restrict__ c1,
                                                   const float* __restrict__ c2,
                                                   unsigned* __restrict__ blockHist){
  __shared__ unsigned lh[7 * NCB];
  for (int i = threadIdx.x; i < 7 * NCB; i += 256) lh[i] = 0;
  __syncthreads();
  unsigned* h0 = lh + (threadIdx.x & 3) * NCB;
  unsigned* h1 = lh + (4 + (threadIdx.x & 1)) * NCB;
  unsigned* h2 = lh + 6 * NCB;
  int g = blockIdx.x * 256 + threadIdx.x;
  const int Q = LTOT / 4;
  for (int q = g; q < Q; q += HB * 256){
    int e = q * 4;
    int idx; const float* p; unsigned* h;
    if (e < L0T){ idx = e; p = c0; h = h0; }
    else if (e < L0T + L1T){ idx = e - L0T; p = c1; h = h1; }
    else { idx = e - (L0T + L1T); p = c2; h = h2; }
    float4 v = *(const float4*)(p + idx);
    atomicAdd(&h[mkey(v.x) >> 21], 1u);
    atomicAdd(&h[mkey(v.y) >> 21], 1u);
    atomicAdd(&h[mkey(v.z) >> 21], 1u);
    atomicAdd(&h[mkey(v.w) >> 21], 1u);
  }
  __syncthreads();
  unsigned* out = blockHist + (size_t)blockIdx.x * 3 * NCB;
  for (int i = threadIdx.x; i < 3 * NCB; i += 256){
    unsigned s;
    if (i < NCB)          s = lh[i] + lh[NCB + i] + lh[2 * NCB + i] + lh[3 * NCB + i];
    else if (i < 2 * NCB) s = lh[4 * NCB + (i - NCB)] + lh[5 * NCB + (i - NCB)];
    else                  s = lh[6 * NCB + (i - 2 * NCB)];
    out[i] = s;
  }
}

// 24 blocks: fold 128 per-block hists into one global hist (6144 counters)
__global__ __launch_bounds__(256) void reduce_hist24(const unsigned* __restrict__ blockHist,
                                                     unsigned* __restrict__ ghist){
  int c = blockIdx.x * 256 + threadIdx.x;   // < 6144
  unsigned s = 0;
#pragma unroll 8
  for (int b = 0; b < HB; ++b) s += blockHist[(size_t)b * 3 * NCB + c];
  ghist[c] = s;
}

// one block per level: find T, per-block suffix counts >= T, exclusive scan -> blockBase
__global__ __launch_bounds__(256) void threshbase_kernel(const unsigned* __restrict__ ghist,
                                                         const unsigned* __restrict__ blockHist,
                                                         unsigned* __restrict__ T,
                                                         unsigned* __restrict__ blockBase,
                                                         unsigned* __restrict__ candCnt){
  __shared__ unsigned h[NCB];
  __shared__ unsigned sT;
  __shared__ unsigned cb[HB];
  int lvl = blockIdx.x;
  for (int c = threadIdx.x; c < NCB; c += 256) h[c] = ghist[lvl * NCB + c];
  __syncthreads();
  if (threadIdx.x < 64){
    int lane = threadIdx.x;
    unsigned K = (lvl == 2) ? 1600u : 2000u;
    unsigned p = 0;
    for (int b = lane * 32; b < lane * 32 + 32; ++b) p += h[b];
    unsigned sincl = p;
    for (int d = 1; d < 64; d <<= 1){
      unsigned t = __shfl_down(sincl, d);
      if (lane + d < 64) sincl += t;
    }
    unsigned s_after = sincl - p;
    if (s_after < K && s_after + p >= K){
      unsigned acc = s_after;
      for (int b = lane * 32 + 31; b >= lane * 32; --b){
        acc += h[b];
        if (acc >= K){ sT = (unsigned)b; break; }
      }
    }
  }
  __syncthreads();
  unsigned tt = sT;
  if (threadIdx.x == 0) T[lvl] = tt;
  if (threadIdx.x < HB){
    const unsigned* bh = blockHist + (size_t)threadIdx.x * 3 * NCB + lvl * NCB;
    unsigned s = 0;
    for (unsigned c = tt; c < NCB; ++c) s += bh[c];
    cb[threadIdx.x] = s;
  }
  __syncthreads();
  if (threadIdx.x == 0){
    unsigned acc = 0;
    for (int b = 0; b < HB; ++b){ unsigned v = cb[b]; blockBase[lvl * HB + b] = acc; acc += v; }
    candCnt[lvl] = (acc > CANDCAP) ? CANDCAP : acc;
  }
}

// single-pass compact: positions from blockBase + intra-block LDS counter + ballot prefix
__global__ __launch_bounds__(256) void compact_kernel(const float* __restrict__ c0,
                                                      const float* __restrict__ c1,
                                                      const float* __restrict__ c2,
                                                      const unsigned* __restrict__ T,
                                                      const unsigned* __restrict__ blockBase,
                                                      unsigned long long* __restrict__ cand){
  __shared__ unsigned run[3];
  if (threadIdx.x < 3) run[threadIdx.x] = 0;
  __syncthreads();
  unsigned t0 = T[0], t1 = T[1], t2 = T[2];
  unsigned bb0 = blockBase[0 * HB + blockIdx.x];
  unsigned bb1 = blockBase[1 * HB + blockIdx.x];
  unsigned bb2 = blockBase[2 * HB + blockIdx.x];
  int lane = threadIdx.x & 63;
  unsigned long long ltmask = (lane == 0) ? 0ull : ((1ull << lane) - 1ull);
  const int Q = LTOT / 4;
  for (int q = blockIdx.x * 256 + threadIdx.x; q < Q; q += HB * 256){
    int e = q * 4;
    int lvl, idx; const float* p; unsigned tt, bb;
    if (e < L0T){ lvl = 0; idx = e; p = c0; tt = t0; bb = bb0; }
    else if (e < L0T + L1T){ lvl = 1; idx = e - L0T; p = c1; tt = t1; bb = bb1; }
    else { lvl = 2; idx = e - (L0T + L1T); p = c2; tt = t2; bb = bb2; }
    float4 v = *(const float4*)(p + idx);
    unsigned k0 = mkey(v.x), k1 = mkey(v.y), k2 = mkey(v.z), k3 = mkey(v.w);
    bool p0 = (k0 >> 21) >= tt, p1 = (k1 >> 21) >= tt, p2 = (k2 >> 21) >= tt, p3 = (k3 >> 21) >= tt;
    unsigned long long bal0 = __ballot(p0), bal1 = __ballot(p1), bal2 = __ballot(p2), bal3 = __ballot(p3);
    unsigned n0 = (unsigned)__popcll(bal0), n1 = (unsigned)__popcll(bal1),
             n2 = (unsigned)__popcll(bal2), n3 = (unsigned)__popcll(bal3);
    unsigned wtot = n0 + n1 + n2 + n3;
    if (wtot == 0) continue;
    unsigned wold = 0;
    if (lane == 0) wold = atomicAdd(&run[lvl], wtot);
    wold = __shfl(wold, 0);
    unsigned base = bb + wold;
    if (p0){ unsigned pos = base + (unsigned)__popcll(bal0 & ltmask);
      if (pos < CANDCAP) cand[lvl * CANDCAP + pos] = ((unsigned long long)k0 << 32) | (unsigned)(~(unsigned)idx); }
    if (p1){ unsigned pos = base + n0 + (unsigned)__popcll(bal1 & ltmask);
      if (pos < CANDCAP) cand[lvl * CANDCAP + pos] = ((unsigned long long)k1 << 32) | (unsigned)(~(unsigned)(idx + 1)); }
    if (p2){ unsigned pos = base + n0 + n1 + (unsigned)__popcll(bal2 & ltmask);
      if (pos < CANDCAP) cand[lvl * CANDCAP + pos] = ((unsigned long long)k2 << 32) | (unsigned)(~(unsigned)(idx + 2)); }
    if (p3){ unsigned pos = base + n0 + n1 + n2 + (unsigned)__popcll(bal3 & ltmask);
      if (pos < CANDCAP) cand[lvl * CANDCAP + pos] = ((unsigned long long)k3 << 32) | (unsigned)(~(unsigned)(idx + 3)); }
  }
}

// level rank, j-split: each block counts one 1024-key chunk for 256 items; atomic partial
__global__ __launch_bounds__(256) void level_rank_partial(
    const unsigned* __restrict__ candCnt, const unsigned long long* __restrict__ cand,
    unsigned* __restrict__ lrank){
  __shared__ unsigned long long ch[LCHUNK];
  int lvl = blockIdx.z;
  int cnt = (int)candCnt[lvl];
  int j0 = blockIdx.y * LCHUNK;
  int i = blockIdx.x * 256 + threadIdx.x;
  if (j0 >= cnt || (int)(blockIdx.x * 256) >= cnt) return;
  int jn = cnt - j0; if (jn > LCHUNK) jn = LCHUNK;
  int jnP = (jn + 7) & ~7;
  for (int j = threadIdx.x; j < jn; j += 256) ch[j] = cand[lvl * CANDCAP + j0 + j];
  for (int j = jn + threadIdx.x; j < jnP; j += 256) ch[j] = 0ull;
  __syncthreads();
  if (i >= cnt) return;
  unsigned long long ki = cand[lvl * CANDCAP + i];
  int r0 = 0, r1 = 0, r2 = 0, r3 = 0;
  for (int j = 0; j < jnP; j += 8){
    unsigned long long a0 = ch[j+0], a1 = ch[j+1], a2 = ch[j+2], a3 = ch[j+3];
    unsigned long long a4 = ch[j+4], a5 = ch[j+5], a6 = ch[j+6], a7 = ch[j+7];
    r0 += (int)(a0 > ki) + (int)(a4 > ki);
    r1 += (int)(a1 > ki) + (int)(a5 > ki);
    r2 += (int)(a2 > ki) + (int)(a6 > ki);
    r3 += (int)(a3 > ki) + (int)(a7 > ki);
  }
  unsigned r = (unsigned)(r0 + r1 + r2 + r3);
  if (r) atomicAdd(&lrank[lvl * CANDCAP + i], r);
}

// place rank<K candidates at concat position base+r; compute sigmoid/valid/box
__global__ __launch_bounds__(256) void level_scatter(
    const float* __restrict__ box0, const float* __restrict__ box1, const float* __restrict__ box2,
    const unsigned* __restrict__ candCnt, const unsigned long long* __restrict__ cand,
    const unsigned* __restrict__ lrank,
    unsigned* __restrict__ ckey, float* __restrict__ cscore, int* __restrict__ clabel,
    float* __restrict__ cbox, unsigned* __restrict__ cvalid){
  int lvl = blockIdx.y;
  int cnt = (int)candCnt[lvl];
  int i = blockIdx.x * 256 + threadIdx.x;
  if (i >= cnt) return;
  unsigned K = (lvl == 2) ? 1600u : 2000u;
  unsigned r = lrank[lvl * CANDCAP + i];
  if (r >= K) return;
  const float* bx = (lvl == 0) ? box0 : ((lvl == 1) ? box1 : box2);
  unsigned long long ki = cand[lvl * CANDCAP + i];
  unsigned key = (unsigned)(ki >> 32);
  unsigned idxm = ~(unsigned)ki;
  int anchor = (int)(idxm / 80u);
  int lbl = (int)(idxm % 80u);
  unsigned fb = (key & 0x80000000u) ? (key ^ 0x80000000u) : ~key;
  float logit = __uint_as_float(fb);
  float sc = 1.0f / (1.0f + expf(-logit));
  int pos = lvl * 2000 + (int)r;
  ckey[pos] = key;
  cscore[pos] = sc;
  clabel[pos] = lbl;
  cvalid[pos] = (sc > 0.05f) ? 1u : 0u;
  float4 b = *(const float4*)(bx + (size_t)anchor * 4);
  *(float4*)(cbox + pos * 4) = b;
}

// global stable rank, j-split (key = (valid?key:0)<<32 | ~concat_pos)
__global__ __launch_bounds__(256) void global_rank_partial(
    const unsigned* __restrict__ ckey, const unsigned* __restrict__ cvalid,
    unsigned* __restrict__ grank){
  __shared__ unsigned long long ch[GCHUNK + 4];
  int j0 = blockIdx.y * GCHUNK;
  for (int j = threadIdx.x; j < GCHUNK; j += 256){
    int g = j0 + j;
    unsigned eff = cvalid[g] ? ckey[g] : 0u;
    ch[j] = ((unsigned long long)eff << 32) | (unsigned)(~(unsigned)g);
  }
  if (threadIdx.x < 4) ch[GCHUNK + threadIdx.x] = 0ull;
  __syncthreads();
  int i = blockIdx.x * 256 + threadIdx.x;
  if (i >= NTOT) return;
  unsigned effi = cvalid[i] ? ckey[i] : 0u;
  unsigned long long ki = ((unsigned long long)effi << 32) | (unsigned)(~(unsigned)i);
  int r0 = 0, r1 = 0, r2 = 0, r3 = 0;
  for (int j = 0; j < GCHUNK + 4; j += 8){
    unsigned long long a0 = ch[j+0], a1 = ch[j+1], a2 = ch[j+2], a3 = ch[j+3];
    unsigned long long a4 = ch[j+4], a5 = ch[j+5], a6 = ch[j+6], a7 = ch[j+7];
    r0 += (int)(a0 > ki) + (int)(a4 > ki);
    r1 += (int)(a1 > ki) + (int)(a5 > ki);
    r2 += (int)(a2 > ki) + (int)(a6 > ki);
    r3 += (int)(a3 > ki) + (int)(a7 > ki);
  }
  unsigned r = (unsigned)(r0 + r1 + r2 + r3);
  if (r) atomicAdd(&grank[i], r);
}

__device__ __forceinline__ float read_dim(const int* p){
  int iv = p[0];
  if (iv > 0 && iv < (1 << 24)) return (float)iv;
  return __int_as_float(iv);
}

// scatter into sorted order; writes bbox/score/label straight into d_out + nms inputs
__global__ __launch_bounds__(256) void global_scatter(
    const unsigned* __restrict__ ckey, const float* __restrict__ cscore,
    const int* __restrict__ clabel, const float* __restrict__ cbox,
    const unsigned* __restrict__ cvalid, const unsigned* __restrict__ grank,
    const int* __restrict__ imw, const int* __restrict__ imh,
    float* __restrict__ out, int* __restrict__ slabel,
    float* __restrict__ soff, unsigned* __restrict__ svalid){
  int i = blockIdx.x * 256 + threadIdx.x;
  if (i >= NTOT) return;
  int r = (int)grank[i];
  int lbl = clabel[i];
  float off = (float)lbl * 10000.0f;
  slabel[r] = lbl;
  svalid[r] = cvalid[i];
  float4 b = *(const float4*)(cbox + (size_t)i * 4);
  float4 bo; bo.x = b.x + off; bo.y = b.y + off; bo.z = b.z + off; bo.w = b.w + off;
  *(float4*)(soff + (size_t)r * 4) = bo;
  float wv = read_dim(imw), hv = read_dim(imh);
  float sw = (float)(1.0 / (double)wv);
  float sh = (float)(1.0 / (double)hv);
  out[r * 4 + 0] = fminf(fmaxf(b.x * sw, 0.0f), 1.0f);
  out[r * 4 + 1] = fminf(fmaxf(b.y * sh, 0.0f), 1.0f);
  out[r * 4 + 2] = fminf(fmaxf(b.z * sw, 0.0f), 1.0f);
  out[r * 4 + 3] = fminf(fmaxf(b.w * sh, 0.0f), 1.0f);
  out[NTOT * 4 + r] = cscore[i];
  out[NTOT * 5 + r] = (float)lbl;
}

// suppression bitmask + explicit sparse pair list (i<<13|j).
// mask upper-tri written unconditionally (fallback path); pairs power the fast scan.
__global__ void nms_mask_kernel(const float* __restrict__ soff, const int* __restrict__ slabel,
                                unsigned* __restrict__ rowAny, unsigned long long* __restrict__ mask,
                                unsigned long long* __restrict__ diagT,
                                unsigned* __restrict__ pairsG, unsigned* __restrict__ pairCnt){
  __shared__ float cb[64][4];
  __shared__ float ca[64];
  __shared__ int cl[64];
  int wi = blockIdx.x, wj = blockIdx.y;
  if (wj < wi) return;
  int t = threadIdx.x;
  int i = wi * 64 + t;
  int j0 = wj * 64;
  int j = j0 + t;
  if (j < NTOT){
    float x1 = soff[j * 4 + 0], y1 = soff[j * 4 + 1];
    float x2 = soff[j * 4 + 2], y2 = soff[j * 4 + 3];
    cb[t][0] = x1; cb[t][1] = y1; cb[t][2] = x2; cb[t][3] = y2;
    {
#pragma clang fp contract(off)
      ca[t] = fmaxf(x2 - x1, 0.0f) * fmaxf(y2 - y1, 0.0f);
    }
    cl[t] = slabel[j];
  } else {
    cl[t] = -1;
  }
  __syncthreads();
  unsigned long long w = 0ull;
  if (i < NTOT){
    float ax1 = soff[i * 4 + 0], ay1 = soff[i * 4 + 1];
    float ax2 = soff[i * 4 + 2], ay2 = soff[i * 4 + 3];
    int li = slabel[i];
    float areaA;
    {
#pragma clang fp contract(off)
      areaA = fmaxf(ax2 - ax1, 0.0f) * fmaxf(ay2 - ay1, 0.0f);
    }
    for (int jj = 0; jj < 64; ++jj){
      int jg = j0 + jj;
      if (jg >= NTOT) break;
      if (jg <= i) continue;
      if (cl[jj] != li) continue;
      {
#pragma clang fp contract(off)
        float ltx = fmaxf(ax1, cb[jj][0]);
        float lty = fmaxf(ay1, cb[jj][1]);
        float rbx = fminf(ax2, cb[jj][2]);
        float rby = fminf(ay2, cb[jj][3]);
        float ww = fmaxf(rbx - ltx, 0.0f);
        float hh = fmaxf(rby - lty, 0.0f);
        float inter = ww * hh;
        float uni = (areaA + ca[jj]) - inter;
        float iou = inter / fmaxf(uni, 1e-9f);
        if (iou > 0.6f) w |= (1ull << jj);
      }
    }
    mask[(size_t)i * NW + wj] = w;
    if (w){
      rowAny[i] = 1u;
      int np = __popcll(w);
      unsigned base = atomicAdd(pairCnt, (unsigned)np);
      unsigned long long t2 = w; unsigned k = 0;
      while (t2){
        int b = __builtin_ctzll(t2); t2 &= t2 - 1;
        unsigned pos = base + k++;
        if (pos < PAIRCAP) pairsG[pos] = ((unsigned)i << 13) | (unsigned)(j0 + b);
      }
    }
  }
  if (wi == wj) diagT[wi * 64 + t] = w;
}

// greedy scan, fast path: Jacobi fixed-point over sparse pairs (edges i<j form a DAG;
// iterate keep = valid & ~sup(keep) until stable; stability => exact greedy result).
// All 256 threads parallel per pass. Fallback (pair overflow): round-9 global-mask path.
__global__ __launch_bounds__(256) void nms_scan_kernel(
    const unsigned long long* __restrict__ mask,
    const unsigned long long* __restrict__ diagT,
    const unsigned* __restrict__ rowAny,
    const unsigned* __restrict__ svalid,
    const unsigned* __restrict__ pairsG,
    const unsigned* __restrict__ pairCnt,
    float* __restrict__ out){
  __shared__ unsigned long long sdiag[NW * 64];     // 45056 B (fallback only)
  __shared__ unsigned long long validW[NW];
  __shared__ unsigned long long keepW[NW];
  __shared__ unsigned long long activeW[NW];        // fallback only
  __shared__ unsigned supW[NW * 2];                 // 32-bit halves for atomicOr
  __shared__ unsigned spair[PAIRCAP];               // 16384 B
  __shared__ int schanged;
  int tid = threadIdx.x;
  int lane = tid & 63;
  int wv = tid >> 6;
  for (int wd = wv; wd < NW; wd += 4){
    int e = wd * 64 + lane;
    unsigned a = (e < NTOT) ? rowAny[e] : 0u;
    unsigned v = (e < NTOT) ? svalid[e] : 0u;
    unsigned long long balv = __ballot(v != 0u);
    unsigned long long bala = __ballot(a != 0u && v != 0u);
    if (lane == 0){ validW[wd] = balv; activeW[wd] = bala; }
  }
  __syncthreads();
  unsigned np = *pairCnt;
  bool fast = (np <= PAIRCAP);
  if (fast){
    for (unsigned t = tid; t < np; t += 256) spair[t] = pairsG[t];
    if (tid < NW) keepW[tid] = validW[tid];
    __syncthreads();
    for (int pass = 0; pass < PAIRCAP; ++pass){
      if (tid < NW){ supW[2 * tid] = 0u; supW[2 * tid + 1] = 0u; }
      if (tid == 0) schanged = 0;
      __syncthreads();
      for (unsigned t = tid; t < np; t += 256){
        unsigned pr = spair[t];
        unsigned ii = pr >> 13;
        unsigned jj = pr & 8191u;
        if ((keepW[ii >> 6] >> (ii & 63u)) & 1ull)
          atomicOr(&supW[jj >> 5], 1u << (jj & 31u));
      }
      __syncthreads();
      if (tid < NW){
        unsigned long long sup = (unsigned long long)supW[2 * tid] |
                                 ((unsigned long long)supW[2 * tid + 1] << 32);
        unsigned long long nk = validW[tid] & ~sup;
        if (nk != keepW[tid]){ keepW[tid] = nk; schanged = 1; }
      }
      __syncthreads();
      if (!schanged) break;
    }
  } else {
    // fallback: stage diag words, single-wave scan with register rem + batched mask loads
    for (int i = tid; i < NW * 64; i += 256) sdiag[i] = diagT[i];
    __syncthreads();
    if (wv == 0){
      unsigned long long rem0 = ~validW[lane];
      unsigned long long rem1 = (lane < NW - 64) ? ~validW[64 + lane] : ~0ull;
      for (int c = 0; c < NW; ++c){
        unsigned long long D = sdiag[c * 64 + lane];
        unsigned long long aw = activeW[c];
        unsigned long long a0 = __shfl(rem0, c & 63);
        unsigned long long a1 = __shfl(rem1, c & 63);
        unsigned long long rem = (c < 64) ? a0 : a1;
        unsigned long long nz = __ballot(D != 0ull);
        while (nz){
          int b = __builtin_ctzll(nz);
          nz &= nz - 1;
          unsigned long long Db = __shfl(D, b);
          if (!((rem >> b) & 1ull)) rem |= Db;
        }
        unsigned long long kp = ~rem;
        if (c < 64){ if (lane == c) rem0 = rem; }
        else       { if (lane == c - 64) rem1 = rem; }
        if (lane == 0) keepW[c] = kp;
        bool lo = (lane >= c);
        bool hi = (lane < NW - 64) && (64 + lane >= c);
        unsigned long long act = kp & aw;
        while (act){
          int b0 = __builtin_ctzll(act); act &= act - 1;
          const unsigned long long* p0 = mask + (size_t)(c * 64 + b0) * NW;
          unsigned long long l0a = lo ? p0[lane] : 0ull;
          unsigned long long l0b = hi ? p0[64 + lane] : 0ull;
          unsigned long long l1a = 0, l1b = 0, l2a = 0, l2b = 0, l3a = 0, l3b = 0;
          if (act){
            int b1 = __builtin_ctzll(act); act &= act - 1;
            const unsigned long long* p1 = mask + (size_t)(c * 64 + b1) * NW;
            l1a = lo ? p1[lane] : 0ull;
            l1b = hi ? p1[64 + lane] : 0ull;
            if (act){
              int b2 = __builtin_ctzll(act); act &= act - 1;
              const unsigned long long* p2 = mask + (size_t)(c * 64 + b2) * NW;
              l2a = lo ? p2[lane] : 0ull;
              l2b = hi ? p2[64 + lane] : 0ull;
              if (act){
                int b3 = __builtin_ctzll(act); act &= act - 1;
                const unsigned long long* p3 = mask + (size_t)(c * 64 + b3) * NW;
                l3a = lo ? p3[lane] : 0ull;
                l3b = hi ? p3[64 + lane] : 0ull;
              }
            }
          }
          rem0 |= l0a | l1a | l2a | l3a;
          rem1 |= l0b | l1b | l2b | l3b;
        }
      }
    }
  }
  __syncthreads();
  for (int r = tid; r < NTOT; r += 256)
    out[NTOT * 6 + r] = ((keepW[r >> 6] >> (r & 63)) & 1ull) ? 1.0f : 0.0f;
}

// ---- workspace layout (bytes) ----
#define WS_TVAL      0u        // 16
#define WS_CANDCNT   16u       // 16
#define WS_ROWANY    32u       // 22400 -> 22432   (zero region start)
#define WS_PAIRCNT   22432u    // 16 -> 22448
#define WS_LRANK     22448u    // 98304 -> 120752
#define WS_GRANK     120752u   // 22400 -> 143152  (zero region end)
#define WS_ZEROSZ    143120u   // [32, 143152)
#define WS_BLOCKBASE 143152u   // 1536 -> 144688
#define WS_GHIST     144688u   // 24576 -> 169264
#define WS_PAIRS     169264u   // 4096*4 = 16384 -> 185648
#define WS_DIAGT     185648u   // 45056 -> 230704  (8-aligned)
#define WS_CAND      230704u   // 196608 -> 427312 (8-aligned)
#define WS_CKEY      427312u   // 22400 -> 449712
#define WS_CSCORE    449712u   // 22400 -> 472112
#define WS_CLABEL    472112u   // 22400 -> 494512
#define WS_CBOX      494512u   // 89600 -> 584112  (16-aligned)
#define WS_CVALID    584112u   // 22400 -> 606512
#define WS_SLABEL    606512u   // 22400 -> 628912
#define WS_SOFF      628912u   // 89600 -> 718512  (16-aligned)
#define WS_SVALID    718512u   // 22400 -> 740912
#define WS_MASK      740912u   // 3942400 -> 4683312 (8-aligned)
#define WS_BLOCKHIST WS_MASK   // reuse: 3145728 <= 3942400, dead before nms_mask

extern "C" void kernel_launch(void* const* d_in, const int* in_sizes, int n_in,
                              void* d_out, int out_size, void* d_ws, size_t ws_size,
                              hipStream_t stream) {
  (void)in_sizes; (void)n_in; (void)out_size; (void)ws_size;
  const float* cls0 = (const float*)d_in[0];
  const float* box0 = (const float*)d_in[1];
  const float* cls1 = (const float*)d_in[2];
  const float* box1 = (const float*)d_in[3];
  const float* cls2 = (const float*)d_in[4];
  const float* box2 = (const float*)d_in[5];
  const int* imw = (const int*)d_in[6];
  const int* imh = (const int*)d_in[7];
  char* w = (char*)d_ws;
  unsigned* tval      = (unsigned*)(w + WS_TVAL);
  unsigned* candCnt   = (unsigned*)(w + WS_CANDCNT);
  unsigned* rowAny    = (unsigned*)(w + WS_ROWANY);
  unsigned* pairCnt   = (unsigned*)(w + WS_PAIRCNT);
  unsigned* lrank     = (unsigned*)(w + WS_LRANK);
  unsigned* grank     = (unsigned*)(w + WS_GRANK);
  unsigned* blockBase = (unsigned*)(w + WS_BLOCKBASE);
  unsigned* ghist     = (unsigned*)(w + WS_GHIST);
  unsigned* pairsG    = (unsigned*)(w + WS_PAIRS);
  unsigned long long* diagT = (unsigned long long*)(w + WS_DIAGT);
  unsigned long long* cand  = (unsigned long long*)(w + WS_CAND);
  unsigned* ckey   = (unsigned*)(w + WS_CKEY);
  float* cscore    = (float*)(w + WS_CSCORE);
  int* clabel      = (int*)(w + WS_CLABEL);
  float* cbox      = (float*)(w + WS_CBOX);
  unsigned* cvalid = (unsigned*)(w + WS_CVALID);
  int* slabel      = (int*)(w + WS_SLABEL);
  float* soff      = (float*)(w + WS_SOFF);
  unsigned* svalid = (unsigned*)(w + WS_SVALID);
  unsigned long long* mask  = (unsigned long long*)(w + WS_MASK);
  unsigned* blockHist = (unsigned*)(w + WS_BLOCKHIST);

  hipMemsetAsync(w + WS_ROWANY, 0, WS_ZEROSZ, stream);   // rowAny + pairCnt + lrank + grank
  hist_blocks<<<HB, 256, 0, stream>>>(cls0, cls1, cls2, blockHist);
  reduce_hist24<<<24, 256, 0, stream>>>(blockHist, ghist);
  threshbase_kernel<<<3, 256, 0, stream>>>(ghist, blockHist, tval, blockBase, candCnt);
  compact_kernel<<<HB, 256, 0, stream>>>(cls0, cls1, cls2, tval, blockBase, cand);
  level_rank_partial<<<dim3(32, 8, 3), 256, 0, stream>>>(candCnt, cand, lrank);
  level_scatter<<<dim3(32, 3), 256, 0, stream>>>(box0, box1, box2, candCnt, cand, lrank,
                                                 ckey, cscore, clabel, cbox, cvalid);
  global_rank_partial<<<dim3(22, 8), 256, 0, stream>>>(ckey, cvalid, grank);
  global_scatter<<<22, 256, 0, stream>>>(ckey, cscore, clabel, cbox, cvalid, grank,
                                         imw, imh, (float*)d_out, slabel, soff, svalid);
  nms_mask_kernel<<<dim3(88, 88), 64, 0, stream>>>(soff, slabel, rowAny, mask, diagT,
                                                   pairsG, pairCnt);
  nms_scan_kernel<<<1, 256, 0, stream>>>(mask, diagT, rowAny, svalid, pairsG, pairCnt,
                                         (float*)d_out);
}